// Round 7
// baseline (203.759 us; speedup 1.0000x reference)
//
#include <hip/hip_runtime.h>
#include <hip/hip_bf16.h>

#define BB 8
#define CC 64
#define LL 4096
#define DD 128
#define NN 16
#define EPS 1e-5f
#define NCH 256
#define CLEN 16

typedef short short8 __attribute__((ext_vector_type(8)));
typedef unsigned short ushort8v __attribute__((ext_vector_type(8)));
typedef float f32x4 __attribute__((ext_vector_type(4)));

__device__ __forceinline__ float silu_f(float v) {
    return v / (1.f + __expf(-v));
}
__device__ __forceinline__ float softplus_f(float t) {
    return fmaxf(t, 0.f) + __logf(1.f + __expf(-fabsf(t)));
}
__device__ __forceinline__ unsigned short f2bf(float f) {
    unsigned int u = __float_as_uint(f);
    u += 0x7fff + ((u >> 16) & 1);
    return (unsigned short)(u >> 16);
}
__device__ __forceinline__ float bf2f(unsigned short u) {
    return __uint_as_float(((unsigned int)u) << 16);
}

// ---------------- K0: residual 1x1 conv + BN -> d_out  (4 oc-groups/wave) ----------------
__global__ __launch_bounds__(256) void k_res(const float* __restrict__ x,
                                             const float* __restrict__ rw,
                                             const float* __restrict__ rbn,
                                             float* __restrict__ out) {
    int blk = blockIdx.x;                       // 512
    int b = blk >> 6;
    int s = ((blk & 63) << 6) + (threadIdx.x & 63);
    int oc0 = __builtin_amdgcn_readfirstlane(threadIdx.x >> 6) * 16;
    const float* xb = x + (size_t)b * CC * LL;
    float xv[64];
#pragma unroll
    for (int ic = 0; ic < 64; ic++) xv[ic] = xb[ic * LL + s];
#pragma unroll
    for (int o = 0; o < 16; o++) {
        int oc = oc0 + o;
        const float* wr = rw + oc * 64;
        float acc = 0.f;
#pragma unroll
        for (int ic = 0; ic < 64; ic++) acc = fmaf(xv[ic], wr[ic], acc);
        float g = rbn[oc], be = rbn[64 + oc], m = rbn[128 + oc], v = rbn[192 + oc];
        float sc = g * rsqrtf(v + EPS);
        float sh = be - m * sc;
        out[((size_t)b * 64 + oc) * LL + s] = fmaf(acc, sc, sh);
    }
}

// ---------------- k_front: in_proj (MFMA) + conv1d + SiLU + x_proj (MFMA) fused ----------------
__global__ __launch_bounds__(256) void k_front(const float* __restrict__ x,
                                               const float* __restrict__ wip,
                                               const float* __restrict__ xw,
                                               const float* __restrict__ cw,
                                               const float* __restrict__ cb,
                                               unsigned short* __restrict__ xmg,
                                               unsigned short* __restrict__ zg,
                                               float* __restrict__ Bc2,
                                               float* __restrict__ Cc2,
                                               float* __restrict__ dtpO) {
    int blk = blockIdx.x;                        // 512 = B * (L/64)
    int b = blk >> 6;
    int l0 = (blk & 63) << 6;
    int tid = threadIdx.x;
    int lane = tid & 63;
    int wv = __builtin_amdgcn_readfirstlane(tid >> 6);
    int l15 = lane & 15, l4g = lane >> 4;

    __shared__ unsigned short xt[80 * 64];
    __shared__ unsigned short xmf[80 * 132];
    __shared__ unsigned short zf[64 * 132];
    __shared__ unsigned short xmc[64 * 128];

    for (int idx = tid; idx < 5120; idx += 256) {
        int c = idx / 80;
        int j = idx - c * 80;
        int l = l0 - 3 + j;
        float v = (l >= 0 && l < LL) ? x[((size_t)b * CC + c) * LL + l] : 0.f;
        xt[j * 64 + (((c >> 3) ^ (j & 7)) * 8) + (c & 7)] = f2bf(v);
    }

    short8 af[4][2];
#pragma unroll
    for (int m0 = 0; m0 < 4; m0++) {
        const float* wr = wip + (size_t)(wv * 64 + m0 * 16 + l15) * 64 + l4g * 8;
#pragma unroll
        for (int h = 0; h < 2; h++) {
            float4 a0 = *(const float4*)(wr + h * 32);
            float4 a1 = *(const float4*)(wr + h * 32 + 4);
            short8 f;
            f[0] = (short)f2bf(a0.x); f[1] = (short)f2bf(a0.y);
            f[2] = (short)f2bf(a0.z); f[3] = (short)f2bf(a0.w);
            f[4] = (short)f2bf(a1.x); f[5] = (short)f2bf(a1.y);
            f[6] = (short)f2bf(a1.z); f[7] = (short)f2bf(a1.w);
            af[m0][h] = f;
        }
    }
    __syncthreads();

    f32x4 acc[4][5];
#pragma unroll
    for (int m0 = 0; m0 < 4; m0++)
#pragma unroll
        for (int n0 = 0; n0 < 5; n0++) acc[m0][n0] = (f32x4){0.f, 0.f, 0.f, 0.f};
#pragma unroll
    for (int n0 = 0; n0 < 5; n0++) {
        int j = n0 * 16 + l15;
#pragma unroll
        for (int h = 0; h < 2; h++) {
            short8 bf = *(const short8*)(xt + j * 64 + (((h * 4 + l4g) ^ (j & 7)) * 8));
#pragma unroll
            for (int m0 = 0; m0 < 4; m0++)
                acc[m0][n0] = __builtin_amdgcn_mfma_f32_16x16x32_bf16(af[m0][h], bf, acc[m0][n0], 0, 0, 0);
        }
    }

#pragma unroll
    for (int m0 = 0; m0 < 4; m0++)
#pragma unroll
        for (int n0 = 0; n0 < 5; n0++) {
            int j = n0 * 16 + l15;
            int d = (wv & 1) * 64 + m0 * 16 + l4g * 4;
            ushort4 u = make_ushort4(f2bf(acc[m0][n0][0]), f2bf(acc[m0][n0][1]),
                                     f2bf(acc[m0][n0][2]), f2bf(acc[m0][n0][3]));
            if (wv < 2) {
                *(ushort4*)(xmf + j * 132 + d) = u;
            } else {
                int t = j - 3;
                if (t >= 0 && t < 64) *(ushort4*)(zf + t * 132 + d) = u;
            }
        }
    __syncthreads();

    {
        int d4 = (tid & 31) * 4;
        int tok0 = (tid >> 5) * 8;
        float4 w0 = *(const float4*)(cw + (d4 + 0) * 4);
        float4 w1 = *(const float4*)(cw + (d4 + 1) * 4);
        float4 w2 = *(const float4*)(cw + (d4 + 2) * 4);
        float4 w3 = *(const float4*)(cw + (d4 + 3) * 4);
        float4 cb4 = *(const float4*)(cb + d4);
        size_t gbase = (size_t)b * LL + l0;
        int kc = d4 >> 3;
#pragma unroll
        for (int tt = 0; tt < 8; tt++) {
            int tok = tok0 + tt;
            ushort4 r0 = *(const ushort4*)(xmf + (tok + 0) * 132 + d4);
            ushort4 r1 = *(const ushort4*)(xmf + (tok + 1) * 132 + d4);
            ushort4 r2 = *(const ushort4*)(xmf + (tok + 2) * 132 + d4);
            ushort4 r3 = *(const ushort4*)(xmf + (tok + 3) * 132 + d4);
            float v0 = cb4.x + w0.x * bf2f(r0.x) + w0.y * bf2f(r1.x) + w0.z * bf2f(r2.x) + w0.w * bf2f(r3.x);
            float v1 = cb4.y + w1.x * bf2f(r0.y) + w1.y * bf2f(r1.y) + w1.z * bf2f(r2.y) + w1.w * bf2f(r3.y);
            float v2 = cb4.z + w2.x * bf2f(r0.z) + w2.y * bf2f(r1.z) + w2.z * bf2f(r2.z) + w2.w * bf2f(r3.z);
            float v3 = cb4.w + w3.x * bf2f(r0.w) + w3.y * bf2f(r1.w) + w3.z * bf2f(r2.w) + w3.w * bf2f(r3.w);
            ushort4 o = make_ushort4(f2bf(silu_f(v0)), f2bf(silu_f(v1)), f2bf(silu_f(v2)), f2bf(silu_f(v3)));
            *(ushort4*)(xmg + (gbase + tok) * 128 + d4) = o;
            *(ushort4*)(xmc + tok * 128 + ((kc ^ (tok & 7)) * 8) + (d4 & 4)) = o;
            ushort4 zv = *(const ushort4*)(zf + tok * 132 + d4);
            *(ushort4*)(zg + (gbase + tok) * 128 + d4) = zv;
        }
    }
    __syncthreads();

    short8 pa_[3][4];
#pragma unroll
    for (int mt = 0; mt < 3; mt++) {
        int j = mt * 16 + l15;
#pragma unroll
        for (int ks = 0; ks < 4; ks++) {
            short8 f = {0, 0, 0, 0, 0, 0, 0, 0};
            if (j < 36) {
                const float* wr = xw + (size_t)j * 128 + ks * 32 + l4g * 8;
                float4 a0 = *(const float4*)(wr);
                float4 a1 = *(const float4*)(wr + 4);
                f[0] = (short)f2bf(a0.x); f[1] = (short)f2bf(a0.y);
                f[2] = (short)f2bf(a0.z); f[3] = (short)f2bf(a0.w);
                f[4] = (short)f2bf(a1.x); f[5] = (short)f2bf(a1.y);
                f[6] = (short)f2bf(a1.z); f[7] = (short)f2bf(a1.w);
            }
            pa_[mt][ks] = f;
        }
    }
    int t = wv * 16 + l15;
    f32x4 a3[3];
#pragma unroll
    for (int mt = 0; mt < 3; mt++) a3[mt] = (f32x4){0.f, 0.f, 0.f, 0.f};
#pragma unroll
    for (int ks = 0; ks < 4; ks++) {
        short8 bf = *(const short8*)(xmc + t * 128 + (((ks * 4 + l4g) ^ (t & 7)) * 8));
#pragma unroll
        for (int mt = 0; mt < 3; mt++)
            a3[mt] = __builtin_amdgcn_mfma_f32_16x16x32_bf16(pa_[mt][ks], bf, a3[mt], 0, 0, 0);
    }
    size_t bl = (size_t)b * LL + l0 + t;
    float4 o0 = make_float4(a3[0][0], a3[0][1], a3[0][2], a3[0][3]);
    float4 o1 = make_float4(a3[1][0], a3[1][1], a3[1][2], a3[1][3]);
    float4 o2 = make_float4(a3[2][0], a3[2][1], a3[2][2], a3[2][3]);
    if (l4g == 0) {
        *(float4*)(dtpO + bl * 4) = o0;
        *(float4*)(Bc2 + bl * 16 + 12) = o1;
        *(float4*)(Cc2 + bl * 16 + 12) = o2;
    } else {
        *(float4*)(Bc2 + bl * 16 + (l4g - 1) * 4) = o0;
        *(float4*)(Cc2 + bl * 16 + (l4g - 1) * 4) = o1;
    }
}

// ---------------- Scan pass 1 (4 chunk-waves per block) ----------------
__global__ __launch_bounds__(256) void k_s1(const unsigned short* __restrict__ xmg,
                                            const float* __restrict__ Bc2,
                                            const float* __restrict__ dtpI,
                                            const float* __restrict__ dtw,
                                            const float* __restrict__ dtb,
                                            const float* __restrict__ A_log,
                                            float* __restrict__ chH,
                                            float* __restrict__ chP) {
    int gid = blockIdx.x * 4 + (threadIdx.x >> 6);
    int lane = threadIdx.x & 63;
    int ck = gid & (NCH - 1);
    int dh = (gid >> 8) & 1;
    int b = gid >> 9;
    int d = dh * 64 + lane;
    float a2[16];
#pragma unroll
    for (int j = 0; j < 4; j++) {
        float4 v = *(const float4*)(A_log + d * 16 + j * 4);
        a2[j * 4 + 0] = -__expf(v.x) * 1.4426950408889634f;
        a2[j * 4 + 1] = -__expf(v.y) * 1.4426950408889634f;
        a2[j * 4 + 2] = -__expf(v.z) * 1.4426950408889634f;
        a2[j * 4 + 3] = -__expf(v.w) * 1.4426950408889634f;
    }
    float4 dw = *(const float4*)(dtw + d * 4);
    float dtbd = dtb[d];
    float h[16];
#pragma unroll
    for (int n = 0; n < 16; n++) h[n] = 0.f;
    float sdt = 0.f;
    size_t bl0 = (size_t)b * LL + ck * CLEN;
    const unsigned short* xmp = xmg + bl0 * DD + d;
    const float* Bp = Bc2 + bl0 * 16;
    const float* dpp = dtpI + bl0 * 4;
#pragma unroll 4
    for (int t = 0; t < CLEN; t++) {
        float xmv = bf2f(xmp[(size_t)t * DD]);
        float4 q = *(const float4*)(dpp + t * 4);
        float tp = dtbd + q.x * dw.x + q.y * dw.y + q.z * dw.z + q.w * dw.w;
        float dtv = softplus_f(tp);
        float dx = dtv * xmv;
        float4 B0 = *(const float4*)(Bp + t * 16);
        float4 B1 = *(const float4*)(Bp + t * 16 + 4);
        float4 B2 = *(const float4*)(Bp + t * 16 + 8);
        float4 B3 = *(const float4*)(Bp + t * 16 + 12);
        float Bv[16] = {B0.x, B0.y, B0.z, B0.w, B1.x, B1.y, B1.z, B1.w,
                        B2.x, B2.y, B2.z, B2.w, B3.x, B3.y, B3.z, B3.w};
#pragma unroll
        for (int n = 0; n < 16; n++) {
            float dA = exp2f(dtv * a2[n]);
            h[n] = fmaf(dA, h[n], dx * Bv[n]);
        }
        sdt += dtv;
    }
    size_t cbase = ((size_t)((b * 2 + dh) * NCH + ck)) * 1024 + lane * 16;
#pragma unroll
    for (int j = 0; j < 4; j++) {
        *(float4*)(chH + cbase + j * 4) = make_float4(h[j * 4], h[j * 4 + 1], h[j * 4 + 2], h[j * 4 + 3]);
        *(float4*)(chP + cbase + j * 4) = make_float4(exp2f(a2[j * 4] * sdt), exp2f(a2[j * 4 + 1] * sdt),
                                                      exp2f(a2[j * 4 + 2] * sdt), exp2f(a2[j * 4 + 3] * sdt));
    }
}

// ---------------- Scan pass 2: 16384 scalar recurrences over 256 chunks ----------------
__global__ __launch_bounds__(256) void k_s2(float* __restrict__ chH,
                                            const float* __restrict__ chP) {
    int t = blockIdx.x * 256 + threadIdx.x;   // 0..16383
    int row = t >> 10;
    int q = t & 1023;
    size_t base = (size_t)row * NCH * 1024 + q;
    float H = 0.f;
#pragma unroll 8
    for (int ck = 0; ck < NCH; ck++) {
        size_t a = base + (size_t)ck * 1024;
        float h = chH[a];
        float p = chP[a];
        chH[a] = H;
        H = fmaf(p, H, h);
    }
}

// ---------------- Scan pass 3 (4 chunk-waves per block), Y out bf16 ----------------
__global__ __launch_bounds__(256) void k_s3(const unsigned short* __restrict__ xmg,
                                            const unsigned short* __restrict__ zg,
                                            const float* __restrict__ Bc2,
                                            const float* __restrict__ Cc2,
                                            const float* __restrict__ dtpI,
                                            const float* __restrict__ dtw,
                                            const float* __restrict__ dtb,
                                            const float* __restrict__ A_log,
                                            const float* __restrict__ Dpp,
                                            const float* __restrict__ hinit,
                                            unsigned short* __restrict__ Y) {
    int gid = blockIdx.x * 4 + (threadIdx.x >> 6);
    int lane = threadIdx.x & 63;
    int ck = gid & (NCH - 1);
    int dh = (gid >> 8) & 1;
    int b = gid >> 9;
    int d = dh * 64 + lane;
    float a2[16];
#pragma unroll
    for (int j = 0; j < 4; j++) {
        float4 v = *(const float4*)(A_log + d * 16 + j * 4);
        a2[j * 4 + 0] = -__expf(v.x) * 1.4426950408889634f;
        a2[j * 4 + 1] = -__expf(v.y) * 1.4426950408889634f;
        a2[j * 4 + 2] = -__expf(v.z) * 1.4426950408889634f;
        a2[j * 4 + 3] = -__expf(v.w) * 1.4426950408889634f;
    }
    float4 dw = *(const float4*)(dtw + d * 4);
    float dtbd = dtb[d];
    float Dpd = Dpp[d];
    size_t cbase = ((size_t)((b * 2 + dh) * NCH + ck)) * 1024 + lane * 16;
    float h[16];
#pragma unroll
    for (int j = 0; j < 4; j++) {
        float4 v = *(const float4*)(hinit + cbase + j * 4);
        h[j * 4 + 0] = v.x; h[j * 4 + 1] = v.y; h[j * 4 + 2] = v.z; h[j * 4 + 3] = v.w;
    }
    size_t bl0 = (size_t)b * LL + ck * CLEN;
    const unsigned short* xmp = xmg + bl0 * DD + d;
    const unsigned short* zp = zg + bl0 * DD + d;
    const float* Bp = Bc2 + bl0 * 16;
    const float* Cp = Cc2 + bl0 * 16;
    const float* dpp = dtpI + bl0 * 4;
    unsigned short* Yp = Y + bl0 * DD + d;
#pragma unroll 4
    for (int t = 0; t < CLEN; t++) {
        float xmv = bf2f(xmp[(size_t)t * DD]);
        float zv = bf2f(zp[(size_t)t * DD]);
        float4 q = *(const float4*)(dpp + t * 4);
        float tp = dtbd + q.x * dw.x + q.y * dw.y + q.z * dw.z + q.w * dw.w;
        float dtv = softplus_f(tp);
        float dx = dtv * xmv;
        float4 B0 = *(const float4*)(Bp + t * 16);
        float4 B1 = *(const float4*)(Bp + t * 16 + 4);
        float4 B2 = *(const float4*)(Bp + t * 16 + 8);
        float4 B3 = *(const float4*)(Bp + t * 16 + 12);
        float4 C0 = *(const float4*)(Cp + t * 16);
        float4 C1 = *(const float4*)(Cp + t * 16 + 4);
        float4 C2 = *(const float4*)(Cp + t * 16 + 8);
        float4 C3 = *(const float4*)(Cp + t * 16 + 12);
        float Bv[16] = {B0.x, B0.y, B0.z, B0.w, B1.x, B1.y, B1.z, B1.w,
                        B2.x, B2.y, B2.z, B2.w, B3.x, B3.y, B3.z, B3.w};
        float Cv[16] = {C0.x, C0.y, C0.z, C0.w, C1.x, C1.y, C1.z, C1.w,
                        C2.x, C2.y, C2.z, C2.w, C3.x, C3.y, C3.z, C3.w};
        float y0 = 0.f, y1 = 0.f, y2 = 0.f, y3 = 0.f;
#pragma unroll
        for (int n = 0; n < 16; n += 4) {
            float dA0 = exp2f(dtv * a2[n]);
            float dA1 = exp2f(dtv * a2[n + 1]);
            float dA2 = exp2f(dtv * a2[n + 2]);
            float dA3 = exp2f(dtv * a2[n + 3]);
            h[n] = fmaf(dA0, h[n], dx * Bv[n]);
            h[n + 1] = fmaf(dA1, h[n + 1], dx * Bv[n + 1]);
            h[n + 2] = fmaf(dA2, h[n + 2], dx * Bv[n + 2]);
            h[n + 3] = fmaf(dA3, h[n + 3], dx * Bv[n + 3]);
            y0 = fmaf(h[n], Cv[n], y0);
            y1 = fmaf(h[n + 1], Cv[n + 1], y1);
            y2 = fmaf(h[n + 2], Cv[n + 2], y2);
            y3 = fmaf(h[n + 3], Cv[n + 3], y3);
        }
        float yv = (y0 + y1) + (y2 + y3);
        yv = fmaf(xmv, Dpd, yv);
        Yp[(size_t)t * DD] = f2bf(yv * silu_f(zv));
    }
}

// ---------------- K4: out_proj + PReLU -> img1t bf16 [b][p*64+q][64]  (4 oc-groups/wave) ----------------
__global__ __launch_bounds__(256) void k_outproj(const unsigned short* __restrict__ Y,
                                                 const float* __restrict__ wo,
                                                 const float* __restrict__ pre,
                                                 unsigned short* __restrict__ img1t) {
    int blk = blockIdx.x;                        // 512
    int bl = (blk << 6) + (threadIdx.x & 63);
    int oc0 = __builtin_amdgcn_readfirstlane(threadIdx.x >> 6) * 16;
    const unsigned short* yr = Y + (size_t)bl * DD;
    float acc[16];
#pragma unroll
    for (int o = 0; o < 16; o++) acc[o] = 0.f;
    for (int c8 = 0; c8 < 8; c8++) {
        ushort8v u0 = *(const ushort8v*)(yr + c8 * 16);
        ushort8v u1 = *(const ushort8v*)(yr + c8 * 16 + 8);
        float xv[16];
#pragma unroll
        for (int j = 0; j < 8; j++) { xv[j] = bf2f(u0[j]); xv[8 + j] = bf2f(u1[j]); }
#pragma unroll
        for (int o = 0; o < 16; o++) {
            const float* wr = wo + (size_t)(oc0 + o) * DD + c8 * 16;
            float a = acc[o];
#pragma unroll
            for (int j = 0; j < 16; j++) a = fmaf(xv[j], wr[j], a);
            acc[o] = a;
        }
    }
    float pa = pre[0];
    int b = bl >> 12, l = bl & 4095;
    int px = (l & 63) * 64 + (l >> 6);           // (p = l%64, q = l/64)
    unsigned short* dst = img1t + ((size_t)b * 4096 + px) * 64 + oc0;
#pragma unroll
    for (int g8 = 0; g8 < 2; g8++) {
        ushort8v w;
#pragma unroll
        for (int j = 0; j < 8; j++) {
            float v = acc[g8 * 8 + j];
            v = v >= 0.f ? v : pa * v;
            w[j] = f2bf(v);
        }
        *(ushort8v*)(dst + g8 * 8) = w;
    }
}

// ---------------- weight prep: Wk[oc][shift*64+ic] bf16 for both 3x3 convs ----------------
__global__ __launch_bounds__(256) void k_wprep(const float* __restrict__ w1,
                                               const float* __restrict__ w2,
                                               unsigned short* __restrict__ Wk1,
                                               unsigned short* __restrict__ Wk2) {
    int idx = blockIdx.x * 256 + threadIdx.x;
    if (idx >= 2 * 36864) return;
    const float* w = (idx < 36864) ? w1 : w2;
    unsigned short* dst = (idx < 36864) ? Wk1 : Wk2;
    int r = (idx < 36864) ? idx : idx - 36864;
    int oc = r / 576, k = r % 576;
    int shift = k >> 6, ic = k & 63;
    dst[oc * 576 + k] = f2bf(w[(oc * 64 + ic) * 9 + shift]);
}

// ---------------- K5/K6: 3x3 conv via MFMA bf16 + BN + PReLU (+residual) ----------------
template <bool FINAL>
__global__ __launch_bounds__(256) void k_conv3m(const unsigned short* __restrict__ in_t,
                                                const unsigned short* __restrict__ Wk,
                                                const float* __restrict__ bnp,
                                                const float* __restrict__ pre,
                                                unsigned short* __restrict__ out_t,
                                                float* __restrict__ outf) {
    int bid = blockIdx.x;
    int b = bid >> 6;
    int p = bid & 63;
    int tid = threadIdx.x;
    int lane = tid & 63;
    int wv = tid >> 6;
    int oc0 = __builtin_amdgcn_readfirstlane(wv * 16);
    __shared__ unsigned short lds[3 * 66 * 64];

    short8 afrag[18];
    const unsigned short* wrow = Wk + (size_t)(oc0 + (lane & 15)) * 576 + ((lane >> 4) * 8);
#pragma unroll
    for (int s = 0; s < 18; s++) afrag[s] = *(const short8*)(wrow + s * 32);

    const unsigned short* ib = in_t + (size_t)b * 4096 * 64;
    for (int idx = tid; idx < 1584; idx += 256) {
        int pair = idx >> 3, c = idx & 7;
        int di = pair / 66, col = pair % 66;
        int r = p - 1 + di, q = col - 1;
        ushort8v v = {0, 0, 0, 0, 0, 0, 0, 0};
        if (r >= 0 && r < 64 && q >= 0 && q < 64)
            v = *(const ushort8v*)(ib + ((size_t)(r * 64 + q)) * 64 + c * 8);
        *(ushort8v*)(lds + pair * 64 + ((c ^ (col & 7)) * 8)) = v;
    }
    __syncthreads();

    f32x4 acc[4];
#pragma unroll
    for (int n0 = 0; n0 < 4; n0++) acc[n0] = (f32x4){0.f, 0.f, 0.f, 0.f};
#pragma unroll
    for (int s = 0; s < 18; s++) {
        const int shift = s >> 1, h = s & 1;
        const int di = shift / 3, dj = shift % 3;
#pragma unroll
        for (int n0 = 0; n0 < 4; n0++) {
            int col = n0 * 16 + (lane & 15) + dj;
            int off = (di * 66 + col) * 64 + (((h * 4 + (lane >> 4)) ^ (col & 7)) * 8);
            short8 bfrag = *(const short8*)(lds + off);
            acc[n0] = __builtin_amdgcn_mfma_f32_16x16x32_bf16(afrag[s], bfrag, acc[n0], 0, 0, 0);
        }
    }

    int ocb = oc0 + ((lane >> 4) << 2);
    float4 g4 = *(const float4*)(bnp + ocb);
    float4 be4 = *(const float4*)(bnp + 64 + ocb);
    float4 m4 = *(const float4*)(bnp + 128 + ocb);
    float4 v4 = *(const float4*)(bnp + 192 + ocb);
    float sc[4], sh[4];
    sc[0] = g4.x * rsqrtf(v4.x + EPS); sh[0] = be4.x - m4.x * sc[0];
    sc[1] = g4.y * rsqrtf(v4.y + EPS); sh[1] = be4.y - m4.y * sc[1];
    sc[2] = g4.z * rsqrtf(v4.z + EPS); sh[2] = be4.z - m4.z * sc[2];
    sc[3] = g4.w * rsqrtf(v4.w + EPS); sh[3] = be4.w - m4.w * sc[3];
    float pa = pre[0];
#pragma unroll
    for (int n0 = 0; n0 < 4; n0++) {
        int q = n0 * 16 + (lane & 15);
        float vals[4];
#pragma unroll
        for (int r = 0; r < 4; r++) {
            float v = fmaf(acc[n0][r], sc[r], sh[r]);
            vals[r] = v >= 0.f ? v : pa * v;
        }
        if (FINAL) {
#pragma unroll
            for (int r = 0; r < 4; r++) {
                size_t addr = ((size_t)b * 64 + ocb + r) * 4096 + p * 64 + q;
                outf[addr] = vals[r] + outf[addr];
            }
        } else {
            ushort4 u = make_ushort4(f2bf(vals[0]), f2bf(vals[1]), f2bf(vals[2]), f2bf(vals[3]));
            *(ushort4*)(out_t + ((size_t)b * 4096 + p * 64 + q) * 64 + ocb) = u;
        }
    }
}

extern "C" void kernel_launch(void* const* d_in, const int* in_sizes, int n_in,
                              void* d_out, int out_size, void* d_ws, size_t ws_size,
                              hipStream_t stream) {
    const float* x = (const float*)d_in[0];
    const float* in_proj_w = (const float*)d_in[1];
    const float* conv1d_w = (const float*)d_in[2];
    const float* conv1d_b = (const float*)d_in[3];
    const float* x_proj_w = (const float*)d_in[4];
    const float* dt_proj_w = (const float*)d_in[5];
    const float* dt_proj_b = (const float*)d_in[6];
    const float* A_log = (const float*)d_in[7];
    const float* Dp = (const float*)d_in[8];
    const float* out_proj_w = (const float*)d_in[9];
    const float* prelu_ssm = (const float*)d_in[10];
    const float* res_w = (const float*)d_in[11];
    const float* res_bn = (const float*)d_in[12];
    const float* conv1_w = (const float*)d_in[13];
    const float* bn1 = (const float*)d_in[14];
    const float* prelu1 = (const float*)d_in[15];
    const float* conv2_w = (const float*)d_in[16];
    const float* bn2 = (const float*)d_in[17];
    const float* prelu2 = (const float*)d_in[18];
    float* out = (float*)d_out;
    float* ws = (float*)d_ws;

    const size_t S = (size_t)BB * LL * DD;        // 4,194,304 floats
    float* chH = ws;                              // [0, S)        f32
    float* chP = ws + S;                          // [S, 2S)       f32
    unsigned short* xmg = (unsigned short*)(ws + 2 * S);           // bf16 (B,L,128)
    unsigned short* zg = (unsigned short*)(ws + 2 * S + S / 2);    // bf16
    unsigned short* Yb = (unsigned short*)(ws + 3 * S);            // bf16
    float* Bc2 = ws + 3 * S + S / 2;              // S/8 floats
    float* Cc2 = Bc2 + S / 8;
    float* dtp = Cc2 + S / 8;                     // S/32
    unsigned short* img1t = (unsigned short*)ws;           // over chH, after s3
    unsigned short* img2t = (unsigned short*)(ws + S);     // over chP, after s2
    unsigned short* Wk1 = (unsigned short*)Bc2;            // over Bc2, after s3
    unsigned short* Wk2 = Wk1 + 36864;

    k_res<<<dim3(512), dim3(256), 0, stream>>>(x, res_w, res_bn, out);
    k_front<<<dim3(512), dim3(256), 0, stream>>>(x, in_proj_w, x_proj_w, conv1d_w, conv1d_b,
                                                 xmg, zg, Bc2, Cc2, dtp);
    k_s1<<<dim3(BB * 2 * NCH / 4), dim3(256), 0, stream>>>(xmg, Bc2, dtp, dt_proj_w, dt_proj_b,
                                                           A_log, chH, chP);
    k_s2<<<dim3(64), dim3(256), 0, stream>>>(chH, chP);
    k_s3<<<dim3(BB * 2 * NCH / 4), dim3(256), 0, stream>>>(xmg, zg, Bc2, Cc2, dtp, dt_proj_w, dt_proj_b,
                                                           A_log, Dp, chH, Yb);
    k_outproj<<<dim3(512), dim3(256), 0, stream>>>(Yb, out_proj_w, prelu_ssm, img1t);
    k_wprep<<<dim3(288), dim3(256), 0, stream>>>(conv1_w, conv2_w, Wk1, Wk2);
    k_conv3m<false><<<dim3(512), dim3(256), 0, stream>>>(img1t, Wk1, bn1, prelu1, img2t, nullptr);
    k_conv3m<true><<<dim3(512), dim3(256), 0, stream>>>(img2t, Wk2, bn2, prelu2, nullptr, out);
}

// Round 8
// 189.659 us; speedup vs baseline: 1.0743x; 1.0743x over previous
//
#include <hip/hip_runtime.h>
#include <hip/hip_bf16.h>

#define BB 8
#define CC 64
#define LL 4096
#define DD 128
#define NN 16
#define EPS 1e-5f
#define NCH 128
#define CLEN 32

typedef short short8 __attribute__((ext_vector_type(8)));
typedef unsigned short ushort8v __attribute__((ext_vector_type(8)));
typedef float f32x4 __attribute__((ext_vector_type(4)));

__device__ __forceinline__ float silu_f(float v) {
    return v / (1.f + __expf(-v));
}
__device__ __forceinline__ float softplus_f(float t) {
    return fmaxf(t, 0.f) + __logf(1.f + __expf(-fabsf(t)));
}
__device__ __forceinline__ unsigned short f2bf(float f) {
    unsigned int u = __float_as_uint(f);
    u += 0x7fff + ((u >> 16) & 1);
    return (unsigned short)(u >> 16);
}
__device__ __forceinline__ float bf2f(unsigned short u) {
    return __uint_as_float(((unsigned int)u) << 16);
}

// ---------------- K0: residual 1x1 conv + BN -> d_out  (4 oc-groups/wave) ----------------
__global__ __launch_bounds__(256) void k_res(const float* __restrict__ x,
                                             const float* __restrict__ rw,
                                             const float* __restrict__ rbn,
                                             float* __restrict__ out) {
    int blk = blockIdx.x;                       // 512
    int b = blk >> 6;
    int s = ((blk & 63) << 6) + (threadIdx.x & 63);
    int oc0 = __builtin_amdgcn_readfirstlane(threadIdx.x >> 6) * 16;
    const float* xb = x + (size_t)b * CC * LL;
    float xv[64];
#pragma unroll
    for (int ic = 0; ic < 64; ic++) xv[ic] = xb[ic * LL + s];
#pragma unroll
    for (int o = 0; o < 16; o++) {
        int oc = oc0 + o;
        const float* wr = rw + oc * 64;
        float acc = 0.f;
#pragma unroll
        for (int ic = 0; ic < 64; ic++) acc = fmaf(xv[ic], wr[ic], acc);
        float g = rbn[oc], be = rbn[64 + oc], m = rbn[128 + oc], v = rbn[192 + oc];
        float sc = g * rsqrtf(v + EPS);
        float sh = be - m * sc;
        out[((size_t)b * 64 + oc) * LL + s] = fmaf(acc, sc, sh);
    }
}

// ---------------- k_front: in_proj (MFMA) + conv1d + SiLU + x_proj (MFMA) fused ----------------
__global__ __launch_bounds__(256) void k_front(const float* __restrict__ x,
                                               const float* __restrict__ wip,
                                               const float* __restrict__ xw,
                                               const float* __restrict__ cw,
                                               const float* __restrict__ cb,
                                               unsigned short* __restrict__ xmg,
                                               unsigned short* __restrict__ zg,
                                               float* __restrict__ Bc2,
                                               float* __restrict__ Cc2,
                                               float* __restrict__ dtpO) {
    int blk = blockIdx.x;                        // 512 = B * (L/64)
    int b = blk >> 6;
    int l0 = (blk & 63) << 6;
    int tid = threadIdx.x;
    int lane = tid & 63;
    int wv = __builtin_amdgcn_readfirstlane(tid >> 6);
    int l15 = lane & 15, l4g = lane >> 4;

    __shared__ unsigned short xt[80 * 64];
    __shared__ unsigned short xmf[80 * 132];
    __shared__ unsigned short zf[64 * 132];
    __shared__ unsigned short xmc[64 * 128];

    for (int idx = tid; idx < 5120; idx += 256) {
        int c = idx / 80;
        int j = idx - c * 80;
        int l = l0 - 3 + j;
        float v = (l >= 0 && l < LL) ? x[((size_t)b * CC + c) * LL + l] : 0.f;
        xt[j * 64 + (((c >> 3) ^ (j & 7)) * 8) + (c & 7)] = f2bf(v);
    }

    short8 af[4][2];
#pragma unroll
    for (int m0 = 0; m0 < 4; m0++) {
        const float* wr = wip + (size_t)(wv * 64 + m0 * 16 + l15) * 64 + l4g * 8;
#pragma unroll
        for (int h = 0; h < 2; h++) {
            float4 a0 = *(const float4*)(wr + h * 32);
            float4 a1 = *(const float4*)(wr + h * 32 + 4);
            short8 f;
            f[0] = (short)f2bf(a0.x); f[1] = (short)f2bf(a0.y);
            f[2] = (short)f2bf(a0.z); f[3] = (short)f2bf(a0.w);
            f[4] = (short)f2bf(a1.x); f[5] = (short)f2bf(a1.y);
            f[6] = (short)f2bf(a1.z); f[7] = (short)f2bf(a1.w);
            af[m0][h] = f;
        }
    }
    __syncthreads();

    f32x4 acc[4][5];
#pragma unroll
    for (int m0 = 0; m0 < 4; m0++)
#pragma unroll
        for (int n0 = 0; n0 < 5; n0++) acc[m0][n0] = (f32x4){0.f, 0.f, 0.f, 0.f};
#pragma unroll
    for (int n0 = 0; n0 < 5; n0++) {
        int j = n0 * 16 + l15;
#pragma unroll
        for (int h = 0; h < 2; h++) {
            short8 bf = *(const short8*)(xt + j * 64 + (((h * 4 + l4g) ^ (j & 7)) * 8));
#pragma unroll
            for (int m0 = 0; m0 < 4; m0++)
                acc[m0][n0] = __builtin_amdgcn_mfma_f32_16x16x32_bf16(af[m0][h], bf, acc[m0][n0], 0, 0, 0);
        }
    }

#pragma unroll
    for (int m0 = 0; m0 < 4; m0++)
#pragma unroll
        for (int n0 = 0; n0 < 5; n0++) {
            int j = n0 * 16 + l15;
            int d = (wv & 1) * 64 + m0 * 16 + l4g * 4;
            ushort4 u = make_ushort4(f2bf(acc[m0][n0][0]), f2bf(acc[m0][n0][1]),
                                     f2bf(acc[m0][n0][2]), f2bf(acc[m0][n0][3]));
            if (wv < 2) {
                *(ushort4*)(xmf + j * 132 + d) = u;
            } else {
                int t = j - 3;
                if (t >= 0 && t < 64) *(ushort4*)(zf + t * 132 + d) = u;
            }
        }
    __syncthreads();

    {
        int d4 = (tid & 31) * 4;
        int tok0 = (tid >> 5) * 8;
        float4 w0 = *(const float4*)(cw + (d4 + 0) * 4);
        float4 w1 = *(const float4*)(cw + (d4 + 1) * 4);
        float4 w2 = *(const float4*)(cw + (d4 + 2) * 4);
        float4 w3 = *(const float4*)(cw + (d4 + 3) * 4);
        float4 cb4 = *(const float4*)(cb + d4);
        size_t gbase = (size_t)b * LL + l0;
        int kc = d4 >> 3;
#pragma unroll
        for (int tt = 0; tt < 8; tt++) {
            int tok = tok0 + tt;
            ushort4 r0 = *(const ushort4*)(xmf + (tok + 0) * 132 + d4);
            ushort4 r1 = *(const ushort4*)(xmf + (tok + 1) * 132 + d4);
            ushort4 r2 = *(const ushort4*)(xmf + (tok + 2) * 132 + d4);
            ushort4 r3 = *(const ushort4*)(xmf + (tok + 3) * 132 + d4);
            float v0 = cb4.x + w0.x * bf2f(r0.x) + w0.y * bf2f(r1.x) + w0.z * bf2f(r2.x) + w0.w * bf2f(r3.x);
            float v1 = cb4.y + w1.x * bf2f(r0.y) + w1.y * bf2f(r1.y) + w1.z * bf2f(r2.y) + w1.w * bf2f(r3.y);
            float v2 = cb4.z + w2.x * bf2f(r0.z) + w2.y * bf2f(r1.z) + w2.z * bf2f(r2.z) + w2.w * bf2f(r3.z);
            float v3 = cb4.w + w3.x * bf2f(r0.w) + w3.y * bf2f(r1.w) + w3.z * bf2f(r2.w) + w3.w * bf2f(r3.w);
            ushort4 o = make_ushort4(f2bf(silu_f(v0)), f2bf(silu_f(v1)), f2bf(silu_f(v2)), f2bf(silu_f(v3)));
            *(ushort4*)(xmg + (gbase + tok) * 128 + d4) = o;
            *(ushort4*)(xmc + tok * 128 + ((kc ^ (tok & 7)) * 8) + (d4 & 4)) = o;
            ushort4 zv = *(const ushort4*)(zf + tok * 132 + d4);
            *(ushort4*)(zg + (gbase + tok) * 128 + d4) = zv;
        }
    }
    __syncthreads();

    short8 pa_[3][4];
#pragma unroll
    for (int mt = 0; mt < 3; mt++) {
        int j = mt * 16 + l15;
#pragma unroll
        for (int ks = 0; ks < 4; ks++) {
            short8 f = {0, 0, 0, 0, 0, 0, 0, 0};
            if (j < 36) {
                const float* wr = xw + (size_t)j * 128 + ks * 32 + l4g * 8;
                float4 a0 = *(const float4*)(wr);
                float4 a1 = *(const float4*)(wr + 4);
                f[0] = (short)f2bf(a0.x); f[1] = (short)f2bf(a0.y);
                f[2] = (short)f2bf(a0.z); f[3] = (short)f2bf(a0.w);
                f[4] = (short)f2bf(a1.x); f[5] = (short)f2bf(a1.y);
                f[6] = (short)f2bf(a1.z); f[7] = (short)f2bf(a1.w);
            }
            pa_[mt][ks] = f;
        }
    }
    int t = wv * 16 + l15;
    f32x4 a3[3];
#pragma unroll
    for (int mt = 0; mt < 3; mt++) a3[mt] = (f32x4){0.f, 0.f, 0.f, 0.f};
#pragma unroll
    for (int ks = 0; ks < 4; ks++) {
        short8 bf = *(const short8*)(xmc + t * 128 + (((ks * 4 + l4g) ^ (t & 7)) * 8));
#pragma unroll
        for (int mt = 0; mt < 3; mt++)
            a3[mt] = __builtin_amdgcn_mfma_f32_16x16x32_bf16(pa_[mt][ks], bf, a3[mt], 0, 0, 0);
    }
    size_t bl = (size_t)b * LL + l0 + t;
    float4 o0 = make_float4(a3[0][0], a3[0][1], a3[0][2], a3[0][3]);
    float4 o1 = make_float4(a3[1][0], a3[1][1], a3[1][2], a3[1][3]);
    float4 o2 = make_float4(a3[2][0], a3[2][1], a3[2][2], a3[2][3]);
    if (l4g == 0) {
        *(float4*)(dtpO + bl * 4) = o0;
        *(float4*)(Bc2 + bl * 16 + 12) = o1;
        *(float4*)(Cc2 + bl * 16 + 12) = o2;
    } else {
        *(float4*)(Bc2 + bl * 16 + (l4g - 1) * 4) = o0;
        *(float4*)(Cc2 + bl * 16 + (l4g - 1) * 4) = o1;
    }
}

// ---------------- k_dt: dt = softplus(dtp @ dtw^T + dtb) -> f32 (B,L,128) ----------------
__global__ __launch_bounds__(256) void k_dt(const float* __restrict__ dtpI,
                                            const float* __restrict__ dtw,
                                            const float* __restrict__ dtb,
                                            float* __restrict__ dtg) {
    int gid = blockIdx.x * 256 + threadIdx.x;    // B*L*32
    int bl = gid >> 5;
    int d0 = (gid & 31) * 4;
    float4 q = *(const float4*)(dtpI + (size_t)bl * 4);
    float4 w0 = *(const float4*)(dtw + (d0 + 0) * 4);
    float4 w1 = *(const float4*)(dtw + (d0 + 1) * 4);
    float4 w2 = *(const float4*)(dtw + (d0 + 2) * 4);
    float4 w3 = *(const float4*)(dtw + (d0 + 3) * 4);
    float4 b4 = *(const float4*)(dtb + d0);
    float4 o;
    o.x = softplus_f(b4.x + q.x * w0.x + q.y * w0.y + q.z * w0.z + q.w * w0.w);
    o.y = softplus_f(b4.y + q.x * w1.x + q.y * w1.y + q.z * w1.z + q.w * w1.w);
    o.z = softplus_f(b4.z + q.x * w2.x + q.y * w2.y + q.z * w2.z + q.w * w2.w);
    o.w = softplus_f(b4.w + q.x * w3.x + q.y * w3.y + q.z * w3.z + q.w * w3.w);
    *(float4*)(dtg + (size_t)bl * 128 + d0) = o;
}

// ---------------- Scan pass 1: block = 2 chunks x 2 d-halves; B staged in LDS ----------------
__global__ __launch_bounds__(256) void k_s1(const unsigned short* __restrict__ xmg,
                                            const float* __restrict__ Bc2,
                                            const float* __restrict__ dtg,
                                            const float* __restrict__ A_log,
                                            float* __restrict__ chH,
                                            float* __restrict__ chP) {
    int b = blockIdx.x >> 6;                     // 512 blocks = B * 64 chunk-pairs
    int ckp = blockIdx.x & 63;
    int w = threadIdx.x >> 6;
    int lane = threadIdx.x & 63;
    int ck = ckp * 2 + (w >> 1);
    int dh = w & 1;
    int d = dh * 64 + lane;

    __shared__ float sB[64][16];
    {
        int l = threadIdx.x >> 2, q = threadIdx.x & 3;
        *(float4*)(&sB[l][q * 4]) = *(const float4*)(Bc2 + ((size_t)b * LL + ckp * 64 + l) * 16 + q * 4);
    }

    float a2[16];
#pragma unroll
    for (int j = 0; j < 4; j++) {
        float4 v = *(const float4*)(A_log + d * 16 + j * 4);
        a2[j * 4 + 0] = -__expf(v.x) * 1.4426950408889634f;
        a2[j * 4 + 1] = -__expf(v.y) * 1.4426950408889634f;
        a2[j * 4 + 2] = -__expf(v.z) * 1.4426950408889634f;
        a2[j * 4 + 3] = -__expf(v.w) * 1.4426950408889634f;
    }
    float h[16];
#pragma unroll
    for (int n = 0; n < 16; n++) h[n] = 0.f;
    float sdt = 0.f;
    size_t bl0 = (size_t)b * LL + ck * CLEN;
    const unsigned short* xmp = xmg + bl0 * DD + d;
    const float* dtp_ = dtg + bl0 * DD + d;
    int lb = (w >> 1) * 32;                      // local token base in sB
    __syncthreads();
#pragma unroll 4
    for (int t = 0; t < CLEN; t++) {
        float xmv = bf2f(xmp[(size_t)t * DD]);
        float dtv = dtp_[(size_t)t * DD];
        float dx = dtv * xmv;
        const float* Br = &sB[lb + t][0];
        sdt += dtv;
#pragma unroll
        for (int n = 0; n < 16; n++) {
            float dA = exp2f(dtv * a2[n]);
            h[n] = fmaf(dA, h[n], dx * Br[n]);
        }
    }
    size_t cbase = ((size_t)((b * 2 + dh) * NCH + ck)) * 1024 + lane * 16;
#pragma unroll
    for (int j = 0; j < 4; j++) {
        *(float4*)(chH + cbase + j * 4) = make_float4(h[j * 4], h[j * 4 + 1], h[j * 4 + 2], h[j * 4 + 3]);
        *(float4*)(chP + cbase + j * 4) = make_float4(exp2f(a2[j * 4] * sdt), exp2f(a2[j * 4 + 1] * sdt),
                                                      exp2f(a2[j * 4 + 2] * sdt), exp2f(a2[j * 4 + 3] * sdt));
    }
}

// ---------------- Scan pass 2: 16384 scalar recurrences over 128 chunks ----------------
__global__ __launch_bounds__(64) void k_s2(float* __restrict__ chH,
                                           const float* __restrict__ chP) {
    int t = blockIdx.x * 64 + threadIdx.x;   // 0..16383
    int row = t >> 10;
    int q = t & 1023;
    size_t base = (size_t)row * NCH * 1024 + q;
    float H = 0.f;
#pragma unroll 8
    for (int ck = 0; ck < NCH; ck++) {
        size_t a = base + (size_t)ck * 1024;
        float h = chH[a];
        float p = chP[a];
        chH[a] = H;
        H = fmaf(p, H, h);
    }
}

// ---------------- Scan pass 3: block = 2 chunks x 2 d-halves; B,C staged in LDS ----------------
__global__ __launch_bounds__(256) void k_s3(const unsigned short* __restrict__ xmg,
                                            const unsigned short* __restrict__ zg,
                                            const float* __restrict__ Bc2,
                                            const float* __restrict__ Cc2,
                                            const float* __restrict__ dtg,
                                            const float* __restrict__ A_log,
                                            const float* __restrict__ Dpp,
                                            const float* __restrict__ hinit,
                                            unsigned short* __restrict__ Y) {
    int b = blockIdx.x >> 6;
    int ckp = blockIdx.x & 63;
    int w = threadIdx.x >> 6;
    int lane = threadIdx.x & 63;
    int ck = ckp * 2 + (w >> 1);
    int dh = w & 1;
    int d = dh * 64 + lane;

    __shared__ float sB[64][16];
    __shared__ float sC[64][16];
    {
        int l = threadIdx.x >> 2, q = threadIdx.x & 3;
        *(float4*)(&sB[l][q * 4]) = *(const float4*)(Bc2 + ((size_t)b * LL + ckp * 64 + l) * 16 + q * 4);
        *(float4*)(&sC[l][q * 4]) = *(const float4*)(Cc2 + ((size_t)b * LL + ckp * 64 + l) * 16 + q * 4);
    }

    float a2[16];
#pragma unroll
    for (int j = 0; j < 4; j++) {
        float4 v = *(const float4*)(A_log + d * 16 + j * 4);
        a2[j * 4 + 0] = -__expf(v.x) * 1.4426950408889634f;
        a2[j * 4 + 1] = -__expf(v.y) * 1.4426950408889634f;
        a2[j * 4 + 2] = -__expf(v.z) * 1.4426950408889634f;
        a2[j * 4 + 3] = -__expf(v.w) * 1.4426950408889634f;
    }
    float Dpd = Dpp[d];
    size_t cbase = ((size_t)((b * 2 + dh) * NCH + ck)) * 1024 + lane * 16;
    float h[16];
#pragma unroll
    for (int j = 0; j < 4; j++) {
        float4 v = *(const float4*)(hinit + cbase + j * 4);
        h[j * 4 + 0] = v.x; h[j * 4 + 1] = v.y; h[j * 4 + 2] = v.z; h[j * 4 + 3] = v.w;
    }
    size_t bl0 = (size_t)b * LL + ck * CLEN;
    const unsigned short* xmp = xmg + bl0 * DD + d;
    const unsigned short* zp = zg + bl0 * DD + d;
    const float* dtp_ = dtg + bl0 * DD + d;
    unsigned short* Yp = Y + bl0 * DD + d;
    int lb = (w >> 1) * 32;
    __syncthreads();
#pragma unroll 4
    for (int t = 0; t < CLEN; t++) {
        float xmv = bf2f(xmp[(size_t)t * DD]);
        float zv = bf2f(zp[(size_t)t * DD]);
        float dtv = dtp_[(size_t)t * DD];
        float dx = dtv * xmv;
        const float* Br = &sB[lb + t][0];
        const float* Cr = &sC[lb + t][0];
        float y0 = 0.f, y1 = 0.f, y2 = 0.f, y3 = 0.f;
#pragma unroll
        for (int n = 0; n < 16; n += 4) {
            float dA0 = exp2f(dtv * a2[n]);
            float dA1 = exp2f(dtv * a2[n + 1]);
            float dA2 = exp2f(dtv * a2[n + 2]);
            float dA3 = exp2f(dtv * a2[n + 3]);
            h[n] = fmaf(dA0, h[n], dx * Br[n]);
            h[n + 1] = fmaf(dA1, h[n + 1], dx * Br[n + 1]);
            h[n + 2] = fmaf(dA2, h[n + 2], dx * Br[n + 2]);
            h[n + 3] = fmaf(dA3, h[n + 3], dx * Br[n + 3]);
            y0 = fmaf(h[n], Cr[n], y0);
            y1 = fmaf(h[n + 1], Cr[n + 1], y1);
            y2 = fmaf(h[n + 2], Cr[n + 2], y2);
            y3 = fmaf(h[n + 3], Cr[n + 3], y3);
        }
        float yv = (y0 + y1) + (y2 + y3);
        yv = fmaf(xmv, Dpd, yv);
        Yp[(size_t)t * DD] = f2bf(yv * silu_f(zv));
    }
}

// ---------------- K4: out_proj + PReLU -> img1t bf16 [b][p*64+q][64]  (4 oc-groups/wave) ----------------
__global__ __launch_bounds__(256) void k_outproj(const unsigned short* __restrict__ Y,
                                                 const float* __restrict__ wo,
                                                 const float* __restrict__ pre,
                                                 unsigned short* __restrict__ img1t) {
    int blk = blockIdx.x;                        // 512
    int bl = (blk << 6) + (threadIdx.x & 63);
    int oc0 = __builtin_amdgcn_readfirstlane(threadIdx.x >> 6) * 16;
    const unsigned short* yr = Y + (size_t)bl * DD;
    float acc[16];
#pragma unroll
    for (int o = 0; o < 16; o++) acc[o] = 0.f;
    for (int c8 = 0; c8 < 8; c8++) {
        ushort8v u0 = *(const ushort8v*)(yr + c8 * 16);
        ushort8v u1 = *(const ushort8v*)(yr + c8 * 16 + 8);
        float xv[16];
#pragma unroll
        for (int j = 0; j < 8; j++) { xv[j] = bf2f(u0[j]); xv[8 + j] = bf2f(u1[j]); }
#pragma unroll
        for (int o = 0; o < 16; o++) {
            const float* wr = wo + (size_t)(oc0 + o) * DD + c8 * 16;
            float a = acc[o];
#pragma unroll
            for (int j = 0; j < 16; j++) a = fmaf(xv[j], wr[j], a);
            acc[o] = a;
        }
    }
    float pa = pre[0];
    int b = bl >> 12, l = bl & 4095;
    int px = (l & 63) * 64 + (l >> 6);           // (p = l%64, q = l/64)
    unsigned short* dst = img1t + ((size_t)b * 4096 + px) * 64 + oc0;
#pragma unroll
    for (int g8 = 0; g8 < 2; g8++) {
        ushort8v w;
#pragma unroll
        for (int j = 0; j < 8; j++) {
            float v = acc[g8 * 8 + j];
            v = v >= 0.f ? v : pa * v;
            w[j] = f2bf(v);
        }
        *(ushort8v*)(dst + g8 * 8) = w;
    }
}

// ---------------- weight prep: Wk[oc][shift*64+ic] bf16 for both 3x3 convs ----------------
__global__ __launch_bounds__(256) void k_wprep(const float* __restrict__ w1,
                                               const float* __restrict__ w2,
                                               unsigned short* __restrict__ Wk1,
                                               unsigned short* __restrict__ Wk2) {
    int idx = blockIdx.x * 256 + threadIdx.x;
    if (idx >= 2 * 36864) return;
    const float* w = (idx < 36864) ? w1 : w2;
    unsigned short* dst = (idx < 36864) ? Wk1 : Wk2;
    int r = (idx < 36864) ? idx : idx - 36864;
    int oc = r / 576, k = r % 576;
    int shift = k >> 6, ic = k & 63;
    dst[oc * 576 + k] = f2bf(w[(oc * 64 + ic) * 9 + shift]);
}

// ---------------- K5/K6: 3x3 conv via MFMA bf16 + BN + PReLU (+residual) ----------------
template <bool FINAL>
__global__ __launch_bounds__(256) void k_conv3m(const unsigned short* __restrict__ in_t,
                                                const unsigned short* __restrict__ Wk,
                                                const float* __restrict__ bnp,
                                                const float* __restrict__ pre,
                                                unsigned short* __restrict__ out_t,
                                                float* __restrict__ outf) {
    int bid = blockIdx.x;
    int b = bid >> 6;
    int p = bid & 63;
    int tid = threadIdx.x;
    int lane = tid & 63;
    int wv = tid >> 6;
    int oc0 = __builtin_amdgcn_readfirstlane(wv * 16);
    __shared__ unsigned short lds[3 * 66 * 64];

    short8 afrag[18];
    const unsigned short* wrow = Wk + (size_t)(oc0 + (lane & 15)) * 576 + ((lane >> 4) * 8);
#pragma unroll
    for (int s = 0; s < 18; s++) afrag[s] = *(const short8*)(wrow + s * 32);

    const unsigned short* ib = in_t + (size_t)b * 4096 * 64;
    for (int idx = tid; idx < 1584; idx += 256) {
        int pair = idx >> 3, c = idx & 7;
        int di = pair / 66, col = pair % 66;
        int r = p - 1 + di, q = col - 1;
        ushort8v v = {0, 0, 0, 0, 0, 0, 0, 0};
        if (r >= 0 && r < 64 && q >= 0 && q < 64)
            v = *(const ushort8v*)(ib + ((size_t)(r * 64 + q)) * 64 + c * 8);
        *(ushort8v*)(lds + pair * 64 + ((c ^ (col & 7)) * 8)) = v;
    }
    __syncthreads();

    f32x4 acc[4];
#pragma unroll
    for (int n0 = 0; n0 < 4; n0++) acc[n0] = (f32x4){0.f, 0.f, 0.f, 0.f};
#pragma unroll
    for (int s = 0; s < 18; s++) {
        const int shift = s >> 1, h = s & 1;
        const int di = shift / 3, dj = shift % 3;
#pragma unroll
        for (int n0 = 0; n0 < 4; n0++) {
            int col = n0 * 16 + (lane & 15) + dj;
            int off = (di * 66 + col) * 64 + (((h * 4 + (lane >> 4)) ^ (col & 7)) * 8);
            short8 bfrag = *(const short8*)(lds + off);
            acc[n0] = __builtin_amdgcn_mfma_f32_16x16x32_bf16(afrag[s], bfrag, acc[n0], 0, 0, 0);
        }
    }

    int ocb = oc0 + ((lane >> 4) << 2);
    float4 g4 = *(const float4*)(bnp + ocb);
    float4 be4 = *(const float4*)(bnp + 64 + ocb);
    float4 m4 = *(const float4*)(bnp + 128 + ocb);
    float4 v4 = *(const float4*)(bnp + 192 + ocb);
    float sc[4], sh[4];
    sc[0] = g4.x * rsqrtf(v4.x + EPS); sh[0] = be4.x - m4.x * sc[0];
    sc[1] = g4.y * rsqrtf(v4.y + EPS); sh[1] = be4.y - m4.y * sc[1];
    sc[2] = g4.z * rsqrtf(v4.z + EPS); sh[2] = be4.z - m4.z * sc[2];
    sc[3] = g4.w * rsqrtf(v4.w + EPS); sh[3] = be4.w - m4.w * sc[3];
    float pa = pre[0];
#pragma unroll
    for (int n0 = 0; n0 < 4; n0++) {
        int q = n0 * 16 + (lane & 15);
        float vals[4];
#pragma unroll
        for (int r = 0; r < 4; r++) {
            float v = fmaf(acc[n0][r], sc[r], sh[r]);
            vals[r] = v >= 0.f ? v : pa * v;
        }
        if (FINAL) {
#pragma unroll
            for (int r = 0; r < 4; r++) {
                size_t addr = ((size_t)b * 64 + ocb + r) * 4096 + p * 64 + q;
                outf[addr] = vals[r] + outf[addr];
            }
        } else {
            ushort4 u = make_ushort4(f2bf(vals[0]), f2bf(vals[1]), f2bf(vals[2]), f2bf(vals[3]));
            *(ushort4*)(out_t + ((size_t)b * 4096 + p * 64 + q) * 64 + ocb) = u;
        }
    }
}

extern "C" void kernel_launch(void* const* d_in, const int* in_sizes, int n_in,
                              void* d_out, int out_size, void* d_ws, size_t ws_size,
                              hipStream_t stream) {
    const float* x = (const float*)d_in[0];
    const float* in_proj_w = (const float*)d_in[1];
    const float* conv1d_w = (const float*)d_in[2];
    const float* conv1d_b = (const float*)d_in[3];
    const float* x_proj_w = (const float*)d_in[4];
    const float* dt_proj_w = (const float*)d_in[5];
    const float* dt_proj_b = (const float*)d_in[6];
    const float* A_log = (const float*)d_in[7];
    const float* Dp = (const float*)d_in[8];
    const float* out_proj_w = (const float*)d_in[9];
    const float* prelu_ssm = (const float*)d_in[10];
    const float* res_w = (const float*)d_in[11];
    const float* res_bn = (const float*)d_in[12];
    const float* conv1_w = (const float*)d_in[13];
    const float* bn1 = (const float*)d_in[14];
    const float* prelu1 = (const float*)d_in[15];
    const float* conv2_w = (const float*)d_in[16];
    const float* bn2 = (const float*)d_in[17];
    const float* prelu2 = (const float*)d_in[18];
    float* out = (float*)d_out;
    float* ws = (float*)d_ws;

    const size_t S = (size_t)BB * LL * DD;        // 4,194,304 floats
    const size_t HALF = S / 2;
    float* chH = ws;                              // [0, HALF)
    float* chP = ws + HALF;                       // [HALF, S)
    unsigned short* xmg = (unsigned short*)(ws + S);              // bf16, S/2 floats
    unsigned short* zg = (unsigned short*)(ws + S + HALF);        // bf16
    float* dtg = ws + 2 * S;                      // f32 (B,L,128), S floats
    unsigned short* Yb = (unsigned short*)(ws + 3 * S);           // bf16, S/2 floats
    float* Bc2 = ws + 3 * S + HALF;               // S/8
    float* Cc2 = Bc2 + S / 8;                     // S/8
    float* dtp = Cc2 + S / 8;                     // S/32
    unsigned short* img1t = (unsigned short*)ws;            // over chH, after s3
    unsigned short* img2t = (unsigned short*)(ws + HALF);   // over chP, after s2
    unsigned short* Wk1 = (unsigned short*)Bc2;             // over Bc2, after s3
    unsigned short* Wk2 = Wk1 + 36864;

    k_res<<<dim3(512), dim3(256), 0, stream>>>(x, res_w, res_bn, out);
    k_front<<<dim3(512), dim3(256), 0, stream>>>(x, in_proj_w, x_proj_w, conv1d_w, conv1d_b,
                                                 xmg, zg, Bc2, Cc2, dtp);
    k_dt<<<dim3(4096), dim3(256), 0, stream>>>(dtp, dt_proj_w, dt_proj_b, dtg);
    k_s1<<<dim3(512), dim3(256), 0, stream>>>(xmg, Bc2, dtg, A_log, chH, chP);
    k_s2<<<dim3(256), dim3(64), 0, stream>>>(chH, chP);
    k_s3<<<dim3(512), dim3(256), 0, stream>>>(xmg, zg, Bc2, Cc2, dtg, A_log, Dp, chH, Yb);
    k_outproj<<<dim3(512), dim3(256), 0, stream>>>(Yb, out_proj_w, prelu_ssm, img1t);
    k_wprep<<<dim3(288), dim3(256), 0, stream>>>(conv1_w, conv2_w, Wk1, Wk2);
    k_conv3m<false><<<dim3(512), dim3(256), 0, stream>>>(img1t, Wk1, bn1, prelu1, img2t, nullptr);
    k_conv3m<true><<<dim3(512), dim3(256), 0, stream>>>(img2t, Wk2, bn2, prelu2, nullptr, out);
}

// Round 9
// 185.865 us; speedup vs baseline: 1.0963x; 1.0204x over previous
//
#include <hip/hip_runtime.h>
#include <hip/hip_bf16.h>

#define BB 8
#define CC 64
#define LL 4096
#define DD 128
#define NN 16
#define EPS 1e-5f
#define NCH 128
#define CLEN 32

typedef short short8 __attribute__((ext_vector_type(8)));
typedef unsigned short ushort8v __attribute__((ext_vector_type(8)));
typedef float f32x4 __attribute__((ext_vector_type(4)));

__device__ __forceinline__ float silu_f(float v) {
    return v / (1.f + __expf(-v));
}
__device__ __forceinline__ float softplus_f(float t) {
    return fmaxf(t, 0.f) + __logf(1.f + __expf(-fabsf(t)));
}
__device__ __forceinline__ unsigned short f2bf(float f) {
    unsigned int u = __float_as_uint(f);
    u += 0x7fff + ((u >> 16) & 1);
    return (unsigned short)(u >> 16);
}
__device__ __forceinline__ float bf2f(unsigned short u) {
    return __uint_as_float(((unsigned int)u) << 16);
}

// ---------------- K0: residual 1x1 conv + BN -> d_out  (4 oc-groups/wave) ----------------
__global__ __launch_bounds__(256) void k_res(const float* __restrict__ x,
                                             const float* __restrict__ rw,
                                             const float* __restrict__ rbn,
                                             float* __restrict__ out) {
    int blk = blockIdx.x;                       // 512
    int b = blk >> 6;
    int s = ((blk & 63) << 6) + (threadIdx.x & 63);
    int oc0 = __builtin_amdgcn_readfirstlane(threadIdx.x >> 6) * 16;
    const float* xb = x + (size_t)b * CC * LL;
    float xv[64];
#pragma unroll
    for (int ic = 0; ic < 64; ic++) xv[ic] = xb[ic * LL + s];
#pragma unroll
    for (int o = 0; o < 16; o++) {
        int oc = oc0 + o;
        const float* wr = rw + oc * 64;
        float acc = 0.f;
#pragma unroll
        for (int ic = 0; ic < 64; ic++) acc = fmaf(xv[ic], wr[ic], acc);
        float g = rbn[oc], be = rbn[64 + oc], m = rbn[128 + oc], v = rbn[192 + oc];
        float sc = g * rsqrtf(v + EPS);
        float sh = be - m * sc;
        out[((size_t)b * 64 + oc) * LL + s] = fmaf(acc, sc, sh);
    }
}

// ---------------- k_front: in_proj (MFMA) + conv1d + SiLU + x_proj (MFMA) + dt fused ----------------
__global__ __launch_bounds__(256) void k_front(const float* __restrict__ x,
                                               const float* __restrict__ wip,
                                               const float* __restrict__ xw,
                                               const float* __restrict__ cw,
                                               const float* __restrict__ cb,
                                               const float* __restrict__ dtw,
                                               const float* __restrict__ dtb,
                                               unsigned short* __restrict__ xmg,
                                               unsigned short* __restrict__ zg,
                                               float* __restrict__ Bc2,
                                               float* __restrict__ Cc2,
                                               float* __restrict__ dtg) {
    int blk = blockIdx.x;                        // 512 = B * (L/64)
    int b = blk >> 6;
    int l0 = (blk & 63) << 6;
    int tid = threadIdx.x;
    int lane = tid & 63;
    int wv = __builtin_amdgcn_readfirstlane(tid >> 6);
    int l15 = lane & 15, l4g = lane >> 4;

    __shared__ unsigned short xt[80 * 64];
    __shared__ unsigned short xmf[80 * 132];     // later reused: first 256 floats = sdtp
    __shared__ unsigned short zf[64 * 132];
    __shared__ unsigned short xmc[64 * 128];
    float* sdtp = (float*)xmf;

    for (int idx = tid; idx < 5120; idx += 256) {
        int c = idx / 80;
        int j = idx - c * 80;
        int l = l0 - 3 + j;
        float v = (l >= 0 && l < LL) ? x[((size_t)b * CC + c) * LL + l] : 0.f;
        xt[j * 64 + (((c >> 3) ^ (j & 7)) * 8) + (c & 7)] = f2bf(v);
    }

    short8 af[4][2];
#pragma unroll
    for (int m0 = 0; m0 < 4; m0++) {
        const float* wr = wip + (size_t)(wv * 64 + m0 * 16 + l15) * 64 + l4g * 8;
#pragma unroll
        for (int h = 0; h < 2; h++) {
            float4 a0 = *(const float4*)(wr + h * 32);
            float4 a1 = *(const float4*)(wr + h * 32 + 4);
            short8 f;
            f[0] = (short)f2bf(a0.x); f[1] = (short)f2bf(a0.y);
            f[2] = (short)f2bf(a0.z); f[3] = (short)f2bf(a0.w);
            f[4] = (short)f2bf(a1.x); f[5] = (short)f2bf(a1.y);
            f[6] = (short)f2bf(a1.z); f[7] = (short)f2bf(a1.w);
            af[m0][h] = f;
        }
    }
    __syncthreads();

    f32x4 acc[4][5];
#pragma unroll
    for (int m0 = 0; m0 < 4; m0++)
#pragma unroll
        for (int n0 = 0; n0 < 5; n0++) acc[m0][n0] = (f32x4){0.f, 0.f, 0.f, 0.f};
#pragma unroll
    for (int n0 = 0; n0 < 5; n0++) {
        int j = n0 * 16 + l15;
#pragma unroll
        for (int h = 0; h < 2; h++) {
            short8 bf = *(const short8*)(xt + j * 64 + (((h * 4 + l4g) ^ (j & 7)) * 8));
#pragma unroll
            for (int m0 = 0; m0 < 4; m0++)
                acc[m0][n0] = __builtin_amdgcn_mfma_f32_16x16x32_bf16(af[m0][h], bf, acc[m0][n0], 0, 0, 0);
        }
    }

#pragma unroll
    for (int m0 = 0; m0 < 4; m0++)
#pragma unroll
        for (int n0 = 0; n0 < 5; n0++) {
            int j = n0 * 16 + l15;
            int d = (wv & 1) * 64 + m0 * 16 + l4g * 4;
            ushort4 u = make_ushort4(f2bf(acc[m0][n0][0]), f2bf(acc[m0][n0][1]),
                                     f2bf(acc[m0][n0][2]), f2bf(acc[m0][n0][3]));
            if (wv < 2) {
                *(ushort4*)(xmf + j * 132 + d) = u;
            } else {
                int t = j - 3;
                if (t >= 0 && t < 64) *(ushort4*)(zf + t * 132 + d) = u;
            }
        }
    __syncthreads();

    {
        int d4 = (tid & 31) * 4;
        int tok0 = (tid >> 5) * 8;
        float4 w0 = *(const float4*)(cw + (d4 + 0) * 4);
        float4 w1 = *(const float4*)(cw + (d4 + 1) * 4);
        float4 w2 = *(const float4*)(cw + (d4 + 2) * 4);
        float4 w3 = *(const float4*)(cw + (d4 + 3) * 4);
        float4 cb4 = *(const float4*)(cb + d4);
        size_t gbase = (size_t)b * LL + l0;
        int kc = d4 >> 3;
#pragma unroll
        for (int tt = 0; tt < 8; tt++) {
            int tok = tok0 + tt;
            ushort4 r0 = *(const ushort4*)(xmf + (tok + 0) * 132 + d4);
            ushort4 r1 = *(const ushort4*)(xmf + (tok + 1) * 132 + d4);
            ushort4 r2 = *(const ushort4*)(xmf + (tok + 2) * 132 + d4);
            ushort4 r3 = *(const ushort4*)(xmf + (tok + 3) * 132 + d4);
            float v0 = cb4.x + w0.x * bf2f(r0.x) + w0.y * bf2f(r1.x) + w0.z * bf2f(r2.x) + w0.w * bf2f(r3.x);
            float v1 = cb4.y + w1.x * bf2f(r0.y) + w1.y * bf2f(r1.y) + w1.z * bf2f(r2.y) + w1.w * bf2f(r3.y);
            float v2 = cb4.z + w2.x * bf2f(r0.z) + w2.y * bf2f(r1.z) + w2.z * bf2f(r2.z) + w2.w * bf2f(r3.z);
            float v3 = cb4.w + w3.x * bf2f(r0.w) + w3.y * bf2f(r1.w) + w3.z * bf2f(r2.w) + w3.w * bf2f(r3.w);
            ushort4 o = make_ushort4(f2bf(silu_f(v0)), f2bf(silu_f(v1)), f2bf(silu_f(v2)), f2bf(silu_f(v3)));
            *(ushort4*)(xmg + (gbase + tok) * 128 + d4) = o;
            *(ushort4*)(xmc + tok * 128 + ((kc ^ (tok & 7)) * 8) + (d4 & 4)) = o;
            ushort4 zv = *(const ushort4*)(zf + tok * 132 + d4);
            *(ushort4*)(zg + (gbase + tok) * 128 + d4) = zv;
        }
    }
    __syncthreads();

    short8 pa_[3][4];
#pragma unroll
    for (int mt = 0; mt < 3; mt++) {
        int j = mt * 16 + l15;
#pragma unroll
        for (int ks = 0; ks < 4; ks++) {
            short8 f = {0, 0, 0, 0, 0, 0, 0, 0};
            if (j < 36) {
                const float* wr = xw + (size_t)j * 128 + ks * 32 + l4g * 8;
                float4 a0 = *(const float4*)(wr);
                float4 a1 = *(const float4*)(wr + 4);
                f[0] = (short)f2bf(a0.x); f[1] = (short)f2bf(a0.y);
                f[2] = (short)f2bf(a0.z); f[3] = (short)f2bf(a0.w);
                f[4] = (short)f2bf(a1.x); f[5] = (short)f2bf(a1.y);
                f[6] = (short)f2bf(a1.z); f[7] = (short)f2bf(a1.w);
            }
            pa_[mt][ks] = f;
        }
    }
    int t = wv * 16 + l15;
    f32x4 a3[3];
#pragma unroll
    for (int mt = 0; mt < 3; mt++) a3[mt] = (f32x4){0.f, 0.f, 0.f, 0.f};
#pragma unroll
    for (int ks = 0; ks < 4; ks++) {
        short8 bf = *(const short8*)(xmc + t * 128 + (((ks * 4 + l4g) ^ (t & 7)) * 8));
#pragma unroll
        for (int mt = 0; mt < 3; mt++)
            a3[mt] = __builtin_amdgcn_mfma_f32_16x16x32_bf16(pa_[mt][ks], bf, a3[mt], 0, 0, 0);
    }
    size_t bl = (size_t)b * LL + l0 + t;
    float4 o0 = make_float4(a3[0][0], a3[0][1], a3[0][2], a3[0][3]);
    float4 o1 = make_float4(a3[1][0], a3[1][1], a3[1][2], a3[1][3]);
    float4 o2 = make_float4(a3[2][0], a3[2][1], a3[2][2], a3[2][3]);
    if (l4g == 0) {
        *(float4*)(sdtp + t * 4) = o0;               // dtp -> LDS
        *(float4*)(Bc2 + bl * 16 + 12) = o1;
        *(float4*)(Cc2 + bl * 16 + 12) = o2;
    } else {
        *(float4*)(Bc2 + bl * 16 + (l4g - 1) * 4) = o0;
        *(float4*)(Cc2 + bl * 16 + (l4g - 1) * 4) = o1;
    }
    __syncthreads();

    // ---- dt = softplus(dtp @ dtw^T + dtb) for the 64 tokens, all 128 d ----
    {
        int d4 = (tid & 31) * 4;
        int tok0 = (tid >> 5) * 8;
        float4 w0 = *(const float4*)(dtw + (d4 + 0) * 4);
        float4 w1 = *(const float4*)(dtw + (d4 + 1) * 4);
        float4 w2 = *(const float4*)(dtw + (d4 + 2) * 4);
        float4 w3 = *(const float4*)(dtw + (d4 + 3) * 4);
        float4 b4 = *(const float4*)(dtb + d4);
        size_t gbase = (size_t)b * LL + l0;
#pragma unroll
        for (int tt = 0; tt < 8; tt++) {
            int tok = tok0 + tt;
            float4 q = *(const float4*)(sdtp + tok * 4);
            float4 o;
            o.x = softplus_f(b4.x + q.x * w0.x + q.y * w0.y + q.z * w0.z + q.w * w0.w);
            o.y = softplus_f(b4.y + q.x * w1.x + q.y * w1.y + q.z * w1.z + q.w * w1.w);
            o.z = softplus_f(b4.z + q.x * w2.x + q.y * w2.y + q.z * w2.z + q.w * w2.w);
            o.w = softplus_f(b4.w + q.x * w3.x + q.y * w3.y + q.z * w3.z + q.w * w3.w);
            *(float4*)(dtg + (gbase + tok) * 128 + d4) = o;
        }
    }
}

// ---------------- Scan pass 1: block = 1 chunk, waves = (dh,nh); 8 states/lane ----------------
__global__ __launch_bounds__(256) void k_s1(const unsigned short* __restrict__ xmg,
                                            const float* __restrict__ Bc2,
                                            const float* __restrict__ dtg,
                                            const float* __restrict__ A_log,
                                            float* __restrict__ chH,
                                            float* __restrict__ chP) {
    int b = blockIdx.x >> 7;                     // 1024 blocks = B * NCH
    int ck = blockIdx.x & 127;
    int w = __builtin_amdgcn_readfirstlane(threadIdx.x >> 6);
    int lane = threadIdx.x & 63;
    int dh = w & 1, nh = w >> 1;
    int d = dh * 64 + lane;
    int n0 = nh * 8;

    __shared__ float sB[32][16];
    if (threadIdx.x < 128) {
        int l = threadIdx.x >> 2, q = threadIdx.x & 3;
        *(float4*)(&sB[l][q * 4]) = *(const float4*)(Bc2 + ((size_t)b * LL + ck * 32 + l) * 16 + q * 4);
    }

    float a2[8];
#pragma unroll
    for (int j = 0; j < 2; j++) {
        float4 v = *(const float4*)(A_log + d * 16 + n0 + j * 4);
        a2[j * 4 + 0] = -__expf(v.x) * 1.4426950408889634f;
        a2[j * 4 + 1] = -__expf(v.y) * 1.4426950408889634f;
        a2[j * 4 + 2] = -__expf(v.z) * 1.4426950408889634f;
        a2[j * 4 + 3] = -__expf(v.w) * 1.4426950408889634f;
    }
    float h[8];
#pragma unroll
    for (int n = 0; n < 8; n++) h[n] = 0.f;
    float sdt = 0.f;
    size_t bl0 = (size_t)b * LL + ck * CLEN;
    const unsigned short* xmp = xmg + bl0 * DD + d;
    const float* dtp_ = dtg + bl0 * DD + d;
    __syncthreads();
#pragma unroll 8
    for (int t = 0; t < CLEN; t++) {
        float xmv = bf2f(xmp[(size_t)t * DD]);
        float dtv = dtp_[(size_t)t * DD];
        float dx = dtv * xmv;
        const float* Br = &sB[t][n0];
        sdt += dtv;
#pragma unroll
        for (int n = 0; n < 8; n++) {
            float dA = exp2f(dtv * a2[n]);
            h[n] = fmaf(dA, h[n], dx * Br[n]);
        }
    }
    size_t cbase = ((size_t)((b * 2 + dh) * NCH + ck)) * 1024 + lane * 16 + n0;
#pragma unroll
    for (int j = 0; j < 2; j++) {
        *(float4*)(chH + cbase + j * 4) = make_float4(h[j * 4], h[j * 4 + 1], h[j * 4 + 2], h[j * 4 + 3]);
        *(float4*)(chP + cbase + j * 4) = make_float4(exp2f(a2[j * 4] * sdt), exp2f(a2[j * 4 + 1] * sdt),
                                                      exp2f(a2[j * 4 + 2] * sdt), exp2f(a2[j * 4 + 3] * sdt));
    }
}

// ---------------- Scan pass 2: 16384 scalar recurrences over 128 chunks ----------------
__global__ __launch_bounds__(64) void k_s2(float* __restrict__ chH,
                                           const float* __restrict__ chP) {
    int t = blockIdx.x * 64 + threadIdx.x;   // 0..16383
    int row = t >> 10;
    int q = t & 1023;
    size_t base = (size_t)row * NCH * 1024 + q;
    float H = 0.f;
#pragma unroll 8
    for (int ck = 0; ck < NCH; ck++) {
        size_t a = base + (size_t)ck * 1024;
        float h = chH[a];
        float p = chP[a];
        chH[a] = H;
        H = fmaf(p, H, h);
    }
}

// ---------------- Scan pass 3: block = 1 chunk, waves = (dh,nh); partial-y combine ----------------
__global__ __launch_bounds__(256) void k_s3(const unsigned short* __restrict__ xmg,
                                            const unsigned short* __restrict__ zg,
                                            const float* __restrict__ Bc2,
                                            const float* __restrict__ Cc2,
                                            const float* __restrict__ dtg,
                                            const float* __restrict__ A_log,
                                            const float* __restrict__ Dpp,
                                            const float* __restrict__ hinit,
                                            unsigned short* __restrict__ Y) {
    int b = blockIdx.x >> 7;
    int ck = blockIdx.x & 127;
    int w = __builtin_amdgcn_readfirstlane(threadIdx.x >> 6);
    int lane = threadIdx.x & 63;
    int dh = w & 1, nh = w >> 1;
    int d = dh * 64 + lane;
    int n0 = nh * 8;

    __shared__ float sB[32][16];
    __shared__ float sC[32][16];
    __shared__ float sY[2][32][64];
    if (threadIdx.x < 128) {
        int l = threadIdx.x >> 2, q = threadIdx.x & 3;
        *(float4*)(&sB[l][q * 4]) = *(const float4*)(Bc2 + ((size_t)b * LL + ck * 32 + l) * 16 + q * 4);
        *(float4*)(&sC[l][q * 4]) = *(const float4*)(Cc2 + ((size_t)b * LL + ck * 32 + l) * 16 + q * 4);
    }

    float a2[8];
#pragma unroll
    for (int j = 0; j < 2; j++) {
        float4 v = *(const float4*)(A_log + d * 16 + n0 + j * 4);
        a2[j * 4 + 0] = -__expf(v.x) * 1.4426950408889634f;
        a2[j * 4 + 1] = -__expf(v.y) * 1.4426950408889634f;
        a2[j * 4 + 2] = -__expf(v.z) * 1.4426950408889634f;
        a2[j * 4 + 3] = -__expf(v.w) * 1.4426950408889634f;
    }
    float Dpd = Dpp[d];
    size_t cbase = ((size_t)((b * 2 + dh) * NCH + ck)) * 1024 + lane * 16 + n0;
    float h[8];
#pragma unroll
    for (int j = 0; j < 2; j++) {
        float4 v = *(const float4*)(hinit + cbase + j * 4);
        h[j * 4 + 0] = v.x; h[j * 4 + 1] = v.y; h[j * 4 + 2] = v.z; h[j * 4 + 3] = v.w;
    }
    size_t bl0 = (size_t)b * LL + ck * CLEN;
    const unsigned short* xmp = xmg + bl0 * DD + d;
    const unsigned short* zp = zg + bl0 * DD + d;
    const float* dtp_ = dtg + bl0 * DD + d;
    unsigned short* Yp = Y + bl0 * DD + d;
    float yacc[CLEN];
    __syncthreads();
#pragma unroll
    for (int t = 0; t < CLEN; t++) {
        float xmv = bf2f(xmp[(size_t)t * DD]);
        float zv = bf2f(zp[(size_t)t * DD]);
        float dtv = dtp_[(size_t)t * DD];
        float dx = dtv * xmv;
        const float* Br = &sB[t][n0];
        const float* Cr = &sC[t][n0];
        float y0 = 0.f, y1 = 0.f, y2 = 0.f, y3 = 0.f;
#pragma unroll
        for (int n = 0; n < 8; n += 4) {
            float dA0 = exp2f(dtv * a2[n]);
            float dA1 = exp2f(dtv * a2[n + 1]);
            float dA2 = exp2f(dtv * a2[n + 2]);
            float dA3 = exp2f(dtv * a2[n + 3]);
            h[n] = fmaf(dA0, h[n], dx * Br[n]);
            h[n + 1] = fmaf(dA1, h[n + 1], dx * Br[n + 1]);
            h[n + 2] = fmaf(dA2, h[n + 2], dx * Br[n + 2]);
            h[n + 3] = fmaf(dA3, h[n + 3], dx * Br[n + 3]);
            y0 = fmaf(h[n], Cr[n], y0);
            y1 = fmaf(h[n + 1], Cr[n + 1], y1);
            y2 = fmaf(h[n + 2], Cr[n + 2], y2);
            y3 = fmaf(h[n + 3], Cr[n + 3], y3);
        }
        float yp = (y0 + y1) + (y2 + y3);
        if (nh == 0) yp = fmaf(xmv, Dpd, yp);
        yacc[t] = yp * silu_f(zv);
    }
    if (nh == 1) {
#pragma unroll
        for (int t = 0; t < CLEN; t++) sY[dh][t][lane] = yacc[t];
    }
    __syncthreads();
    if (nh == 0) {
#pragma unroll
        for (int t = 0; t < CLEN; t++)
            Yp[(size_t)t * DD] = f2bf(yacc[t] + sY[dh][t][lane]);
    }
}

// ---------------- K4: out_proj + PReLU -> img1t bf16 [b][p*64+q][64]  (4 oc-groups/wave) ----------------
__global__ __launch_bounds__(256) void k_outproj(const unsigned short* __restrict__ Y,
                                                 const float* __restrict__ wo,
                                                 const float* __restrict__ pre,
                                                 unsigned short* __restrict__ img1t) {
    int blk = blockIdx.x;                        // 512
    int bl = (blk << 6) + (threadIdx.x & 63);
    int oc0 = __builtin_amdgcn_readfirstlane(threadIdx.x >> 6) * 16;
    const unsigned short* yr = Y + (size_t)bl * DD;
    float acc[16];
#pragma unroll
    for (int o = 0; o < 16; o++) acc[o] = 0.f;
    for (int c8 = 0; c8 < 8; c8++) {
        ushort8v u0 = *(const ushort8v*)(yr + c8 * 16);
        ushort8v u1 = *(const ushort8v*)(yr + c8 * 16 + 8);
        float xv[16];
#pragma unroll
        for (int j = 0; j < 8; j++) { xv[j] = bf2f(u0[j]); xv[8 + j] = bf2f(u1[j]); }
#pragma unroll
        for (int o = 0; o < 16; o++) {
            const float* wr = wo + (size_t)(oc0 + o) * DD + c8 * 16;
            float a = acc[o];
#pragma unroll
            for (int j = 0; j < 16; j++) a = fmaf(xv[j], wr[j], a);
            acc[o] = a;
        }
    }
    float pa = pre[0];
    int b = bl >> 12, l = bl & 4095;
    int px = (l & 63) * 64 + (l >> 6);           // (p = l%64, q = l/64)
    unsigned short* dst = img1t + ((size_t)b * 4096 + px) * 64 + oc0;
#pragma unroll
    for (int g8 = 0; g8 < 2; g8++) {
        ushort8v w;
#pragma unroll
        for (int j = 0; j < 8; j++) {
            float v = acc[g8 * 8 + j];
            v = v >= 0.f ? v : pa * v;
            w[j] = f2bf(v);
        }
        *(ushort8v*)(dst + g8 * 8) = w;
    }
}

// ---------------- weight prep: Wk[oc][shift*64+ic] bf16 for both 3x3 convs ----------------
__global__ __launch_bounds__(256) void k_wprep(const float* __restrict__ w1,
                                               const float* __restrict__ w2,
                                               unsigned short* __restrict__ Wk1,
                                               unsigned short* __restrict__ Wk2) {
    int idx = blockIdx.x * 256 + threadIdx.x;
    if (idx >= 2 * 36864) return;
    const float* w = (idx < 36864) ? w1 : w2;
    unsigned short* dst = (idx < 36864) ? Wk1 : Wk2;
    int r = (idx < 36864) ? idx : idx - 36864;
    int oc = r / 576, k = r % 576;
    int shift = k >> 6, ic = k & 63;
    dst[oc * 576 + k] = f2bf(w[(oc * 64 + ic) * 9 + shift]);
}

// ---------------- K5/K6: 3x3 conv via MFMA bf16 + BN + PReLU (+residual) ----------------
template <bool FINAL>
__global__ __launch_bounds__(256) void k_conv3m(const unsigned short* __restrict__ in_t,
                                                const unsigned short* __restrict__ Wk,
                                                const float* __restrict__ bnp,
                                                const float* __restrict__ pre,
                                                unsigned short* __restrict__ out_t,
                                                float* __restrict__ outf) {
    int bid = blockIdx.x;
    int b = bid >> 6;
    int p = bid & 63;
    int tid = threadIdx.x;
    int lane = tid & 63;
    int wv = tid >> 6;
    int oc0 = __builtin_amdgcn_readfirstlane(wv * 16);
    __shared__ unsigned short lds[3 * 66 * 64];

    short8 afrag[18];
    const unsigned short* wrow = Wk + (size_t)(oc0 + (lane & 15)) * 576 + ((lane >> 4) * 8);
#pragma unroll
    for (int s = 0; s < 18; s++) afrag[s] = *(const short8*)(wrow + s * 32);

    const unsigned short* ib = in_t + (size_t)b * 4096 * 64;
    for (int idx = tid; idx < 1584; idx += 256) {
        int pair = idx >> 3, c = idx & 7;
        int di = pair / 66, col = pair % 66;
        int r = p - 1 + di, q = col - 1;
        ushort8v v = {0, 0, 0, 0, 0, 0, 0, 0};
        if (r >= 0 && r < 64 && q >= 0 && q < 64)
            v = *(const ushort8v*)(ib + ((size_t)(r * 64 + q)) * 64 + c * 8);
        *(ushort8v*)(lds + pair * 64 + ((c ^ (col & 7)) * 8)) = v;
    }
    __syncthreads();

    f32x4 acc[4];
#pragma unroll
    for (int n0 = 0; n0 < 4; n0++) acc[n0] = (f32x4){0.f, 0.f, 0.f, 0.f};
#pragma unroll
    for (int s = 0; s < 18; s++) {
        const int shift = s >> 1, h = s & 1;
        const int di = shift / 3, dj = shift % 3;
#pragma unroll
        for (int n0 = 0; n0 < 4; n0++) {
            int col = n0 * 16 + (lane & 15) + dj;
            int off = (di * 66 + col) * 64 + (((h * 4 + (lane >> 4)) ^ (col & 7)) * 8);
            short8 bfrag = *(const short8*)(lds + off);
            acc[n0] = __builtin_amdgcn_mfma_f32_16x16x32_bf16(afrag[s], bfrag, acc[n0], 0, 0, 0);
        }
    }

    int ocb = oc0 + ((lane >> 4) << 2);
    float4 g4 = *(const float4*)(bnp + ocb);
    float4 be4 = *(const float4*)(bnp + 64 + ocb);
    float4 m4 = *(const float4*)(bnp + 128 + ocb);
    float4 v4 = *(const float4*)(bnp + 192 + ocb);
    float sc[4], sh[4];
    sc[0] = g4.x * rsqrtf(v4.x + EPS); sh[0] = be4.x - m4.x * sc[0];
    sc[1] = g4.y * rsqrtf(v4.y + EPS); sh[1] = be4.y - m4.y * sc[1];
    sc[2] = g4.z * rsqrtf(v4.z + EPS); sh[2] = be4.z - m4.z * sc[2];
    sc[3] = g4.w * rsqrtf(v4.w + EPS); sh[3] = be4.w - m4.w * sc[3];
    float pa = pre[0];
#pragma unroll
    for (int n0 = 0; n0 < 4; n0++) {
        int q = n0 * 16 + (lane & 15);
        float vals[4];
#pragma unroll
        for (int r = 0; r < 4; r++) {
            float v = fmaf(acc[n0][r], sc[r], sh[r]);
            vals[r] = v >= 0.f ? v : pa * v;
        }
        if (FINAL) {
#pragma unroll
            for (int r = 0; r < 4; r++) {
                size_t addr = ((size_t)b * 64 + ocb + r) * 4096 + p * 64 + q;
                outf[addr] = vals[r] + outf[addr];
            }
        } else {
            ushort4 u = make_ushort4(f2bf(vals[0]), f2bf(vals[1]), f2bf(vals[2]), f2bf(vals[3]));
            *(ushort4*)(out_t + ((size_t)b * 4096 + p * 64 + q) * 64 + ocb) = u;
        }
    }
}

extern "C" void kernel_launch(void* const* d_in, const int* in_sizes, int n_in,
                              void* d_out, int out_size, void* d_ws, size_t ws_size,
                              hipStream_t stream) {
    const float* x = (const float*)d_in[0];
    const float* in_proj_w = (const float*)d_in[1];
    const float* conv1d_w = (const float*)d_in[2];
    const float* conv1d_b = (const float*)d_in[3];
    const float* x_proj_w = (const float*)d_in[4];
    const float* dt_proj_w = (const float*)d_in[5];
    const float* dt_proj_b = (const float*)d_in[6];
    const float* A_log = (const float*)d_in[7];
    const float* Dp = (const float*)d_in[8];
    const float* out_proj_w = (const float*)d_in[9];
    const float* prelu_ssm = (const float*)d_in[10];
    const float* res_w = (const float*)d_in[11];
    const float* res_bn = (const float*)d_in[12];
    const float* conv1_w = (const float*)d_in[13];
    const float* bn1 = (const float*)d_in[14];
    const float* prelu1 = (const float*)d_in[15];
    const float* conv2_w = (const float*)d_in[16];
    const float* bn2 = (const float*)d_in[17];
    const float* prelu2 = (const float*)d_in[18];
    float* out = (float*)d_out;
    float* ws = (float*)d_ws;

    const size_t S = (size_t)BB * LL * DD;        // 4,194,304 floats
    const size_t HALF = S / 2;
    float* chH = ws;                              // [0, HALF)
    float* chP = ws + HALF;                       // [HALF, S)
    unsigned short* xmg = (unsigned short*)(ws + S);              // bf16
    unsigned short* zg = (unsigned short*)(ws + S + HALF);        // bf16
    float* dtg = ws + 2 * S;                      // f32 (B,L,128)
    unsigned short* Yb = (unsigned short*)(ws + 3 * S);           // bf16
    float* Bc2 = ws + 3 * S + HALF;               // S/8
    float* Cc2 = Bc2 + S / 8;                     // S/8
    unsigned short* img1t = (unsigned short*)ws;            // over chH, after s3
    unsigned short* img2t = (unsigned short*)(ws + HALF);   // over chP, after s2
    unsigned short* Wk1 = (unsigned short*)Bc2;             // over Bc2, after s3
    unsigned short* Wk2 = Wk1 + 36864;

    k_res<<<dim3(512), dim3(256), 0, stream>>>(x, res_w, res_bn, out);
    k_front<<<dim3(512), dim3(256), 0, stream>>>(x, in_proj_w, x_proj_w, conv1d_w, conv1d_b,
                                                 dt_proj_w, dt_proj_b,
                                                 xmg, zg, Bc2, Cc2, dtg);
    k_s1<<<dim3(BB * NCH), dim3(256), 0, stream>>>(xmg, Bc2, dtg, A_log, chH, chP);
    k_s2<<<dim3(256), dim3(64), 0, stream>>>(chH, chP);
    k_s3<<<dim3(BB * NCH), dim3(256), 0, stream>>>(xmg, zg, Bc2, Cc2, dtg, A_log, Dp, chH, Yb);
    k_outproj<<<dim3(512), dim3(256), 0, stream>>>(Yb, out_proj_w, prelu_ssm, img1t);
    k_wprep<<<dim3(288), dim3(256), 0, stream>>>(conv1_w, conv2_w, Wk1, Wk2);
    k_conv3m<false><<<dim3(512), dim3(256), 0, stream>>>(img1t, Wk1, bn1, prelu1, img2t, nullptr);
    k_conv3m<true><<<dim3(512), dim3(256), 0, stream>>>(img2t, Wk2, bn2, prelu2, nullptr, out);
}

// Round 10
// 175.960 us; speedup vs baseline: 1.1580x; 1.0563x over previous
//
#include <hip/hip_runtime.h>
#include <hip/hip_bf16.h>

#define BB 8
#define CC 64
#define LL 4096
#define DD 128
#define NN 16
#define EPS 1e-5f
#define NCH 128
#define CLEN 32

typedef short short8 __attribute__((ext_vector_type(8)));
typedef unsigned short ushort8v __attribute__((ext_vector_type(8)));
typedef float f32x4 __attribute__((ext_vector_type(4)));

__device__ __forceinline__ float silu_f(float v) {
    return v / (1.f + __expf(-v));
}
__device__ __forceinline__ float softplus_f(float t) {
    return fmaxf(t, 0.f) + __logf(1.f + __expf(-fabsf(t)));
}
__device__ __forceinline__ unsigned short f2bf(float f) {
    unsigned int u = __float_as_uint(f);
    u += 0x7fff + ((u >> 16) & 1);
    return (unsigned short)(u >> 16);
}
__device__ __forceinline__ float bf2f(unsigned short u) {
    return __uint_as_float(((unsigned int)u) << 16);
}

// ---------------- K0: residual 1x1 conv + BN -> d_out  (4 oc-groups/wave) ----------------
__global__ __launch_bounds__(256) void k_res(const float* __restrict__ x,
                                             const float* __restrict__ rw,
                                             const float* __restrict__ rbn,
                                             float* __restrict__ out) {
    int blk = blockIdx.x;                       // 512
    int b = blk >> 6;
    int s = ((blk & 63) << 6) + (threadIdx.x & 63);
    int oc0 = __builtin_amdgcn_readfirstlane(threadIdx.x >> 6) * 16;
    const float* xb = x + (size_t)b * CC * LL;
    float xv[64];
#pragma unroll
    for (int ic = 0; ic < 64; ic++) xv[ic] = xb[ic * LL + s];
#pragma unroll
    for (int o = 0; o < 16; o++) {
        int oc = oc0 + o;
        const float* wr = rw + oc * 64;
        float acc = 0.f;
#pragma unroll
        for (int ic = 0; ic < 64; ic++) acc = fmaf(xv[ic], wr[ic], acc);
        float g = rbn[oc], be = rbn[64 + oc], m = rbn[128 + oc], v = rbn[192 + oc];
        float sc = g * rsqrtf(v + EPS);
        float sh = be - m * sc;
        out[((size_t)b * 64 + oc) * LL + s] = fmaf(acc, sc, sh);
    }
}

// ---------------- k_front: in_proj (MFMA) + conv1d + SiLU + x_proj (MFMA) + dt fused ----------------
// scan-facing outputs in chunk-transposed layout: xmT/zT bf16 [b][ck][d][32t], dtT f32 same
__global__ __launch_bounds__(256) void k_front(const float* __restrict__ x,
                                               const float* __restrict__ wip,
                                               const float* __restrict__ xw,
                                               const float* __restrict__ cw,
                                               const float* __restrict__ cb,
                                               const float* __restrict__ dtw,
                                               const float* __restrict__ dtb,
                                               unsigned short* __restrict__ xmT,
                                               unsigned short* __restrict__ zT,
                                               float* __restrict__ Bc2,
                                               float* __restrict__ Cc2,
                                               float* __restrict__ dtT) {
    int blk = blockIdx.x;                        // 512 = B * (L/64)
    int b = blk >> 6;
    int l0 = (blk & 63) << 6;
    int tid = threadIdx.x;
    int lane = tid & 63;
    int wv = __builtin_amdgcn_readfirstlane(tid >> 6);
    int l15 = lane & 15, l4g = lane >> 4;

    __shared__ unsigned short xt[80 * 64];
    __shared__ unsigned short xmf[80 * 132];     // later reused: first 256 floats = sdtp
    __shared__ unsigned short zf[64 * 132];
    __shared__ unsigned short xmc[64 * 128];
    float* sdtp = (float*)xmf;

    for (int idx = tid; idx < 5120; idx += 256) {
        int c = idx / 80;
        int j = idx - c * 80;
        int l = l0 - 3 + j;
        float v = (l >= 0 && l < LL) ? x[((size_t)b * CC + c) * LL + l] : 0.f;
        xt[j * 64 + (((c >> 3) ^ (j & 7)) * 8) + (c & 7)] = f2bf(v);
    }

    short8 af[4][2];
#pragma unroll
    for (int m0 = 0; m0 < 4; m0++) {
        const float* wr = wip + (size_t)(wv * 64 + m0 * 16 + l15) * 64 + l4g * 8;
#pragma unroll
        for (int h = 0; h < 2; h++) {
            float4 a0 = *(const float4*)(wr + h * 32);
            float4 a1 = *(const float4*)(wr + h * 32 + 4);
            short8 f;
            f[0] = (short)f2bf(a0.x); f[1] = (short)f2bf(a0.y);
            f[2] = (short)f2bf(a0.z); f[3] = (short)f2bf(a0.w);
            f[4] = (short)f2bf(a1.x); f[5] = (short)f2bf(a1.y);
            f[6] = (short)f2bf(a1.z); f[7] = (short)f2bf(a1.w);
            af[m0][h] = f;
        }
    }
    __syncthreads();

    f32x4 acc[4][5];
#pragma unroll
    for (int m0 = 0; m0 < 4; m0++)
#pragma unroll
        for (int n0 = 0; n0 < 5; n0++) acc[m0][n0] = (f32x4){0.f, 0.f, 0.f, 0.f};
#pragma unroll
    for (int n0 = 0; n0 < 5; n0++) {
        int j = n0 * 16 + l15;
#pragma unroll
        for (int h = 0; h < 2; h++) {
            short8 bf = *(const short8*)(xt + j * 64 + (((h * 4 + l4g) ^ (j & 7)) * 8));
#pragma unroll
            for (int m0 = 0; m0 < 4; m0++)
                acc[m0][n0] = __builtin_amdgcn_mfma_f32_16x16x32_bf16(af[m0][h], bf, acc[m0][n0], 0, 0, 0);
        }
    }

#pragma unroll
    for (int m0 = 0; m0 < 4; m0++)
#pragma unroll
        for (int n0 = 0; n0 < 5; n0++) {
            int j = n0 * 16 + l15;
            int d = (wv & 1) * 64 + m0 * 16 + l4g * 4;
            ushort4 u = make_ushort4(f2bf(acc[m0][n0][0]), f2bf(acc[m0][n0][1]),
                                     f2bf(acc[m0][n0][2]), f2bf(acc[m0][n0][3]));
            if (wv < 2) {
                *(ushort4*)(xmf + j * 132 + d) = u;
            } else {
                int t = j - 3;
                if (t >= 0 && t < 64) *(ushort4*)(zf + t * 132 + d) = u;
            }
        }
    __syncthreads();

    // ---- conv1d + SiLU; collect per-thread [4 d][8 t] then write chunk-transposed tiles ----
    {
        int d4 = (tid & 31) * 4;
        int tok0 = (tid >> 5) * 8;
        float4 w0 = *(const float4*)(cw + (d4 + 0) * 4);
        float4 w1 = *(const float4*)(cw + (d4 + 1) * 4);
        float4 w2 = *(const float4*)(cw + (d4 + 2) * 4);
        float4 w3 = *(const float4*)(cw + (d4 + 3) * 4);
        float4 cb4 = *(const float4*)(cb + d4);
        int kc = d4 >> 3;
        unsigned short xm_loc[4][8], z_loc[4][8];
#pragma unroll
        for (int tt = 0; tt < 8; tt++) {
            int tok = tok0 + tt;
            ushort4 r0 = *(const ushort4*)(xmf + (tok + 0) * 132 + d4);
            ushort4 r1 = *(const ushort4*)(xmf + (tok + 1) * 132 + d4);
            ushort4 r2 = *(const ushort4*)(xmf + (tok + 2) * 132 + d4);
            ushort4 r3 = *(const ushort4*)(xmf + (tok + 3) * 132 + d4);
            float v0 = cb4.x + w0.x * bf2f(r0.x) + w0.y * bf2f(r1.x) + w0.z * bf2f(r2.x) + w0.w * bf2f(r3.x);
            float v1 = cb4.y + w1.x * bf2f(r0.y) + w1.y * bf2f(r1.y) + w1.z * bf2f(r2.y) + w1.w * bf2f(r3.y);
            float v2 = cb4.z + w2.x * bf2f(r0.z) + w2.y * bf2f(r1.z) + w2.z * bf2f(r2.z) + w2.w * bf2f(r3.z);
            float v3 = cb4.w + w3.x * bf2f(r0.w) + w3.y * bf2f(r1.w) + w3.z * bf2f(r2.w) + w3.w * bf2f(r3.w);
            ushort4 o = make_ushort4(f2bf(silu_f(v0)), f2bf(silu_f(v1)), f2bf(silu_f(v2)), f2bf(silu_f(v3)));
            *(ushort4*)(xmc + tok * 128 + ((kc ^ (tok & 7)) * 8) + (d4 & 4)) = o;
            xm_loc[0][tt] = o.x; xm_loc[1][tt] = o.y; xm_loc[2][tt] = o.z; xm_loc[3][tt] = o.w;
            ushort4 zv = *(const ushort4*)(zf + tok * 132 + d4);
            z_loc[0][tt] = zv.x; z_loc[1][tt] = zv.y; z_loc[2][tt] = zv.z; z_loc[3][tt] = zv.w;
        }
        int ck = (l0 >> 5) + (tok0 >> 5);
        int tb = tok0 & 31;
#pragma unroll
        for (int r = 0; r < 4; r++) {
            size_t rowb = (((size_t)b * NCH + ck) * DD + d4 + r) * 32 + tb;
            ushort8v px, pz;
#pragma unroll
            for (int j = 0; j < 8; j++) { px[j] = xm_loc[r][j]; pz[j] = z_loc[r][j]; }
            *(ushort8v*)(xmT + rowb) = px;
            *(ushort8v*)(zT + rowb) = pz;
        }
    }
    __syncthreads();

    short8 pa_[3][4];
#pragma unroll
    for (int mt = 0; mt < 3; mt++) {
        int j = mt * 16 + l15;
#pragma unroll
        for (int ks = 0; ks < 4; ks++) {
            short8 f = {0, 0, 0, 0, 0, 0, 0, 0};
            if (j < 36) {
                const float* wr = xw + (size_t)j * 128 + ks * 32 + l4g * 8;
                float4 a0 = *(const float4*)(wr);
                float4 a1 = *(const float4*)(wr + 4);
                f[0] = (short)f2bf(a0.x); f[1] = (short)f2bf(a0.y);
                f[2] = (short)f2bf(a0.z); f[3] = (short)f2bf(a0.w);
                f[4] = (short)f2bf(a1.x); f[5] = (short)f2bf(a1.y);
                f[6] = (short)f2bf(a1.z); f[7] = (short)f2bf(a1.w);
            }
            pa_[mt][ks] = f;
        }
    }
    int t = wv * 16 + l15;
    f32x4 a3[3];
#pragma unroll
    for (int mt = 0; mt < 3; mt++) a3[mt] = (f32x4){0.f, 0.f, 0.f, 0.f};
#pragma unroll
    for (int ks = 0; ks < 4; ks++) {
        short8 bf = *(const short8*)(xmc + t * 128 + (((ks * 4 + l4g) ^ (t & 7)) * 8));
#pragma unroll
        for (int mt = 0; mt < 3; mt++)
            a3[mt] = __builtin_amdgcn_mfma_f32_16x16x32_bf16(pa_[mt][ks], bf, a3[mt], 0, 0, 0);
    }
    size_t bl = (size_t)b * LL + l0 + t;
    float4 o0 = make_float4(a3[0][0], a3[0][1], a3[0][2], a3[0][3]);
    float4 o1 = make_float4(a3[1][0], a3[1][1], a3[1][2], a3[1][3]);
    float4 o2 = make_float4(a3[2][0], a3[2][1], a3[2][2], a3[2][3]);
    if (l4g == 0) {
        *(float4*)(sdtp + t * 4) = o0;               // dtp -> LDS
        *(float4*)(Bc2 + bl * 16 + 12) = o1;
        *(float4*)(Cc2 + bl * 16 + 12) = o2;
    } else {
        *(float4*)(Bc2 + bl * 16 + (l4g - 1) * 4) = o0;
        *(float4*)(Cc2 + bl * 16 + (l4g - 1) * 4) = o1;
    }
    __syncthreads();

    // ---- dt = softplus(dtp @ dtw^T + dtb), write chunk-transposed f32 tiles ----
    {
        int d4 = (tid & 31) * 4;
        int tok0 = (tid >> 5) * 8;
        float4 w0 = *(const float4*)(dtw + (d4 + 0) * 4);
        float4 w1 = *(const float4*)(dtw + (d4 + 1) * 4);
        float4 w2 = *(const float4*)(dtw + (d4 + 2) * 4);
        float4 w3 = *(const float4*)(dtw + (d4 + 3) * 4);
        float4 b4 = *(const float4*)(dtb + d4);
        float dt_loc[4][8];
#pragma unroll
        for (int tt = 0; tt < 8; tt++) {
            float4 q = *(const float4*)(sdtp + (tok0 + tt) * 4);
            dt_loc[0][tt] = softplus_f(b4.x + q.x * w0.x + q.y * w0.y + q.z * w0.z + q.w * w0.w);
            dt_loc[1][tt] = softplus_f(b4.y + q.x * w1.x + q.y * w1.y + q.z * w1.z + q.w * w1.w);
            dt_loc[2][tt] = softplus_f(b4.z + q.x * w2.x + q.y * w2.y + q.z * w2.z + q.w * w2.w);
            dt_loc[3][tt] = softplus_f(b4.w + q.x * w3.x + q.y * w3.y + q.z * w3.z + q.w * w3.w);
        }
        int ck = (l0 >> 5) + (tok0 >> 5);
        int tb = tok0 & 31;
#pragma unroll
        for (int r = 0; r < 4; r++) {
            size_t rowb = (((size_t)b * NCH + ck) * DD + d4 + r) * 32 + tb;
            *(float4*)(dtT + rowb) = make_float4(dt_loc[r][0], dt_loc[r][1], dt_loc[r][2], dt_loc[r][3]);
            *(float4*)(dtT + rowb + 4) = make_float4(dt_loc[r][4], dt_loc[r][5], dt_loc[r][6], dt_loc[r][7]);
        }
    }
}

// ---------------- Scan pass 1: block = 2 chunks x 2 dh; vectorized chunk loads ----------------
__global__ __launch_bounds__(256) void k_s1(const unsigned short* __restrict__ xmT,
                                            const float* __restrict__ Bc2,
                                            const float* __restrict__ dtT,
                                            const float* __restrict__ A_log,
                                            float* __restrict__ chH,
                                            float* __restrict__ chP) {
    int b = blockIdx.x >> 6;                     // 512 blocks
    int ckp = blockIdx.x & 63;
    int w = __builtin_amdgcn_readfirstlane(threadIdx.x >> 6);
    int lane = threadIdx.x & 63;
    int ck = ckp * 2 + (w >> 1);
    int dh = w & 1;
    int d = dh * 64 + lane;

    __shared__ float sB[64][16];
    {
        int l = threadIdx.x >> 2, q = threadIdx.x & 3;
        *(float4*)(&sB[l][q * 4]) = *(const float4*)(Bc2 + ((size_t)b * LL + ckp * 64 + l) * 16 + q * 4);
    }

    float a2[16];
#pragma unroll
    for (int j = 0; j < 4; j++) {
        float4 v = *(const float4*)(A_log + d * 16 + j * 4);
        a2[j * 4 + 0] = -__expf(v.x) * 1.4426950408889634f;
        a2[j * 4 + 1] = -__expf(v.y) * 1.4426950408889634f;
        a2[j * 4 + 2] = -__expf(v.z) * 1.4426950408889634f;
        a2[j * 4 + 3] = -__expf(v.w) * 1.4426950408889634f;
    }
    size_t rowb = (((size_t)b * NCH + ck) * DD + d) * 32;
    unsigned short xms[32];
    float dts[32];
#pragma unroll
    for (int j = 0; j < 4; j++) {
        ushort8v v = *(const ushort8v*)(xmT + rowb + j * 8);
#pragma unroll
        for (int e = 0; e < 8; e++) xms[j * 8 + e] = v[e];
    }
#pragma unroll
    for (int j = 0; j < 8; j++) {
        float4 v = *(const float4*)(dtT + rowb + j * 4);
        dts[j * 4 + 0] = v.x; dts[j * 4 + 1] = v.y; dts[j * 4 + 2] = v.z; dts[j * 4 + 3] = v.w;
    }

    float h[16];
#pragma unroll
    for (int n = 0; n < 16; n++) h[n] = 0.f;
    float sdt = 0.f;
    int lb = (w >> 1) * 32;
    __syncthreads();
#pragma unroll
    for (int t = 0; t < CLEN; t++) {
        float xmv = bf2f(xms[t]);
        float dtv = dts[t];
        float dx = dtv * xmv;
        const float* Br = &sB[lb + t][0];
        sdt += dtv;
#pragma unroll
        for (int n = 0; n < 16; n++) {
            float dA = exp2f(dtv * a2[n]);
            h[n] = fmaf(dA, h[n], dx * Br[n]);
        }
    }
    size_t cbase = ((size_t)((b * 2 + dh) * NCH + ck)) * 1024 + lane * 16;
#pragma unroll
    for (int j = 0; j < 4; j++) {
        *(float4*)(chH + cbase + j * 4) = make_float4(h[j * 4], h[j * 4 + 1], h[j * 4 + 2], h[j * 4 + 3]);
        *(float4*)(chP + cbase + j * 4) = make_float4(exp2f(a2[j * 4] * sdt), exp2f(a2[j * 4 + 1] * sdt),
                                                      exp2f(a2[j * 4 + 2] * sdt), exp2f(a2[j * 4 + 3] * sdt));
    }
}

// ---------------- Scan pass 2: 16384 scalar recurrences over 128 chunks ----------------
__global__ __launch_bounds__(64) void k_s2(float* __restrict__ chH,
                                           const float* __restrict__ chP) {
    int t = blockIdx.x * 64 + threadIdx.x;   // 0..16383
    int row = t >> 10;
    int q = t & 1023;
    size_t base = (size_t)row * NCH * 1024 + q;
    float H = 0.f;
#pragma unroll 8
    for (int ck = 0; ck < NCH; ck++) {
        size_t a = base + (size_t)ck * 1024;
        float h = chH[a];
        float p = chP[a];
        chH[a] = H;
        H = fmaf(p, H, h);
    }
}

// ---------------- Scan pass 3: block = 2 chunks x 2 dh; vectorized chunk loads ----------------
__global__ __launch_bounds__(256) void k_s3(const unsigned short* __restrict__ xmT,
                                            const unsigned short* __restrict__ zT,
                                            const float* __restrict__ Bc2,
                                            const float* __restrict__ Cc2,
                                            const float* __restrict__ dtT,
                                            const float* __restrict__ A_log,
                                            const float* __restrict__ Dpp,
                                            const float* __restrict__ hinit,
                                            unsigned short* __restrict__ Y) {
    int b = blockIdx.x >> 6;
    int ckp = blockIdx.x & 63;
    int w = __builtin_amdgcn_readfirstlane(threadIdx.x >> 6);
    int lane = threadIdx.x & 63;
    int ck = ckp * 2 + (w >> 1);
    int dh = w & 1;
    int d = dh * 64 + lane;

    __shared__ float sB[64][16];
    __shared__ float sC[64][16];
    {
        int l = threadIdx.x >> 2, q = threadIdx.x & 3;
        *(float4*)(&sB[l][q * 4]) = *(const float4*)(Bc2 + ((size_t)b * LL + ckp * 64 + l) * 16 + q * 4);
        *(float4*)(&sC[l][q * 4]) = *(const float4*)(Cc2 + ((size_t)b * LL + ckp * 64 + l) * 16 + q * 4);
    }

    float a2[16];
#pragma unroll
    for (int j = 0; j < 4; j++) {
        float4 v = *(const float4*)(A_log + d * 16 + j * 4);
        a2[j * 4 + 0] = -__expf(v.x) * 1.4426950408889634f;
        a2[j * 4 + 1] = -__expf(v.y) * 1.4426950408889634f;
        a2[j * 4 + 2] = -__expf(v.z) * 1.4426950408889634f;
        a2[j * 4 + 3] = -__expf(v.w) * 1.4426950408889634f;
    }
    float Dpd = Dpp[d];
    size_t cbase = ((size_t)((b * 2 + dh) * NCH + ck)) * 1024 + lane * 16;
    float h[16];
#pragma unroll
    for (int j = 0; j < 4; j++) {
        float4 v = *(const float4*)(hinit + cbase + j * 4);
        h[j * 4 + 0] = v.x; h[j * 4 + 1] = v.y; h[j * 4 + 2] = v.z; h[j * 4 + 3] = v.w;
    }

    size_t rowb = (((size_t)b * NCH + ck) * DD + d) * 32;
    unsigned short xms[32], zs[32];
    float dts[32];
#pragma unroll
    for (int j = 0; j < 4; j++) {
        ushort8v v = *(const ushort8v*)(xmT + rowb + j * 8);
        ushort8v vz = *(const ushort8v*)(zT + rowb + j * 8);
#pragma unroll
        for (int e = 0; e < 8; e++) { xms[j * 8 + e] = v[e]; zs[j * 8 + e] = vz[e]; }
    }
#pragma unroll
    for (int j = 0; j < 8; j++) {
        float4 v = *(const float4*)(dtT + rowb + j * 4);
        dts[j * 4 + 0] = v.x; dts[j * 4 + 1] = v.y; dts[j * 4 + 2] = v.z; dts[j * 4 + 3] = v.w;
    }

    size_t bl0 = (size_t)b * LL + ck * CLEN;
    unsigned short* Yp = Y + bl0 * DD + d;
    int lb = (w >> 1) * 32;
    __syncthreads();
#pragma unroll
    for (int t = 0; t < CLEN; t++) {
        float xmv = bf2f(xms[t]);
        float zv = bf2f(zs[t]);
        float dtv = dts[t];
        float dx = dtv * xmv;
        const float* Br = &sB[lb + t][0];
        const float* Cr = &sC[lb + t][0];
        float y0 = 0.f, y1 = 0.f, y2 = 0.f, y3 = 0.f;
#pragma unroll
        for (int n = 0; n < 16; n += 4) {
            float dA0 = exp2f(dtv * a2[n]);
            float dA1 = exp2f(dtv * a2[n + 1]);
            float dA2 = exp2f(dtv * a2[n + 2]);
            float dA3 = exp2f(dtv * a2[n + 3]);
            h[n] = fmaf(dA0, h[n], dx * Br[n]);
            h[n + 1] = fmaf(dA1, h[n + 1], dx * Br[n + 1]);
            h[n + 2] = fmaf(dA2, h[n + 2], dx * Br[n + 2]);
            h[n + 3] = fmaf(dA3, h[n + 3], dx * Br[n + 3]);
            y0 = fmaf(h[n], Cr[n], y0);
            y1 = fmaf(h[n + 1], Cr[n + 1], y1);
            y2 = fmaf(h[n + 2], Cr[n + 2], y2);
            y3 = fmaf(h[n + 3], Cr[n + 3], y3);
        }
        float yv = (y0 + y1) + (y2 + y3);
        yv = fmaf(xmv, Dpd, yv);
        Yp[(size_t)t * DD] = f2bf(yv * silu_f(zv));
    }
}

// ---------------- K4: out_proj + PReLU -> img1t bf16 [b][p*64+q][64]  (4 oc-groups/wave) ----------------
__global__ __launch_bounds__(256) void k_outproj(const unsigned short* __restrict__ Y,
                                                 const float* __restrict__ wo,
                                                 const float* __restrict__ pre,
                                                 unsigned short* __restrict__ img1t) {
    int blk = blockIdx.x;                        // 512
    int bl = (blk << 6) + (threadIdx.x & 63);
    int oc0 = __builtin_amdgcn_readfirstlane(threadIdx.x >> 6) * 16;
    const unsigned short* yr = Y + (size_t)bl * DD;
    float acc[16];
#pragma unroll
    for (int o = 0; o < 16; o++) acc[o] = 0.f;
    for (int c8 = 0; c8 < 8; c8++) {
        ushort8v u0 = *(const ushort8v*)(yr + c8 * 16);
        ushort8v u1 = *(const ushort8v*)(yr + c8 * 16 + 8);
        float xv[16];
#pragma unroll
        for (int j = 0; j < 8; j++) { xv[j] = bf2f(u0[j]); xv[8 + j] = bf2f(u1[j]); }
#pragma unroll
        for (int o = 0; o < 16; o++) {
            const float* wr = wo + (size_t)(oc0 + o) * DD + c8 * 16;
            float a = acc[o];
#pragma unroll
            for (int j = 0; j < 16; j++) a = fmaf(xv[j], wr[j], a);
            acc[o] = a;
        }
    }
    float pa = pre[0];
    int b = bl >> 12, l = bl & 4095;
    int px = (l & 63) * 64 + (l >> 6);           // (p = l%64, q = l/64)
    unsigned short* dst = img1t + ((size_t)b * 4096 + px) * 64 + oc0;
#pragma unroll
    for (int g8 = 0; g8 < 2; g8++) {
        ushort8v w;
#pragma unroll
        for (int j = 0; j < 8; j++) {
            float v = acc[g8 * 8 + j];
            v = v >= 0.f ? v : pa * v;
            w[j] = f2bf(v);
        }
        *(ushort8v*)(dst + g8 * 8) = w;
    }
}

// ---------------- weight prep: Wk[oc][shift*64+ic] bf16 for both 3x3 convs ----------------
__global__ __launch_bounds__(256) void k_wprep(const float* __restrict__ w1,
                                               const float* __restrict__ w2,
                                               unsigned short* __restrict__ Wk1,
                                               unsigned short* __restrict__ Wk2) {
    int idx = blockIdx.x * 256 + threadIdx.x;
    if (idx >= 2 * 36864) return;
    const float* w = (idx < 36864) ? w1 : w2;
    unsigned short* dst = (idx < 36864) ? Wk1 : Wk2;
    int r = (idx < 36864) ? idx : idx - 36864;
    int oc = r / 576, k = r % 576;
    int shift = k >> 6, ic = k & 63;
    dst[oc * 576 + k] = f2bf(w[(oc * 64 + ic) * 9 + shift]);
}

// ---------------- K5/K6: 3x3 conv via MFMA bf16 + BN + PReLU (+residual) ----------------
template <bool FINAL>
__global__ __launch_bounds__(256) void k_conv3m(const unsigned short* __restrict__ in_t,
                                                const unsigned short* __restrict__ Wk,
                                                const float* __restrict__ bnp,
                                                const float* __restrict__ pre,
                                                unsigned short* __restrict__ out_t,
                                                float* __restrict__ outf) {
    int bid = blockIdx.x;
    int b = bid >> 6;
    int p = bid & 63;
    int tid = threadIdx.x;
    int lane = tid & 63;
    int wv = tid >> 6;
    int oc0 = __builtin_amdgcn_readfirstlane(wv * 16);
    __shared__ unsigned short lds[3 * 66 * 64];

    short8 afrag[18];
    const unsigned short* wrow = Wk + (size_t)(oc0 + (lane & 15)) * 576 + ((lane >> 4) * 8);
#pragma unroll
    for (int s = 0; s < 18; s++) afrag[s] = *(const short8*)(wrow + s * 32);

    const unsigned short* ib = in_t + (size_t)b * 4096 * 64;
    for (int idx = tid; idx < 1584; idx += 256) {
        int pair = idx >> 3, c = idx & 7;
        int di = pair / 66, col = pair % 66;
        int r = p - 1 + di, q = col - 1;
        ushort8v v = {0, 0, 0, 0, 0, 0, 0, 0};
        if (r >= 0 && r < 64 && q >= 0 && q < 64)
            v = *(const ushort8v*)(ib + ((size_t)(r * 64 + q)) * 64 + c * 8);
        *(ushort8v*)(lds + pair * 64 + ((c ^ (col & 7)) * 8)) = v;
    }
    __syncthreads();

    f32x4 acc[4];
#pragma unroll
    for (int n0 = 0; n0 < 4; n0++) acc[n0] = (f32x4){0.f, 0.f, 0.f, 0.f};
#pragma unroll
    for (int s = 0; s < 18; s++) {
        const int shift = s >> 1, h = s & 1;
        const int di = shift / 3, dj = shift % 3;
#pragma unroll
        for (int n0 = 0; n0 < 4; n0++) {
            int col = n0 * 16 + (lane & 15) + dj;
            int off = (di * 66 + col) * 64 + (((h * 4 + (lane >> 4)) ^ (col & 7)) * 8);
            short8 bfrag = *(const short8*)(lds + off);
            acc[n0] = __builtin_amdgcn_mfma_f32_16x16x32_bf16(afrag[s], bfrag, acc[n0], 0, 0, 0);
        }
    }

    int ocb = oc0 + ((lane >> 4) << 2);
    float4 g4 = *(const float4*)(bnp + ocb);
    float4 be4 = *(const float4*)(bnp + 64 + ocb);
    float4 m4 = *(const float4*)(bnp + 128 + ocb);
    float4 v4 = *(const float4*)(bnp + 192 + ocb);
    float sc[4], sh[4];
    sc[0] = g4.x * rsqrtf(v4.x + EPS); sh[0] = be4.x - m4.x * sc[0];
    sc[1] = g4.y * rsqrtf(v4.y + EPS); sh[1] = be4.y - m4.y * sc[1];
    sc[2] = g4.z * rsqrtf(v4.z + EPS); sh[2] = be4.z - m4.z * sc[2];
    sc[3] = g4.w * rsqrtf(v4.w + EPS); sh[3] = be4.w - m4.w * sc[3];
    float pa = pre[0];
#pragma unroll
    for (int n0 = 0; n0 < 4; n0++) {
        int q = n0 * 16 + (lane & 15);
        float vals[4];
#pragma unroll
        for (int r = 0; r < 4; r++) {
            float v = fmaf(acc[n0][r], sc[r], sh[r]);
            vals[r] = v >= 0.f ? v : pa * v;
        }
        if (FINAL) {
#pragma unroll
            for (int r = 0; r < 4; r++) {
                size_t addr = ((size_t)b * 64 + ocb + r) * 4096 + p * 64 + q;
                outf[addr] = vals[r] + outf[addr];
            }
        } else {
            ushort4 u = make_ushort4(f2bf(vals[0]), f2bf(vals[1]), f2bf(vals[2]), f2bf(vals[3]));
            *(ushort4*)(out_t + ((size_t)b * 4096 + p * 64 + q) * 64 + ocb) = u;
        }
    }
}

extern "C" void kernel_launch(void* const* d_in, const int* in_sizes, int n_in,
                              void* d_out, int out_size, void* d_ws, size_t ws_size,
                              hipStream_t stream) {
    const float* x = (const float*)d_in[0];
    const float* in_proj_w = (const float*)d_in[1];
    const float* conv1d_w = (const float*)d_in[2];
    const float* conv1d_b = (const float*)d_in[3];
    const float* x_proj_w = (const float*)d_in[4];
    const float* dt_proj_w = (const float*)d_in[5];
    const float* dt_proj_b = (const float*)d_in[6];
    const float* A_log = (const float*)d_in[7];
    const float* Dp = (const float*)d_in[8];
    const float* out_proj_w = (const float*)d_in[9];
    const float* prelu_ssm = (const float*)d_in[10];
    const float* res_w = (const float*)d_in[11];
    const float* res_bn = (const float*)d_in[12];
    const float* conv1_w = (const float*)d_in[13];
    const float* bn1 = (const float*)d_in[14];
    const float* prelu1 = (const float*)d_in[15];
    const float* conv2_w = (const float*)d_in[16];
    const float* bn2 = (const float*)d_in[17];
    const float* prelu2 = (const float*)d_in[18];
    float* out = (float*)d_out;
    float* ws = (float*)d_ws;

    const size_t S = (size_t)BB * LL * DD;        // 4,194,304 floats
    const size_t HALF = S / 2;
    float* chH = ws;                              // [0, HALF)
    float* chP = ws + HALF;                       // [HALF, S)
    unsigned short* xmT = (unsigned short*)(ws + S);              // bf16 [b][ck][d][32]
    unsigned short* zT = (unsigned short*)(ws + S + HALF);        // bf16
    float* dtT = ws + 2 * S;                      // f32 [b][ck][d][32]
    unsigned short* Yb = (unsigned short*)(ws + 3 * S);           // bf16 (B,L,D)
    float* Bc2 = ws + 3 * S + HALF;               // S/8
    float* Cc2 = Bc2 + S / 8;                     // S/8
    unsigned short* img1t = (unsigned short*)ws;            // over chH, after s3
    unsigned short* img2t = (unsigned short*)(ws + HALF);   // over chP, after s2
    unsigned short* Wk1 = (unsigned short*)Bc2;             // over Bc2, after s3
    unsigned short* Wk2 = Wk1 + 36864;

    k_res<<<dim3(512), dim3(256), 0, stream>>>(x, res_w, res_bn, out);
    k_front<<<dim3(512), dim3(256), 0, stream>>>(x, in_proj_w, x_proj_w, conv1d_w, conv1d_b,
                                                 dt_proj_w, dt_proj_b,
                                                 xmT, zT, Bc2, Cc2, dtT);
    k_s1<<<dim3(512), dim3(256), 0, stream>>>(xmT, Bc2, dtT, A_log, chH, chP);
    k_s2<<<dim3(256), dim3(64), 0, stream>>>(chH, chP);
    k_s3<<<dim3(512), dim3(256), 0, stream>>>(xmT, zT, Bc2, Cc2, dtT, A_log, Dp, chH, Yb);
    k_outproj<<<dim3(512), dim3(256), 0, stream>>>(Yb, out_proj_w, prelu_ssm, img1t);
    k_wprep<<<dim3(288), dim3(256), 0, stream>>>(conv1_w, conv2_w, Wk1, Wk2);
    k_conv3m<false><<<dim3(512), dim3(256), 0, stream>>>(img1t, Wk1, bn1, prelu1, img2t, nullptr);
    k_conv3m<true><<<dim3(512), dim3(256), 0, stream>>>(img2t, Wk2, bn2, prelu2, nullptr, out);
}

// Round 11
// 143.388 us; speedup vs baseline: 1.4210x; 1.2272x over previous
//
#include <hip/hip_runtime.h>
#include <hip/hip_bf16.h>

#define BB 8
#define CC 64
#define LL 4096
#define DD 128
#define NN 16
#define EPS 1e-5f
#define NCH 128
#define CLEN 32

typedef short short8 __attribute__((ext_vector_type(8)));
typedef unsigned short ushort8v __attribute__((ext_vector_type(8)));
typedef float f32x4 __attribute__((ext_vector_type(4)));

__device__ __forceinline__ float silu_f(float v) {
    return v / (1.f + __expf(-v));
}
__device__ __forceinline__ float softplus_f(float t) {
    return fmaxf(t, 0.f) + __logf(1.f + __expf(-fabsf(t)));
}
__device__ __forceinline__ unsigned short f2bf(float f) {
    unsigned int u = __float_as_uint(f);
    u += 0x7fff + ((u >> 16) & 1);
    return (unsigned short)(u >> 16);
}
__device__ __forceinline__ float bf2f(unsigned short u) {
    return __uint_as_float(((unsigned int)u) << 16);
}

// ---------------- k_front: in_proj (MFMA) + conv1d + SiLU + x_proj (MFMA) + dt fused ----------------
// scan-facing outputs in chunk-transposed layout: xmT/zT bf16 [b][ck][d][32t], dtT f32 same
__global__ __launch_bounds__(256) void k_front(const float* __restrict__ x,
                                               const float* __restrict__ wip,
                                               const float* __restrict__ xw,
                                               const float* __restrict__ cw,
                                               const float* __restrict__ cb,
                                               const float* __restrict__ dtw,
                                               const float* __restrict__ dtb,
                                               unsigned short* __restrict__ xmT,
                                               unsigned short* __restrict__ zT,
                                               float* __restrict__ Bc2,
                                               float* __restrict__ Cc2,
                                               float* __restrict__ dtT) {
    int blk = blockIdx.x;                        // 512 = B * (L/64)
    int b = blk >> 6;
    int l0 = (blk & 63) << 6;
    int tid = threadIdx.x;
    int lane = tid & 63;
    int wv = __builtin_amdgcn_readfirstlane(tid >> 6);
    int l15 = lane & 15, l4g = lane >> 4;

    __shared__ unsigned short xt[80 * 64];
    __shared__ unsigned short xmf[80 * 132];     // later reused: first 256 floats = sdtp
    __shared__ unsigned short zf[64 * 132];
    __shared__ unsigned short xmc[64 * 128];
    float* sdtp = (float*)xmf;

    for (int idx = tid; idx < 5120; idx += 256) {
        int c = idx / 80;
        int j = idx - c * 80;
        int l = l0 - 3 + j;
        float v = (l >= 0 && l < LL) ? x[((size_t)b * CC + c) * LL + l] : 0.f;
        xt[j * 64 + (((c >> 3) ^ (j & 7)) * 8) + (c & 7)] = f2bf(v);
    }

    short8 af[4][2];
#pragma unroll
    for (int m0 = 0; m0 < 4; m0++) {
        const float* wr = wip + (size_t)(wv * 64 + m0 * 16 + l15) * 64 + l4g * 8;
#pragma unroll
        for (int h = 0; h < 2; h++) {
            float4 a0 = *(const float4*)(wr + h * 32);
            float4 a1 = *(const float4*)(wr + h * 32 + 4);
            short8 f;
            f[0] = (short)f2bf(a0.x); f[1] = (short)f2bf(a0.y);
            f[2] = (short)f2bf(a0.z); f[3] = (short)f2bf(a0.w);
            f[4] = (short)f2bf(a1.x); f[5] = (short)f2bf(a1.y);
            f[6] = (short)f2bf(a1.z); f[7] = (short)f2bf(a1.w);
            af[m0][h] = f;
        }
    }
    __syncthreads();

    f32x4 acc[4][5];
#pragma unroll
    for (int m0 = 0; m0 < 4; m0++)
#pragma unroll
        for (int n0 = 0; n0 < 5; n0++) acc[m0][n0] = (f32x4){0.f, 0.f, 0.f, 0.f};
#pragma unroll
    for (int n0 = 0; n0 < 5; n0++) {
        int j = n0 * 16 + l15;
#pragma unroll
        for (int h = 0; h < 2; h++) {
            short8 bf = *(const short8*)(xt + j * 64 + (((h * 4 + l4g) ^ (j & 7)) * 8));
#pragma unroll
            for (int m0 = 0; m0 < 4; m0++)
                acc[m0][n0] = __builtin_amdgcn_mfma_f32_16x16x32_bf16(af[m0][h], bf, acc[m0][n0], 0, 0, 0);
        }
    }

#pragma unroll
    for (int m0 = 0; m0 < 4; m0++)
#pragma unroll
        for (int n0 = 0; n0 < 5; n0++) {
            int j = n0 * 16 + l15;
            int d = (wv & 1) * 64 + m0 * 16 + l4g * 4;
            ushort4 u = make_ushort4(f2bf(acc[m0][n0][0]), f2bf(acc[m0][n0][1]),
                                     f2bf(acc[m0][n0][2]), f2bf(acc[m0][n0][3]));
            if (wv < 2) {
                *(ushort4*)(xmf + j * 132 + d) = u;
            } else {
                int t = j - 3;
                if (t >= 0 && t < 64) *(ushort4*)(zf + t * 132 + d) = u;
            }
        }
    __syncthreads();

    // ---- conv1d + SiLU; collect per-thread [4 d][8 t] then write chunk-transposed tiles ----
    {
        int d4 = (tid & 31) * 4;
        int tok0 = (tid >> 5) * 8;
        float4 w0 = *(const float4*)(cw + (d4 + 0) * 4);
        float4 w1 = *(const float4*)(cw + (d4 + 1) * 4);
        float4 w2 = *(const float4*)(cw + (d4 + 2) * 4);
        float4 w3 = *(const float4*)(cw + (d4 + 3) * 4);
        float4 cb4 = *(const float4*)(cb + d4);
        int kc = d4 >> 3;
        unsigned short xm_loc[4][8], z_loc[4][8];
#pragma unroll
        for (int tt = 0; tt < 8; tt++) {
            int tok = tok0 + tt;
            ushort4 r0 = *(const ushort4*)(xmf + (tok + 0) * 132 + d4);
            ushort4 r1 = *(const ushort4*)(xmf + (tok + 1) * 132 + d4);
            ushort4 r2 = *(const ushort4*)(xmf + (tok + 2) * 132 + d4);
            ushort4 r3 = *(const ushort4*)(xmf + (tok + 3) * 132 + d4);
            float v0 = cb4.x + w0.x * bf2f(r0.x) + w0.y * bf2f(r1.x) + w0.z * bf2f(r2.x) + w0.w * bf2f(r3.x);
            float v1 = cb4.y + w1.x * bf2f(r0.y) + w1.y * bf2f(r1.y) + w1.z * bf2f(r2.y) + w1.w * bf2f(r3.y);
            float v2 = cb4.z + w2.x * bf2f(r0.z) + w2.y * bf2f(r1.z) + w2.z * bf2f(r2.z) + w2.w * bf2f(r3.z);
            float v3 = cb4.w + w3.x * bf2f(r0.w) + w3.y * bf2f(r1.w) + w3.z * bf2f(r2.w) + w3.w * bf2f(r3.w);
            ushort4 o = make_ushort4(f2bf(silu_f(v0)), f2bf(silu_f(v1)), f2bf(silu_f(v2)), f2bf(silu_f(v3)));
            *(ushort4*)(xmc + tok * 128 + ((kc ^ (tok & 7)) * 8) + (d4 & 4)) = o;
            xm_loc[0][tt] = o.x; xm_loc[1][tt] = o.y; xm_loc[2][tt] = o.z; xm_loc[3][tt] = o.w;
            ushort4 zv = *(const ushort4*)(zf + tok * 132 + d4);
            z_loc[0][tt] = zv.x; z_loc[1][tt] = zv.y; z_loc[2][tt] = zv.z; z_loc[3][tt] = zv.w;
        }
        int ck = (l0 >> 5) + (tok0 >> 5);
        int tb = tok0 & 31;
#pragma unroll
        for (int r = 0; r < 4; r++) {
            size_t rowb = (((size_t)b * NCH + ck) * DD + d4 + r) * 32 + tb;
            ushort8v px, pz;
#pragma unroll
            for (int j = 0; j < 8; j++) { px[j] = xm_loc[r][j]; pz[j] = z_loc[r][j]; }
            *(ushort8v*)(xmT + rowb) = px;
            *(ushort8v*)(zT + rowb) = pz;
        }
    }
    __syncthreads();

    short8 pa_[3][4];
#pragma unroll
    for (int mt = 0; mt < 3; mt++) {
        int j = mt * 16 + l15;
#pragma unroll
        for (int ks = 0; ks < 4; ks++) {
            short8 f = {0, 0, 0, 0, 0, 0, 0, 0};
            if (j < 36) {
                const float* wr = xw + (size_t)j * 128 + ks * 32 + l4g * 8;
                float4 a0 = *(const float4*)(wr);
                float4 a1 = *(const float4*)(wr + 4);
                f[0] = (short)f2bf(a0.x); f[1] = (short)f2bf(a0.y);
                f[2] = (short)f2bf(a0.z); f[3] = (short)f2bf(a0.w);
                f[4] = (short)f2bf(a1.x); f[5] = (short)f2bf(a1.y);
                f[6] = (short)f2bf(a1.z); f[7] = (short)f2bf(a1.w);
            }
            pa_[mt][ks] = f;
        }
    }
    int t = wv * 16 + l15;
    f32x4 a3[3];
#pragma unroll
    for (int mt = 0; mt < 3; mt++) a3[mt] = (f32x4){0.f, 0.f, 0.f, 0.f};
#pragma unroll
    for (int ks = 0; ks < 4; ks++) {
        short8 bf = *(const short8*)(xmc + t * 128 + (((ks * 4 + l4g) ^ (t & 7)) * 8));
#pragma unroll
        for (int mt = 0; mt < 3; mt++)
            a3[mt] = __builtin_amdgcn_mfma_f32_16x16x32_bf16(pa_[mt][ks], bf, a3[mt], 0, 0, 0);
    }
    size_t bl = (size_t)b * LL + l0 + t;
    float4 o0 = make_float4(a3[0][0], a3[0][1], a3[0][2], a3[0][3]);
    float4 o1 = make_float4(a3[1][0], a3[1][1], a3[1][2], a3[1][3]);
    float4 o2 = make_float4(a3[2][0], a3[2][1], a3[2][2], a3[2][3]);
    if (l4g == 0) {
        *(float4*)(sdtp + t * 4) = o0;               // dtp -> LDS
        *(float4*)(Bc2 + bl * 16 + 12) = o1;
        *(float4*)(Cc2 + bl * 16 + 12) = o2;
    } else {
        *(float4*)(Bc2 + bl * 16 + (l4g - 1) * 4) = o0;
        *(float4*)(Cc2 + bl * 16 + (l4g - 1) * 4) = o1;
    }
    __syncthreads();

    // ---- dt = softplus(dtp @ dtw^T + dtb), write chunk-transposed f32 tiles ----
    {
        int d4 = (tid & 31) * 4;
        int tok0 = (tid >> 5) * 8;
        float4 w0 = *(const float4*)(dtw + (d4 + 0) * 4);
        float4 w1 = *(const float4*)(dtw + (d4 + 1) * 4);
        float4 w2 = *(const float4*)(dtw + (d4 + 2) * 4);
        float4 w3 = *(const float4*)(dtw + (d4 + 3) * 4);
        float4 b4 = *(const float4*)(dtb + d4);
        float dt_loc[4][8];
#pragma unroll
        for (int tt = 0; tt < 8; tt++) {
            float4 q = *(const float4*)(sdtp + (tok0 + tt) * 4);
            dt_loc[0][tt] = softplus_f(b4.x + q.x * w0.x + q.y * w0.y + q.z * w0.z + q.w * w0.w);
            dt_loc[1][tt] = softplus_f(b4.y + q.x * w1.x + q.y * w1.y + q.z * w1.z + q.w * w1.w);
            dt_loc[2][tt] = softplus_f(b4.z + q.x * w2.x + q.y * w2.y + q.z * w2.z + q.w * w2.w);
            dt_loc[3][tt] = softplus_f(b4.w + q.x * w3.x + q.y * w3.y + q.z * w3.z + q.w * w3.w);
        }
        int ck = (l0 >> 5) + (tok0 >> 5);
        int tb = tok0 & 31;
#pragma unroll
        for (int r = 0; r < 4; r++) {
            size_t rowb = (((size_t)b * NCH + ck) * DD + d4 + r) * 32 + tb;
            *(float4*)(dtT + rowb) = make_float4(dt_loc[r][0], dt_loc[r][1], dt_loc[r][2], dt_loc[r][3]);
            *(float4*)(dtT + rowb + 4) = make_float4(dt_loc[r][4], dt_loc[r][5], dt_loc[r][6], dt_loc[r][7]);
        }
    }
}

// ---------------- Scan pass 1: block = 2 chunks x 2 dh; vectorized chunk loads ----------------
__global__ __launch_bounds__(256) void k_s1(const unsigned short* __restrict__ xmT,
                                            const float* __restrict__ Bc2,
                                            const float* __restrict__ dtT,
                                            const float* __restrict__ A_log,
                                            float* __restrict__ chH,
                                            float* __restrict__ chP) {
    int b = blockIdx.x >> 6;                     // 512 blocks
    int ckp = blockIdx.x & 63;
    int w = __builtin_amdgcn_readfirstlane(threadIdx.x >> 6);
    int lane = threadIdx.x & 63;
    int ck = ckp * 2 + (w >> 1);
    int dh = w & 1;
    int d = dh * 64 + lane;

    __shared__ float sB[64][16];
    {
        int l = threadIdx.x >> 2, q = threadIdx.x & 3;
        *(float4*)(&sB[l][q * 4]) = *(const float4*)(Bc2 + ((size_t)b * LL + ckp * 64 + l) * 16 + q * 4);
    }

    float a2[16];
#pragma unroll
    for (int j = 0; j < 4; j++) {
        float4 v = *(const float4*)(A_log + d * 16 + j * 4);
        a2[j * 4 + 0] = -__expf(v.x) * 1.4426950408889634f;
        a2[j * 4 + 1] = -__expf(v.y) * 1.4426950408889634f;
        a2[j * 4 + 2] = -__expf(v.z) * 1.4426950408889634f;
        a2[j * 4 + 3] = -__expf(v.w) * 1.4426950408889634f;
    }
    size_t rowb = (((size_t)b * NCH + ck) * DD + d) * 32;
    unsigned short xms[32];
    float dts[32];
#pragma unroll
    for (int j = 0; j < 4; j++) {
        ushort8v v = *(const ushort8v*)(xmT + rowb + j * 8);
#pragma unroll
        for (int e = 0; e < 8; e++) xms[j * 8 + e] = v[e];
    }
#pragma unroll
    for (int j = 0; j < 8; j++) {
        float4 v = *(const float4*)(dtT + rowb + j * 4);
        dts[j * 4 + 0] = v.x; dts[j * 4 + 1] = v.y; dts[j * 4 + 2] = v.z; dts[j * 4 + 3] = v.w;
    }

    float h[16];
#pragma unroll
    for (int n = 0; n < 16; n++) h[n] = 0.f;
    float sdt = 0.f;
    int lb = (w >> 1) * 32;
    __syncthreads();
#pragma unroll
    for (int t = 0; t < CLEN; t++) {
        float xmv = bf2f(xms[t]);
        float dtv = dts[t];
        float dx = dtv * xmv;
        const float* Br = &sB[lb + t][0];
        sdt += dtv;
#pragma unroll
        for (int n = 0; n < 16; n++) {
            float dA = exp2f(dtv * a2[n]);
            h[n] = fmaf(dA, h[n], dx * Br[n]);
        }
    }
    size_t cbase = ((size_t)((b * 2 + dh) * NCH + ck)) * 1024 + lane * 16;
#pragma unroll
    for (int j = 0; j < 4; j++) {
        *(float4*)(chH + cbase + j * 4) = make_float4(h[j * 4], h[j * 4 + 1], h[j * 4 + 2], h[j * 4 + 3]);
        *(float4*)(chP + cbase + j * 4) = make_float4(exp2f(a2[j * 4] * sdt), exp2f(a2[j * 4 + 1] * sdt),
                                                      exp2f(a2[j * 4 + 2] * sdt), exp2f(a2[j * 4 + 3] * sdt));
    }
}

// ---------------- Scan pass 2: 16384 scalar recurrences over 128 chunks ----------------
__global__ __launch_bounds__(64) void k_s2(float* __restrict__ chH,
                                           const float* __restrict__ chP) {
    int t = blockIdx.x * 64 + threadIdx.x;   // 0..16383
    int row = t >> 10;
    int q = t & 1023;
    size_t base = (size_t)row * NCH * 1024 + q;
    float H = 0.f;
#pragma unroll 8
    for (int ck = 0; ck < NCH; ck++) {
        size_t a = base + (size_t)ck * 1024;
        float h = chH[a];
        float p = chP[a];
        chH[a] = H;
        H = fmaf(p, H, h);
    }
}

// ---------------- Scan pass 3 + out_proj: block = 2 chunks x 2 dh; epilogue MFMA -> img1t ----------------
__global__ __launch_bounds__(256) void k_s3(const unsigned short* __restrict__ xmT,
                                            const unsigned short* __restrict__ zT,
                                            const float* __restrict__ Bc2,
                                            const float* __restrict__ Cc2,
                                            const float* __restrict__ dtT,
                                            const float* __restrict__ A_log,
                                            const float* __restrict__ Dpp,
                                            const float* __restrict__ hinit,
                                            const float* __restrict__ wo,
                                            const float* __restrict__ pre,
                                            unsigned short* __restrict__ img1t) {
    int b = blockIdx.x >> 6;
    int ckp = blockIdx.x & 63;
    int w = __builtin_amdgcn_readfirstlane(threadIdx.x >> 6);
    int lane = threadIdx.x & 63;
    int ck = ckp * 2 + (w >> 1);
    int dh = w & 1;
    int d = dh * 64 + lane;
    int l15 = lane & 15, l4g = lane >> 4;

    __shared__ float sB[64][16];
    __shared__ float sC[64][16];
    __shared__ unsigned short sYt[64 * 128];     // [token][d], swizzled 8-chunks
    {
        int l = threadIdx.x >> 2, q = threadIdx.x & 3;
        *(float4*)(&sB[l][q * 4]) = *(const float4*)(Bc2 + ((size_t)b * LL + ckp * 64 + l) * 16 + q * 4);
        *(float4*)(&sC[l][q * 4]) = *(const float4*)(Cc2 + ((size_t)b * LL + ckp * 64 + l) * 16 + q * 4);
    }

    float a2[16];
#pragma unroll
    for (int j = 0; j < 4; j++) {
        float4 v = *(const float4*)(A_log + d * 16 + j * 4);
        a2[j * 4 + 0] = -__expf(v.x) * 1.4426950408889634f;
        a2[j * 4 + 1] = -__expf(v.y) * 1.4426950408889634f;
        a2[j * 4 + 2] = -__expf(v.z) * 1.4426950408889634f;
        a2[j * 4 + 3] = -__expf(v.w) * 1.4426950408889634f;
    }
    float Dpd = Dpp[d];
    size_t cbase = ((size_t)((b * 2 + dh) * NCH + ck)) * 1024 + lane * 16;
    float h[16];
#pragma unroll
    for (int j = 0; j < 4; j++) {
        float4 v = *(const float4*)(hinit + cbase + j * 4);
        h[j * 4 + 0] = v.x; h[j * 4 + 1] = v.y; h[j * 4 + 2] = v.z; h[j * 4 + 3] = v.w;
    }

    size_t rowb = (((size_t)b * NCH + ck) * DD + d) * 32;
    unsigned short xms[32], zs[32];
    float dts[32];
#pragma unroll
    for (int j = 0; j < 4; j++) {
        ushort8v v = *(const ushort8v*)(xmT + rowb + j * 8);
        ushort8v vz = *(const ushort8v*)(zT + rowb + j * 8);
#pragma unroll
        for (int e = 0; e < 8; e++) { xms[j * 8 + e] = v[e]; zs[j * 8 + e] = vz[e]; }
    }
#pragma unroll
    for (int j = 0; j < 8; j++) {
        float4 v = *(const float4*)(dtT + rowb + j * 4);
        dts[j * 4 + 0] = v.x; dts[j * 4 + 1] = v.y; dts[j * 4 + 2] = v.z; dts[j * 4 + 3] = v.w;
    }

    // out_proj A fragments while scan data loads: wave m-tile = 16 oc (oc0 = w*16)
    int oc0 = w * 16;
    short8 pao[4];
#pragma unroll
    for (int ks = 0; ks < 4; ks++) {
        const float* wr = wo + (size_t)(oc0 + l15) * 128 + ks * 32 + l4g * 8;
        float4 a0 = *(const float4*)(wr);
        float4 a1 = *(const float4*)(wr + 4);
        short8 f;
        f[0] = (short)f2bf(a0.x); f[1] = (short)f2bf(a0.y);
        f[2] = (short)f2bf(a0.z); f[3] = (short)f2bf(a0.w);
        f[4] = (short)f2bf(a1.x); f[5] = (short)f2bf(a1.y);
        f[6] = (short)f2bf(a1.z); f[7] = (short)f2bf(a1.w);
        pao[ks] = f;
    }

    int lb = (w >> 1) * 32;
    int cperm = d >> 3;
    __syncthreads();
#pragma unroll
    for (int t = 0; t < CLEN; t++) {
        float xmv = bf2f(xms[t]);
        float zv = bf2f(zs[t]);
        float dtv = dts[t];
        float dx = dtv * xmv;
        const float* Br = &sB[lb + t][0];
        const float* Cr = &sC[lb + t][0];
        float y0 = 0.f, y1 = 0.f, y2 = 0.f, y3 = 0.f;
#pragma unroll
        for (int n = 0; n < 16; n += 4) {
            float dA0 = exp2f(dtv * a2[n]);
            float dA1 = exp2f(dtv * a2[n + 1]);
            float dA2 = exp2f(dtv * a2[n + 2]);
            float dA3 = exp2f(dtv * a2[n + 3]);
            h[n] = fmaf(dA0, h[n], dx * Br[n]);
            h[n + 1] = fmaf(dA1, h[n + 1], dx * Br[n + 1]);
            h[n + 2] = fmaf(dA2, h[n + 2], dx * Br[n + 2]);
            h[n + 3] = fmaf(dA3, h[n + 3], dx * Br[n + 3]);
            y0 = fmaf(h[n], Cr[n], y0);
            y1 = fmaf(h[n + 1], Cr[n + 1], y1);
            y2 = fmaf(h[n + 2], Cr[n + 2], y2);
            y3 = fmaf(h[n + 3], Cr[n + 3], y3);
        }
        float yv = (y0 + y1) + (y2 + y3);
        yv = fmaf(xmv, Dpd, yv);
        int lt = lb + t;
        sYt[lt * 128 + ((cperm ^ (lt & 7)) * 8) + (d & 7)] = f2bf(yv * silu_f(zv));
    }
    __syncthreads();

    // ---- out_proj MFMA: M=16 oc (this wave), N=64 tokens, K=128 ----
    f32x4 po[4];
#pragma unroll
    for (int n0 = 0; n0 < 4; n0++) po[n0] = (f32x4){0.f, 0.f, 0.f, 0.f};
#pragma unroll
    for (int ks = 0; ks < 4; ks++) {
#pragma unroll
        for (int n0 = 0; n0 < 4; n0++) {
            int j = n0 * 16 + l15;
            short8 bf = *(const short8*)(sYt + j * 128 + (((ks * 4 + l4g) ^ (j & 7)) * 8));
            po[n0] = __builtin_amdgcn_mfma_f32_16x16x32_bf16(pao[ks], bf, po[n0], 0, 0, 0);
        }
    }
    float pa = pre[0];
    int ocb = oc0 + (l4g << 2);
#pragma unroll
    for (int n0 = 0; n0 < 4; n0++) {
        int tj = n0 * 16 + l15;
        int px = tj * 64 + ckp;                  // l = ckp*64+tj -> px=(l&63)*64+(l>>6)
        ushort4 u;
        float v0 = po[n0][0]; v0 = v0 >= 0.f ? v0 : pa * v0;
        float v1 = po[n0][1]; v1 = v1 >= 0.f ? v1 : pa * v1;
        float v2 = po[n0][2]; v2 = v2 >= 0.f ? v2 : pa * v2;
        float v3 = po[n0][3]; v3 = v3 >= 0.f ? v3 : pa * v3;
        u = make_ushort4(f2bf(v0), f2bf(v1), f2bf(v2), f2bf(v3));
        *(ushort4*)(img1t + ((size_t)b * 4096 + px) * 64 + ocb) = u;
    }
}

// ---------------- weight prep: Wk[oc][shift*64+ic] bf16 for both 3x3 convs ----------------
__global__ __launch_bounds__(256) void k_wprep(const float* __restrict__ w1,
                                               const float* __restrict__ w2,
                                               unsigned short* __restrict__ Wk1,
                                               unsigned short* __restrict__ Wk2) {
    int idx = blockIdx.x * 256 + threadIdx.x;
    if (idx >= 2 * 36864) return;
    const float* w = (idx < 36864) ? w1 : w2;
    unsigned short* dst = (idx < 36864) ? Wk1 : Wk2;
    int r = (idx < 36864) ? idx : idx - 36864;
    int oc = r / 576, k = r % 576;
    int shift = k >> 6, ic = k & 63;
    dst[oc * 576 + k] = f2bf(w[(oc * 64 + ic) * 9 + shift]);
}

// ---------------- K5: 3x3 conv via MFMA bf16 + BN + PReLU -> img2t bf16 ----------------
__global__ __launch_bounds__(256) void k_conv3m(const unsigned short* __restrict__ in_t,
                                                const unsigned short* __restrict__ Wk,
                                                const float* __restrict__ bnp,
                                                const float* __restrict__ pre,
                                                unsigned short* __restrict__ out_t) {
    int bid = blockIdx.x;
    int b = bid >> 6;
    int p = bid & 63;
    int tid = threadIdx.x;
    int lane = tid & 63;
    int wv = tid >> 6;
    int oc0 = __builtin_amdgcn_readfirstlane(wv * 16);
    __shared__ unsigned short lds[3 * 66 * 64];

    short8 afrag[18];
    const unsigned short* wrow = Wk + (size_t)(oc0 + (lane & 15)) * 576 + ((lane >> 4) * 8);
#pragma unroll
    for (int s = 0; s < 18; s++) afrag[s] = *(const short8*)(wrow + s * 32);

    const unsigned short* ib = in_t + (size_t)b * 4096 * 64;
    for (int idx = tid; idx < 1584; idx += 256) {
        int pair = idx >> 3, c = idx & 7;
        int di = pair / 66, col = pair % 66;
        int r = p - 1 + di, q = col - 1;
        ushort8v v = {0, 0, 0, 0, 0, 0, 0, 0};
        if (r >= 0 && r < 64 && q >= 0 && q < 64)
            v = *(const ushort8v*)(ib + ((size_t)(r * 64 + q)) * 64 + c * 8);
        *(ushort8v*)(lds + pair * 64 + ((c ^ (col & 7)) * 8)) = v;
    }
    __syncthreads();

    f32x4 acc[4];
#pragma unroll
    for (int n0 = 0; n0 < 4; n0++) acc[n0] = (f32x4){0.f, 0.f, 0.f, 0.f};
#pragma unroll
    for (int s = 0; s < 18; s++) {
        const int shift = s >> 1, h = s & 1;
        const int di = shift / 3, dj = shift % 3;
#pragma unroll
        for (int n0 = 0; n0 < 4; n0++) {
            int col = n0 * 16 + (lane & 15) + dj;
            int off = (di * 66 + col) * 64 + (((h * 4 + (lane >> 4)) ^ (col & 7)) * 8);
            short8 bfrag = *(const short8*)(lds + off);
            acc[n0] = __builtin_amdgcn_mfma_f32_16x16x32_bf16(afrag[s], bfrag, acc[n0], 0, 0, 0);
        }
    }

    int ocb = oc0 + ((lane >> 4) << 2);
    float4 g4 = *(const float4*)(bnp + ocb);
    float4 be4 = *(const float4*)(bnp + 64 + ocb);
    float4 m4 = *(const float4*)(bnp + 128 + ocb);
    float4 v4 = *(const float4*)(bnp + 192 + ocb);
    float sc[4], sh[4];
    sc[0] = g4.x * rsqrtf(v4.x + EPS); sh[0] = be4.x - m4.x * sc[0];
    sc[1] = g4.y * rsqrtf(v4.y + EPS); sh[1] = be4.y - m4.y * sc[1];
    sc[2] = g4.z * rsqrtf(v4.z + EPS); sh[2] = be4.z - m4.z * sc[2];
    sc[3] = g4.w * rsqrtf(v4.w + EPS); sh[3] = be4.w - m4.w * sc[3];
    float pa = pre[0];
#pragma unroll
    for (int n0 = 0; n0 < 4; n0++) {
        int q = n0 * 16 + (lane & 15);
        float vals[4];
#pragma unroll
        for (int r = 0; r < 4; r++) {
            float v = fmaf(acc[n0][r], sc[r], sh[r]);
            vals[r] = v >= 0.f ? v : pa * v;
        }
        ushort4 u = make_ushort4(f2bf(vals[0]), f2bf(vals[1]), f2bf(vals[2]), f2bf(vals[3]));
        *(ushort4*)(out_t + ((size_t)b * 4096 + p * 64 + q) * 64 + ocb) = u;
    }
}

// ---------------- K6: 3x3 conv + BN + PReLU + fused residual(1x1 conv+BN on x) -> f32 out ----------------
__global__ __launch_bounds__(256) void k_conv3f(const unsigned short* __restrict__ in_t,
                                                const unsigned short* __restrict__ Wk,
                                                const float* __restrict__ bnp,
                                                const float* __restrict__ pre,
                                                const float* __restrict__ x,
                                                const float* __restrict__ rw,
                                                const float* __restrict__ rbn,
                                                float* __restrict__ outf) {
    int bid = blockIdx.x;
    int b = bid >> 6;
    int p = bid & 63;
    int tid = threadIdx.x;
    int lane = tid & 63;
    int wv = tid >> 6;
    int oc0 = __builtin_amdgcn_readfirstlane(wv * 16);
    int l15 = lane & 15, l4g = lane >> 4;
    __shared__ unsigned short lds[3 * 66 * 64];
    __shared__ unsigned short xr[64 * 64];       // x row-tile [q][ic], swizzled

    short8 afrag[18];
    const unsigned short* wrow = Wk + (size_t)(oc0 + l15) * 576 + (l4g * 8);
#pragma unroll
    for (int s = 0; s < 18; s++) afrag[s] = *(const short8*)(wrow + s * 32);

    // residual A fragments: res_w rows oc0+l15, K=64
    short8 arf[2];
#pragma unroll
    for (int hh = 0; hh < 2; hh++) {
        const float* wr = rw + (size_t)(oc0 + l15) * 64 + hh * 32 + l4g * 8;
        float4 a0 = *(const float4*)(wr);
        float4 a1 = *(const float4*)(wr + 4);
        short8 f;
        f[0] = (short)f2bf(a0.x); f[1] = (short)f2bf(a0.y);
        f[2] = (short)f2bf(a0.z); f[3] = (short)f2bf(a0.w);
        f[4] = (short)f2bf(a1.x); f[5] = (short)f2bf(a1.y);
        f[6] = (short)f2bf(a1.z); f[7] = (short)f2bf(a1.w);
        arf[hh] = f;
    }

    const unsigned short* ib = in_t + (size_t)b * 4096 * 64;
    for (int idx = tid; idx < 1584; idx += 256) {
        int pair = idx >> 3, c = idx & 7;
        int di = pair / 66, col = pair % 66;
        int r = p - 1 + di, q = col - 1;
        ushort8v v = {0, 0, 0, 0, 0, 0, 0, 0};
        if (r >= 0 && r < 64 && q >= 0 && q < 64)
            v = *(const ushort8v*)(ib + ((size_t)(r * 64 + q)) * 64 + c * 8);
        *(ushort8v*)(lds + pair * 64 + ((c ^ (col & 7)) * 8)) = v;
    }
    // stage x row-tile: 64 ic x 64 q
    for (int idx = tid; idx < 4096; idx += 256) {
        int ic = idx >> 6, q = idx & 63;
        float v = x[((size_t)b * 64 + ic) * 4096 + p * 64 + q];
        xr[q * 64 + (((ic >> 3) ^ (q & 7)) * 8) + (ic & 7)] = f2bf(v);
    }
    __syncthreads();

    f32x4 acc[4], accr[4];
#pragma unroll
    for (int n0 = 0; n0 < 4; n0++) {
        acc[n0] = (f32x4){0.f, 0.f, 0.f, 0.f};
        accr[n0] = (f32x4){0.f, 0.f, 0.f, 0.f};
    }
#pragma unroll
    for (int s = 0; s < 18; s++) {
        const int shift = s >> 1, h = s & 1;
        const int di = shift / 3, dj = shift % 3;
#pragma unroll
        for (int n0 = 0; n0 < 4; n0++) {
            int col = n0 * 16 + l15 + dj;
            int off = (di * 66 + col) * 64 + (((h * 4 + l4g) ^ (col & 7)) * 8);
            short8 bfrag = *(const short8*)(lds + off);
            acc[n0] = __builtin_amdgcn_mfma_f32_16x16x32_bf16(afrag[s], bfrag, acc[n0], 0, 0, 0);
        }
    }
#pragma unroll
    for (int hh = 0; hh < 2; hh++) {
#pragma unroll
        for (int n0 = 0; n0 < 4; n0++) {
            int j = n0 * 16 + l15;
            short8 bfr = *(const short8*)(xr + j * 64 + (((hh * 4 + l4g) ^ (j & 7)) * 8));
            accr[n0] = __builtin_amdgcn_mfma_f32_16x16x32_bf16(arf[hh], bfr, accr[n0], 0, 0, 0);
        }
    }

    int ocb = oc0 + (l4g << 2);
    float4 g4 = *(const float4*)(bnp + ocb);
    float4 be4 = *(const float4*)(bnp + 64 + ocb);
    float4 m4 = *(const float4*)(bnp + 128 + ocb);
    float4 v4 = *(const float4*)(bnp + 192 + ocb);
    float sc[4], sh[4];
    sc[0] = g4.x * rsqrtf(v4.x + EPS); sh[0] = be4.x - m4.x * sc[0];
    sc[1] = g4.y * rsqrtf(v4.y + EPS); sh[1] = be4.y - m4.y * sc[1];
    sc[2] = g4.z * rsqrtf(v4.z + EPS); sh[2] = be4.z - m4.z * sc[2];
    sc[3] = g4.w * rsqrtf(v4.w + EPS); sh[3] = be4.w - m4.w * sc[3];
    float4 rg4 = *(const float4*)(rbn + ocb);
    float4 rbe4 = *(const float4*)(rbn + 64 + ocb);
    float4 rm4 = *(const float4*)(rbn + 128 + ocb);
    float4 rv4 = *(const float4*)(rbn + 192 + ocb);
    float rsc[4], rsh[4];
    rsc[0] = rg4.x * rsqrtf(rv4.x + EPS); rsh[0] = rbe4.x - rm4.x * rsc[0];
    rsc[1] = rg4.y * rsqrtf(rv4.y + EPS); rsh[1] = rbe4.y - rm4.y * rsc[1];
    rsc[2] = rg4.z * rsqrtf(rv4.z + EPS); rsh[2] = rbe4.z - rm4.z * rsc[2];
    rsc[3] = rg4.w * rsqrtf(rv4.w + EPS); rsh[3] = rbe4.w - rm4.w * rsc[3];
    float pa = pre[0];
#pragma unroll
    for (int n0 = 0; n0 < 4; n0++) {
        int q = n0 * 16 + l15;
#pragma unroll
        for (int r = 0; r < 4; r++) {
            float v = fmaf(acc[n0][r], sc[r], sh[r]);
            v = v >= 0.f ? v : pa * v;
            float rv = fmaf(accr[n0][r], rsc[r], rsh[r]);
            size_t addr = ((size_t)b * 64 + ocb + r) * 4096 + p * 64 + q;
            outf[addr] = v + rv;
        }
    }
}

extern "C" void kernel_launch(void* const* d_in, const int* in_sizes, int n_in,
                              void* d_out, int out_size, void* d_ws, size_t ws_size,
                              hipStream_t stream) {
    const float* x = (const float*)d_in[0];
    const float* in_proj_w = (const float*)d_in[1];
    const float* conv1d_w = (const float*)d_in[2];
    const float* conv1d_b = (const float*)d_in[3];
    const float* x_proj_w = (const float*)d_in[4];
    const float* dt_proj_w = (const float*)d_in[5];
    const float* dt_proj_b = (const float*)d_in[6];
    const float* A_log = (const float*)d_in[7];
    const float* Dp = (const float*)d_in[8];
    const float* out_proj_w = (const float*)d_in[9];
    const float* prelu_ssm = (const float*)d_in[10];
    const float* res_w = (const float*)d_in[11];
    const float* res_bn = (const float*)d_in[12];
    const float* conv1_w = (const float*)d_in[13];
    const float* bn1 = (const float*)d_in[14];
    const float* prelu1 = (const float*)d_in[15];
    const float* conv2_w = (const float*)d_in[16];
    const float* bn2 = (const float*)d_in[17];
    const float* prelu2 = (const float*)d_in[18];
    float* out = (float*)d_out;
    float* ws = (float*)d_ws;

    const size_t S = (size_t)BB * LL * DD;        // 4,194,304 floats
    const size_t HALF = S / 2;
    float* chH = ws;                              // [0, HALF)    live s1..s3
    float* chP = ws + HALF;                       // [HALF, S)    live s1..s2
    unsigned short* xmT = (unsigned short*)(ws + S);              // bf16 [b][ck][d][32]
    unsigned short* zT = (unsigned short*)(ws + S + HALF);        // bf16
    float* dtT = ws + 2 * S;                      // f32 [b][ck][d][32]
    unsigned short* img1t = (unsigned short*)(ws + 3 * S);        // bf16 [b][px][64]
    float* Bc2 = ws + 3 * S + S / 4;              // S/8
    float* Cc2 = Bc2 + S / 8;                     // S/8
    unsigned short* Wk1 = (unsigned short*)(Cc2 + S / 8);         // 36864 bf16 each
    unsigned short* Wk2 = Wk1 + 36864;
    unsigned short* img2t = (unsigned short*)(ws + HALF);         // over chP, after s2

    k_front<<<dim3(512), dim3(256), 0, stream>>>(x, in_proj_w, x_proj_w, conv1d_w, conv1d_b,
                                                 dt_proj_w, dt_proj_b,
                                                 xmT, zT, Bc2, Cc2, dtT);
    k_wprep<<<dim3(288), dim3(256), 0, stream>>>(conv1_w, conv2_w, Wk1, Wk2);
    k_s1<<<dim3(512), dim3(256), 0, stream>>>(xmT, Bc2, dtT, A_log, chH, chP);
    k_s2<<<dim3(256), dim3(64), 0, stream>>>(chH, chP);
    k_s3<<<dim3(512), dim3(256), 0, stream>>>(xmT, zT, Bc2, Cc2, dtT, A_log, Dp, chH,
                                              out_proj_w, prelu_ssm, img1t);
    k_conv3m<<<dim3(512), dim3(256), 0, stream>>>(img1t, Wk1, bn1, prelu1, img2t);
    k_conv3f<<<dim3(512), dim3(256), 0, stream>>>(img2t, Wk2, bn2, prelu2, x, res_w, res_bn, out);
}

// Round 12
// 133.891 us; speedup vs baseline: 1.5218x; 1.0709x over previous
//
#include <hip/hip_runtime.h>
#include <hip/hip_bf16.h>

#define BB 8
#define CC 64
#define LL 4096
#define DD 128
#define NN 16
#define EPS 1e-5f
#define NCH 128
#define CLEN 32

typedef short short8 __attribute__((ext_vector_type(8)));
typedef unsigned short ushort8v __attribute__((ext_vector_type(8)));
typedef float f32x4 __attribute__((ext_vector_type(4)));

__device__ __forceinline__ float silu_f(float v) {
    return v / (1.f + __expf(-v));
}
__device__ __forceinline__ float softplus_f(float t) {
    return fmaxf(t, 0.f) + __logf(1.f + __expf(-fabsf(t)));
}
__device__ __forceinline__ unsigned short f2bf(float f) {
    unsigned int u = __float_as_uint(f);
    u += 0x7fff + ((u >> 16) & 1);
    return (unsigned short)(u >> 16);
}
__device__ __forceinline__ float bf2f(unsigned short u) {
    return __uint_as_float(((unsigned int)u) << 16);
}

// ---------------- k_front: in_proj (MFMA) + conv1d + SiLU + x_proj (MFMA) + dt fused ----------------
__global__ __launch_bounds__(256) void k_front(const float* __restrict__ x,
                                               const float* __restrict__ wip,
                                               const float* __restrict__ xw,
                                               const float* __restrict__ cw,
                                               const float* __restrict__ cb,
                                               const float* __restrict__ dtw,
                                               const float* __restrict__ dtb,
                                               unsigned short* __restrict__ xmT,
                                               unsigned short* __restrict__ zT,
                                               float* __restrict__ Bc2,
                                               float* __restrict__ Cc2,
                                               float* __restrict__ dtT) {
    int blk = blockIdx.x;                        // 512 = B * (L/64)
    int b = blk >> 6;
    int l0 = (blk & 63) << 6;
    int tid = threadIdx.x;
    int lane = tid & 63;
    int wv = __builtin_amdgcn_readfirstlane(tid >> 6);
    int l15 = lane & 15, l4g = lane >> 4;

    __shared__ unsigned short xt[80 * 64];
    __shared__ unsigned short xmf[80 * 132];     // later reused: first 256 floats = sdtp
    __shared__ unsigned short zf[64 * 132];
    __shared__ unsigned short xmc[64 * 128];
    float* sdtp = (float*)xmf;

    for (int idx = tid; idx < 5120; idx += 256) {
        int c = idx / 80;
        int j = idx - c * 80;
        int l = l0 - 3 + j;
        float v = (l >= 0 && l < LL) ? x[((size_t)b * CC + c) * LL + l] : 0.f;
        xt[j * 64 + (((c >> 3) ^ (j & 7)) * 8) + (c & 7)] = f2bf(v);
    }

    short8 af[4][2];
#pragma unroll
    for (int m0 = 0; m0 < 4; m0++) {
        const float* wr = wip + (size_t)(wv * 64 + m0 * 16 + l15) * 64 + l4g * 8;
#pragma unroll
        for (int h = 0; h < 2; h++) {
            float4 a0 = *(const float4*)(wr + h * 32);
            float4 a1 = *(const float4*)(wr + h * 32 + 4);
            short8 f;
            f[0] = (short)f2bf(a0.x); f[1] = (short)f2bf(a0.y);
            f[2] = (short)f2bf(a0.z); f[3] = (short)f2bf(a0.w);
            f[4] = (short)f2bf(a1.x); f[5] = (short)f2bf(a1.y);
            f[6] = (short)f2bf(a1.z); f[7] = (short)f2bf(a1.w);
            af[m0][h] = f;
        }
    }
    __syncthreads();

    f32x4 acc[4][5];
#pragma unroll
    for (int m0 = 0; m0 < 4; m0++)
#pragma unroll
        for (int n0 = 0; n0 < 5; n0++) acc[m0][n0] = (f32x4){0.f, 0.f, 0.f, 0.f};
#pragma unroll
    for (int n0 = 0; n0 < 5; n0++) {
        int j = n0 * 16 + l15;
#pragma unroll
        for (int h = 0; h < 2; h++) {
            short8 bf = *(const short8*)(xt + j * 64 + (((h * 4 + l4g) ^ (j & 7)) * 8));
#pragma unroll
            for (int m0 = 0; m0 < 4; m0++)
                acc[m0][n0] = __builtin_amdgcn_mfma_f32_16x16x32_bf16(af[m0][h], bf, acc[m0][n0], 0, 0, 0);
        }
    }

#pragma unroll
    for (int m0 = 0; m0 < 4; m0++)
#pragma unroll
        for (int n0 = 0; n0 < 5; n0++) {
            int j = n0 * 16 + l15;
            int d = (wv & 1) * 64 + m0 * 16 + l4g * 4;
            ushort4 u = make_ushort4(f2bf(acc[m0][n0][0]), f2bf(acc[m0][n0][1]),
                                     f2bf(acc[m0][n0][2]), f2bf(acc[m0][n0][3]));
            if (wv < 2) {
                *(ushort4*)(xmf + j * 132 + d) = u;
            } else {
                int t = j - 3;
                if (t >= 0 && t < 64) *(ushort4*)(zf + t * 132 + d) = u;
            }
        }
    __syncthreads();

    // ---- conv1d + SiLU; collect per-thread [4 d][8 t] then write chunk-transposed tiles ----
    {
        int d4 = (tid & 31) * 4;
        int tok0 = (tid >> 5) * 8;
        float4 w0 = *(const float4*)(cw + (d4 + 0) * 4);
        float4 w1 = *(const float4*)(cw + (d4 + 1) * 4);
        float4 w2 = *(const float4*)(cw + (d4 + 2) * 4);
        float4 w3 = *(const float4*)(cw + (d4 + 3) * 4);
        float4 cb4 = *(const float4*)(cb + d4);
        int kc = d4 >> 3;
        unsigned short xm_loc[4][8], z_loc[4][8];
#pragma unroll
        for (int tt = 0; tt < 8; tt++) {
            int tok = tok0 + tt;
            ushort4 r0 = *(const ushort4*)(xmf + (tok + 0) * 132 + d4);
            ushort4 r1 = *(const ushort4*)(xmf + (tok + 1) * 132 + d4);
            ushort4 r2 = *(const ushort4*)(xmf + (tok + 2) * 132 + d4);
            ushort4 r3 = *(const ushort4*)(xmf + (tok + 3) * 132 + d4);
            float v0 = cb4.x + w0.x * bf2f(r0.x) + w0.y * bf2f(r1.x) + w0.z * bf2f(r2.x) + w0.w * bf2f(r3.x);
            float v1 = cb4.y + w1.x * bf2f(r0.y) + w1.y * bf2f(r1.y) + w1.z * bf2f(r2.y) + w1.w * bf2f(r3.y);
            float v2 = cb4.z + w2.x * bf2f(r0.z) + w2.y * bf2f(r1.z) + w2.z * bf2f(r2.z) + w2.w * bf2f(r3.z);
            float v3 = cb4.w + w3.x * bf2f(r0.w) + w3.y * bf2f(r1.w) + w3.z * bf2f(r2.w) + w3.w * bf2f(r3.w);
            ushort4 o = make_ushort4(f2bf(silu_f(v0)), f2bf(silu_f(v1)), f2bf(silu_f(v2)), f2bf(silu_f(v3)));
            *(ushort4*)(xmc + tok * 128 + ((kc ^ (tok & 7)) * 8) + (d4 & 4)) = o;
            xm_loc[0][tt] = o.x; xm_loc[1][tt] = o.y; xm_loc[2][tt] = o.z; xm_loc[3][tt] = o.w;
            ushort4 zv = *(const ushort4*)(zf + tok * 132 + d4);
            z_loc[0][tt] = zv.x; z_loc[1][tt] = zv.y; z_loc[2][tt] = zv.z; z_loc[3][tt] = zv.w;
        }
        int ck = (l0 >> 5) + (tok0 >> 5);
        int tb = tok0 & 31;
#pragma unroll
        for (int r = 0; r < 4; r++) {
            size_t rowb = (((size_t)b * NCH + ck) * DD + d4 + r) * 32 + tb;
            ushort8v px, pz;
#pragma unroll
            for (int j = 0; j < 8; j++) { px[j] = xm_loc[r][j]; pz[j] = z_loc[r][j]; }
            *(ushort8v*)(xmT + rowb) = px;
            *(ushort8v*)(zT + rowb) = pz;
        }
    }
    __syncthreads();

    short8 pa_[3][4];
#pragma unroll
    for (int mt = 0; mt < 3; mt++) {
        int j = mt * 16 + l15;
#pragma unroll
        for (int ks = 0; ks < 4; ks++) {
            short8 f = {0, 0, 0, 0, 0, 0, 0, 0};
            if (j < 36) {
                const float* wr = xw + (size_t)j * 128 + ks * 32 + l4g * 8;
                float4 a0 = *(const float4*)(wr);
                float4 a1 = *(const float4*)(wr + 4);
                f[0] = (short)f2bf(a0.x); f[1] = (short)f2bf(a0.y);
                f[2] = (short)f2bf(a0.z); f[3] = (short)f2bf(a0.w);
                f[4] = (short)f2bf(a1.x); f[5] = (short)f2bf(a1.y);
                f[6] = (short)f2bf(a1.z); f[7] = (short)f2bf(a1.w);
            }
            pa_[mt][ks] = f;
        }
    }
    int t = wv * 16 + l15;
    f32x4 a3[3];
#pragma unroll
    for (int mt = 0; mt < 3; mt++) a3[mt] = (f32x4){0.f, 0.f, 0.f, 0.f};
#pragma unroll
    for (int ks = 0; ks < 4; ks++) {
        short8 bf = *(const short8*)(xmc + t * 128 + (((ks * 4 + l4g) ^ (t & 7)) * 8));
#pragma unroll
        for (int mt = 0; mt < 3; mt++)
            a3[mt] = __builtin_amdgcn_mfma_f32_16x16x32_bf16(pa_[mt][ks], bf, a3[mt], 0, 0, 0);
    }
    size_t bl = (size_t)b * LL + l0 + t;
    float4 o0 = make_float4(a3[0][0], a3[0][1], a3[0][2], a3[0][3]);
    float4 o1 = make_float4(a3[1][0], a3[1][1], a3[1][2], a3[1][3]);
    float4 o2 = make_float4(a3[2][0], a3[2][1], a3[2][2], a3[2][3]);
    if (l4g == 0) {
        *(float4*)(sdtp + t * 4) = o0;               // dtp -> LDS
        *(float4*)(Bc2 + bl * 16 + 12) = o1;
        *(float4*)(Cc2 + bl * 16 + 12) = o2;
    } else {
        *(float4*)(Bc2 + bl * 16 + (l4g - 1) * 4) = o0;
        *(float4*)(Cc2 + bl * 16 + (l4g - 1) * 4) = o1;
    }
    __syncthreads();

    // ---- dt = softplus(dtp @ dtw^T + dtb), write chunk-transposed f32 tiles ----
    {
        int d4 = (tid & 31) * 4;
        int tok0 = (tid >> 5) * 8;
        float4 w0 = *(const float4*)(dtw + (d4 + 0) * 4);
        float4 w1 = *(const float4*)(dtw + (d4 + 1) * 4);
        float4 w2 = *(const float4*)(dtw + (d4 + 2) * 4);
        float4 w3 = *(const float4*)(dtw + (d4 + 3) * 4);
        float4 b4 = *(const float4*)(dtb + d4);
        float dt_loc[4][8];
#pragma unroll
        for (int tt = 0; tt < 8; tt++) {
            float4 q = *(const float4*)(sdtp + (tok0 + tt) * 4);
            dt_loc[0][tt] = softplus_f(b4.x + q.x * w0.x + q.y * w0.y + q.z * w0.z + q.w * w0.w);
            dt_loc[1][tt] = softplus_f(b4.y + q.x * w1.x + q.y * w1.y + q.z * w1.z + q.w * w1.w);
            dt_loc[2][tt] = softplus_f(b4.z + q.x * w2.x + q.y * w2.y + q.z * w2.z + q.w * w2.w);
            dt_loc[3][tt] = softplus_f(b4.w + q.x * w3.x + q.y * w3.y + q.z * w3.z + q.w * w3.w);
        }
        int ck = (l0 >> 5) + (tok0 >> 5);
        int tb = tok0 & 31;
#pragma unroll
        for (int r = 0; r < 4; r++) {
            size_t rowb = (((size_t)b * NCH + ck) * DD + d4 + r) * 32 + tb;
            *(float4*)(dtT + rowb) = make_float4(dt_loc[r][0], dt_loc[r][1], dt_loc[r][2], dt_loc[r][3]);
            *(float4*)(dtT + rowb + 4) = make_float4(dt_loc[r][4], dt_loc[r][5], dt_loc[r][6], dt_loc[r][7]);
        }
    }
}

// ---------------- Scan pass 1: bf16 B in LDS (2 ds_read/t), packed xm regs ----------------
__global__ __launch_bounds__(256) void k_s1(const unsigned short* __restrict__ xmT,
                                            const float* __restrict__ Bc2,
                                            const float* __restrict__ dtT,
                                            const float* __restrict__ A_log,
                                            float* __restrict__ chH,
                                            float* __restrict__ chP) {
    int b = blockIdx.x >> 6;                     // 512 blocks
    int ckp = blockIdx.x & 63;
    int w = __builtin_amdgcn_readfirstlane(threadIdx.x >> 6);
    int lane = threadIdx.x & 63;
    int ck = ckp * 2 + (w >> 1);
    int dh = w & 1;
    int d = dh * 64 + lane;

    __shared__ unsigned short sB[64][16];
    {
        int l = threadIdx.x >> 2, q = threadIdx.x & 3;
        float4 bv = *(const float4*)(Bc2 + ((size_t)b * LL + ckp * 64 + l) * 16 + q * 4);
        *(ushort4*)(&sB[l][q * 4]) = make_ushort4(f2bf(bv.x), f2bf(bv.y), f2bf(bv.z), f2bf(bv.w));
    }

    float a2[16];
#pragma unroll
    for (int j = 0; j < 4; j++) {
        float4 v = *(const float4*)(A_log + d * 16 + j * 4);
        a2[j * 4 + 0] = -__expf(v.x) * 1.4426950408889634f;
        a2[j * 4 + 1] = -__expf(v.y) * 1.4426950408889634f;
        a2[j * 4 + 2] = -__expf(v.z) * 1.4426950408889634f;
        a2[j * 4 + 3] = -__expf(v.w) * 1.4426950408889634f;
    }
    size_t rowb = (((size_t)b * NCH + ck) * DD + d) * 32;
    unsigned int xp[16];                         // 2 bf16 xm per reg
    float dts[32];
#pragma unroll
    for (int j = 0; j < 4; j++) {
        ushort8v v = *(const ushort8v*)(xmT + rowb + j * 8);
#pragma unroll
        for (int e = 0; e < 4; e++)
            xp[j * 4 + e] = (unsigned int)v[2 * e] | ((unsigned int)v[2 * e + 1] << 16);
    }
#pragma unroll
    for (int j = 0; j < 8; j++) {
        float4 v = *(const float4*)(dtT + rowb + j * 4);
        dts[j * 4 + 0] = v.x; dts[j * 4 + 1] = v.y; dts[j * 4 + 2] = v.z; dts[j * 4 + 3] = v.w;
    }

    float h[16];
#pragma unroll
    for (int n = 0; n < 16; n++) h[n] = 0.f;
    float sdt = 0.f;
    int lb = (w >> 1) * 32;
    __syncthreads();
#pragma unroll
    for (int t = 0; t < CLEN; t++) {
        unsigned int xw_ = xp[t >> 1];
        float xmv = __uint_as_float((t & 1) ? (xw_ & 0xffff0000u) : (xw_ << 16));
        float dtv = dts[t];
        float dx = dtv * xmv;
        ushort8v b0 = *(const ushort8v*)(&sB[lb + t][0]);
        ushort8v b1 = *(const ushort8v*)(&sB[lb + t][8]);
        sdt += dtv;
#pragma unroll
        for (int n = 0; n < 8; n++) {
            float dA = exp2f(dtv * a2[n]);
            h[n] = fmaf(dA, h[n], dx * bf2f(b0[n]));
        }
#pragma unroll
        for (int n = 0; n < 8; n++) {
            float dA = exp2f(dtv * a2[8 + n]);
            h[8 + n] = fmaf(dA, h[8 + n], dx * bf2f(b1[n]));
        }
    }
    size_t cbase = ((size_t)((b * 2 + dh) * NCH + ck)) * 1024 + lane * 16;
#pragma unroll
    for (int j = 0; j < 4; j++) {
        *(float4*)(chH + cbase + j * 4) = make_float4(h[j * 4], h[j * 4 + 1], h[j * 4 + 2], h[j * 4 + 3]);
        *(float4*)(chP + cbase + j * 4) = make_float4(exp2f(a2[j * 4] * sdt), exp2f(a2[j * 4 + 1] * sdt),
                                                      exp2f(a2[j * 4 + 2] * sdt), exp2f(a2[j * 4 + 3] * sdt));
    }
}

// ---------------- Scan pass 2: 16384 scalar recurrences over 128 chunks ----------------
__global__ __launch_bounds__(64) void k_s2(float* __restrict__ chH,
                                           const float* __restrict__ chP) {
    int t = blockIdx.x * 64 + threadIdx.x;   // 0..16383
    int row = t >> 10;
    int q = t & 1023;
    size_t base = (size_t)row * NCH * 1024 + q;
    float H = 0.f;
#pragma unroll 8
    for (int ck = 0; ck < NCH; ck++) {
        size_t a = base + (size_t)ck * 1024;
        float h = chH[a];
        float p = chP[a];
        chH[a] = H;
        H = fmaf(p, H, h);
    }
}

// ---------------- Scan pass 3 + out_proj: bf16 B/C in LDS, packed xm+z regs ----------------
__global__ __launch_bounds__(256) void k_s3(const unsigned short* __restrict__ xmT,
                                            const unsigned short* __restrict__ zT,
                                            const float* __restrict__ Bc2,
                                            const float* __restrict__ Cc2,
                                            const float* __restrict__ dtT,
                                            const float* __restrict__ A_log,
                                            const float* __restrict__ Dpp,
                                            const float* __restrict__ hinit,
                                            const float* __restrict__ wo,
                                            const float* __restrict__ pre,
                                            unsigned short* __restrict__ img1t) {
    int b = blockIdx.x >> 6;
    int ckp = blockIdx.x & 63;
    int w = __builtin_amdgcn_readfirstlane(threadIdx.x >> 6);
    int lane = threadIdx.x & 63;
    int ck = ckp * 2 + (w >> 1);
    int dh = w & 1;
    int d = dh * 64 + lane;
    int l15 = lane & 15, l4g = lane >> 4;

    __shared__ unsigned short sB[64][16];
    __shared__ unsigned short sC[64][16];
    __shared__ unsigned short sYt[64 * 128];     // [token][d], swizzled 8-chunks
    {
        int l = threadIdx.x >> 2, q = threadIdx.x & 3;
        float4 bv = *(const float4*)(Bc2 + ((size_t)b * LL + ckp * 64 + l) * 16 + q * 4);
        float4 cv = *(const float4*)(Cc2 + ((size_t)b * LL + ckp * 64 + l) * 16 + q * 4);
        *(ushort4*)(&sB[l][q * 4]) = make_ushort4(f2bf(bv.x), f2bf(bv.y), f2bf(bv.z), f2bf(bv.w));
        *(ushort4*)(&sC[l][q * 4]) = make_ushort4(f2bf(cv.x), f2bf(cv.y), f2bf(cv.z), f2bf(cv.w));
    }

    float a2[16];
#pragma unroll
    for (int j = 0; j < 4; j++) {
        float4 v = *(const float4*)(A_log + d * 16 + j * 4);
        a2[j * 4 + 0] = -__expf(v.x) * 1.4426950408889634f;
        a2[j * 4 + 1] = -__expf(v.y) * 1.4426950408889634f;
        a2[j * 4 + 2] = -__expf(v.z) * 1.4426950408889634f;
        a2[j * 4 + 3] = -__expf(v.w) * 1.4426950408889634f;
    }
    float Dpd = Dpp[d];
    size_t cbase = ((size_t)((b * 2 + dh) * NCH + ck)) * 1024 + lane * 16;
    float h[16];
#pragma unroll
    for (int j = 0; j < 4; j++) {
        float4 v = *(const float4*)(hinit + cbase + j * 4);
        h[j * 4 + 0] = v.x; h[j * 4 + 1] = v.y; h[j * 4 + 2] = v.z; h[j * 4 + 3] = v.w;
    }

    size_t rowb = (((size_t)b * NCH + ck) * DD + d) * 32;
    unsigned int xz[32];                         // z<<16 | xm per t
    float dts[32];
#pragma unroll
    for (int j = 0; j < 4; j++) {
        ushort8v v = *(const ushort8v*)(xmT + rowb + j * 8);
        ushort8v vz = *(const ushort8v*)(zT + rowb + j * 8);
#pragma unroll
        for (int e = 0; e < 8; e++)
            xz[j * 8 + e] = (unsigned int)v[e] | ((unsigned int)vz[e] << 16);
    }
#pragma unroll
    for (int j = 0; j < 8; j++) {
        float4 v = *(const float4*)(dtT + rowb + j * 4);
        dts[j * 4 + 0] = v.x; dts[j * 4 + 1] = v.y; dts[j * 4 + 2] = v.z; dts[j * 4 + 3] = v.w;
    }

    int lb = (w >> 1) * 32;
    int cperm = d >> 3;
    __syncthreads();
#pragma unroll
    for (int t = 0; t < CLEN; t++) {
        unsigned int xzv = xz[t];
        float xmv = __uint_as_float(xzv << 16);
        float zv = __uint_as_float(xzv & 0xffff0000u);
        float dtv = dts[t];
        float dx = dtv * xmv;
        ushort8v b0 = *(const ushort8v*)(&sB[lb + t][0]);
        ushort8v b1 = *(const ushort8v*)(&sB[lb + t][8]);
        ushort8v c0 = *(const ushort8v*)(&sC[lb + t][0]);
        ushort8v c1 = *(const ushort8v*)(&sC[lb + t][8]);
        float y0 = 0.f, y1 = 0.f, y2 = 0.f, y3 = 0.f;
#pragma unroll
        for (int n = 0; n < 8; n += 4) {
            float dA0 = exp2f(dtv * a2[n]);
            float dA1 = exp2f(dtv * a2[n + 1]);
            float dA2 = exp2f(dtv * a2[n + 2]);
            float dA3 = exp2f(dtv * a2[n + 3]);
            h[n] = fmaf(dA0, h[n], dx * bf2f(b0[n]));
            h[n + 1] = fmaf(dA1, h[n + 1], dx * bf2f(b0[n + 1]));
            h[n + 2] = fmaf(dA2, h[n + 2], dx * bf2f(b0[n + 2]));
            h[n + 3] = fmaf(dA3, h[n + 3], dx * bf2f(b0[n + 3]));
            y0 = fmaf(h[n], bf2f(c0[n]), y0);
            y1 = fmaf(h[n + 1], bf2f(c0[n + 1]), y1);
            y2 = fmaf(h[n + 2], bf2f(c0[n + 2]), y2);
            y3 = fmaf(h[n + 3], bf2f(c0[n + 3]), y3);
        }
#pragma unroll
        for (int n = 0; n < 8; n += 4) {
            float dA0 = exp2f(dtv * a2[8 + n]);
            float dA1 = exp2f(dtv * a2[8 + n + 1]);
            float dA2 = exp2f(dtv * a2[8 + n + 2]);
            float dA3 = exp2f(dtv * a2[8 + n + 3]);
            h[8 + n] = fmaf(dA0, h[8 + n], dx * bf2f(b1[n]));
            h[8 + n + 1] = fmaf(dA1, h[8 + n + 1], dx * bf2f(b1[n + 1]));
            h[8 + n + 2] = fmaf(dA2, h[8 + n + 2], dx * bf2f(b1[n + 2]));
            h[8 + n + 3] = fmaf(dA3, h[8 + n + 3], dx * bf2f(b1[n + 3]));
            y0 = fmaf(h[8 + n], bf2f(c1[n]), y0);
            y1 = fmaf(h[8 + n + 1], bf2f(c1[n + 1]), y1);
            y2 = fmaf(h[8 + n + 2], bf2f(c1[n + 2]), y2);
            y3 = fmaf(h[8 + n + 3], bf2f(c1[n + 3]), y3);
        }
        float yv = (y0 + y1) + (y2 + y3);
        yv = fmaf(xmv, Dpd, yv);
        int lt = lb + t;
        sYt[lt * 128 + ((cperm ^ (lt & 7)) * 8) + (d & 7)] = f2bf(yv * silu_f(zv));
    }
    __syncthreads();

    // out_proj A fragments (loaded after scan to keep scan VGPR low)
    int oc0 = w * 16;
    short8 pao[4];
#pragma unroll
    for (int ks = 0; ks < 4; ks++) {
        const float* wr = wo + (size_t)(oc0 + l15) * 128 + ks * 32 + l4g * 8;
        float4 a0 = *(const float4*)(wr);
        float4 a1 = *(const float4*)(wr + 4);
        short8 f;
        f[0] = (short)f2bf(a0.x); f[1] = (short)f2bf(a0.y);
        f[2] = (short)f2bf(a0.z); f[3] = (short)f2bf(a0.w);
        f[4] = (short)f2bf(a1.x); f[5] = (short)f2bf(a1.y);
        f[6] = (short)f2bf(a1.z); f[7] = (short)f2bf(a1.w);
        pao[ks] = f;
    }

    // ---- out_proj MFMA: M=16 oc (this wave), N=64 tokens, K=128 ----
    f32x4 po[4];
#pragma unroll
    for (int n0 = 0; n0 < 4; n0++) po[n0] = (f32x4){0.f, 0.f, 0.f, 0.f};
#pragma unroll
    for (int ks = 0; ks < 4; ks++) {
#pragma unroll
        for (int n0 = 0; n0 < 4; n0++) {
            int j = n0 * 16 + l15;
            short8 bf = *(const short8*)(sYt + j * 128 + (((ks * 4 + l4g) ^ (j & 7)) * 8));
            po[n0] = __builtin_amdgcn_mfma_f32_16x16x32_bf16(pao[ks], bf, po[n0], 0, 0, 0);
        }
    }
    float pa = pre[0];
    int ocb = oc0 + (l4g << 2);
#pragma unroll
    for (int n0 = 0; n0 < 4; n0++) {
        int tj = n0 * 16 + l15;
        int px = tj * 64 + ckp;                  // l = ckp*64+tj -> px=(l&63)*64+(l>>6)
        ushort4 u;
        float v0 = po[n0][0]; v0 = v0 >= 0.f ? v0 : pa * v0;
        float v1 = po[n0][1]; v1 = v1 >= 0.f ? v1 : pa * v1;
        float v2 = po[n0][2]; v2 = v2 >= 0.f ? v2 : pa * v2;
        float v3 = po[n0][3]; v3 = v3 >= 0.f ? v3 : pa * v3;
        u = make_ushort4(f2bf(v0), f2bf(v1), f2bf(v2), f2bf(v3));
        *(ushort4*)(img1t + ((size_t)b * 4096 + px) * 64 + ocb) = u;
    }
}

// ---------------- weight prep: Wk[oc][shift*64+ic] bf16 for both 3x3 convs ----------------
__global__ __launch_bounds__(256) void k_wprep(const float* __restrict__ w1,
                                               const float* __restrict__ w2,
                                               unsigned short* __restrict__ Wk1,
                                               unsigned short* __restrict__ Wk2) {
    int idx = blockIdx.x * 256 + threadIdx.x;
    if (idx >= 2 * 36864) return;
    const float* w = (idx < 36864) ? w1 : w2;
    unsigned short* dst = (idx < 36864) ? Wk1 : Wk2;
    int r = (idx < 36864) ? idx : idx - 36864;
    int oc = r / 576, k = r % 576;
    int shift = k >> 6, ic = k & 63;
    dst[oc * 576 + k] = f2bf(w[(oc * 64 + ic) * 9 + shift]);
}

// ---------------- K5: 3x3 conv via MFMA bf16 + BN + PReLU -> img2t bf16 ----------------
__global__ __launch_bounds__(256) void k_conv3m(const unsigned short* __restrict__ in_t,
                                                const unsigned short* __restrict__ Wk,
                                                const float* __restrict__ bnp,
                                                const float* __restrict__ pre,
                                                unsigned short* __restrict__ out_t) {
    int bid = blockIdx.x;
    int b = bid >> 6;
    int p = bid & 63;
    int tid = threadIdx.x;
    int lane = tid & 63;
    int wv = tid >> 6;
    int oc0 = __builtin_amdgcn_readfirstlane(wv * 16);
    __shared__ unsigned short lds[3 * 66 * 64];

    short8 afrag[18];
    const unsigned short* wrow = Wk + (size_t)(oc0 + (lane & 15)) * 576 + ((lane >> 4) * 8);
#pragma unroll
    for (int s = 0; s < 18; s++) afrag[s] = *(const short8*)(wrow + s * 32);

    const unsigned short* ib = in_t + (size_t)b * 4096 * 64;
    for (int idx = tid; idx < 1584; idx += 256) {
        int pair = idx >> 3, c = idx & 7;
        int di = pair / 66, col = pair % 66;
        int r = p - 1 + di, q = col - 1;
        ushort8v v = {0, 0, 0, 0, 0, 0, 0, 0};
        if (r >= 0 && r < 64 && q >= 0 && q < 64)
            v = *(const ushort8v*)(ib + ((size_t)(r * 64 + q)) * 64 + c * 8);
        *(ushort8v*)(lds + pair * 64 + ((c ^ (col & 7)) * 8)) = v;
    }
    __syncthreads();

    f32x4 acc[4];
#pragma unroll
    for (int n0 = 0; n0 < 4; n0++) acc[n0] = (f32x4){0.f, 0.f, 0.f, 0.f};
#pragma unroll
    for (int s = 0; s < 18; s++) {
        const int shift = s >> 1, h = s & 1;
        const int di = shift / 3, dj = shift % 3;
#pragma unroll
        for (int n0 = 0; n0 < 4; n0++) {
            int col = n0 * 16 + (lane & 15) + dj;
            int off = (di * 66 + col) * 64 + (((h * 4 + (lane >> 4)) ^ (col & 7)) * 8);
            short8 bfrag = *(const short8*)(lds + off);
            acc[n0] = __builtin_amdgcn_mfma_f32_16x16x32_bf16(afrag[s], bfrag, acc[n0], 0, 0, 0);
        }
    }

    int ocb = oc0 + ((lane >> 4) << 2);
    float4 g4 = *(const float4*)(bnp + ocb);
    float4 be4 = *(const float4*)(bnp + 64 + ocb);
    float4 m4 = *(const float4*)(bnp + 128 + ocb);
    float4 v4 = *(const float4*)(bnp + 192 + ocb);
    float sc[4], sh[4];
    sc[0] = g4.x * rsqrtf(v4.x + EPS); sh[0] = be4.x - m4.x * sc[0];
    sc[1] = g4.y * rsqrtf(v4.y + EPS); sh[1] = be4.y - m4.y * sc[1];
    sc[2] = g4.z * rsqrtf(v4.z + EPS); sh[2] = be4.z - m4.z * sc[2];
    sc[3] = g4.w * rsqrtf(v4.w + EPS); sh[3] = be4.w - m4.w * sc[3];
    float pa = pre[0];
#pragma unroll
    for (int n0 = 0; n0 < 4; n0++) {
        int q = n0 * 16 + (lane & 15);
        float vals[4];
#pragma unroll
        for (int r = 0; r < 4; r++) {
            float v = fmaf(acc[n0][r], sc[r], sh[r]);
            vals[r] = v >= 0.f ? v : pa * v;
        }
        ushort4 u = make_ushort4(f2bf(vals[0]), f2bf(vals[1]), f2bf(vals[2]), f2bf(vals[3]));
        *(ushort4*)(out_t + ((size_t)b * 4096 + p * 64 + q) * 64 + ocb) = u;
    }
}

// ---------------- K6: 3x3 conv + BN + PReLU + fused residual(1x1 conv+BN on x) -> f32 out ----------------
__global__ __launch_bounds__(256) void k_conv3f(const unsigned short* __restrict__ in_t,
                                                const unsigned short* __restrict__ Wk,
                                                const float* __restrict__ bnp,
                                                const float* __restrict__ pre,
                                                const float* __restrict__ x,
                                                const float* __restrict__ rw,
                                                const float* __restrict__ rbn,
                                                float* __restrict__ outf) {
    int bid = blockIdx.x;
    int b = bid >> 6;
    int p = bid & 63;
    int tid = threadIdx.x;
    int lane = tid & 63;
    int wv = tid >> 6;
    int oc0 = __builtin_amdgcn_readfirstlane(wv * 16);
    int l15 = lane & 15, l4g = lane >> 4;
    __shared__ unsigned short lds[3 * 66 * 64];
    __shared__ unsigned short xr[64 * 64];       // x row-tile [q][ic], swizzled

    short8 afrag[18];
    const unsigned short* wrow = Wk + (size_t)(oc0 + l15) * 576 + (l4g * 8);
#pragma unroll
    for (int s = 0; s < 18; s++) afrag[s] = *(const short8*)(wrow + s * 32);

    short8 arf[2];
#pragma unroll
    for (int hh = 0; hh < 2; hh++) {
        const float* wr = rw + (size_t)(oc0 + l15) * 64 + hh * 32 + l4g * 8;
        float4 a0 = *(const float4*)(wr);
        float4 a1 = *(const float4*)(wr + 4);
        short8 f;
        f[0] = (short)f2bf(a0.x); f[1] = (short)f2bf(a0.y);
        f[2] = (short)f2bf(a0.z); f[3] = (short)f2bf(a0.w);
        f[4] = (short)f2bf(a1.x); f[5] = (short)f2bf(a1.y);
        f[6] = (short)f2bf(a1.z); f[7] = (short)f2bf(a1.w);
        arf[hh] = f;
    }

    const unsigned short* ib = in_t + (size_t)b * 4096 * 64;
    for (int idx = tid; idx < 1584; idx += 256) {
        int pair = idx >> 3, c = idx & 7;
        int di = pair / 66, col = pair % 66;
        int r = p - 1 + di, q = col - 1;
        ushort8v v = {0, 0, 0, 0, 0, 0, 0, 0};
        if (r >= 0 && r < 64 && q >= 0 && q < 64)
            v = *(const ushort8v*)(ib + ((size_t)(r * 64 + q)) * 64 + c * 8);
        *(ushort8v*)(lds + pair * 64 + ((c ^ (col & 7)) * 8)) = v;
    }
    for (int idx = tid; idx < 4096; idx += 256) {
        int ic = idx >> 6, q = idx & 63;
        float v = x[((size_t)b * 64 + ic) * 4096 + p * 64 + q];
        xr[q * 64 + (((ic >> 3) ^ (q & 7)) * 8) + (ic & 7)] = f2bf(v);
    }
    __syncthreads();

    f32x4 acc[4], accr[4];
#pragma unroll
    for (int n0 = 0; n0 < 4; n0++) {
        acc[n0] = (f32x4){0.f, 0.f, 0.f, 0.f};
        accr[n0] = (f32x4){0.f, 0.f, 0.f, 0.f};
    }
#pragma unroll
    for (int s = 0; s < 18; s++) {
        const int shift = s >> 1, h = s & 1;
        const int di = shift / 3, dj = shift % 3;
#pragma unroll
        for (int n0 = 0; n0 < 4; n0++) {
            int col = n0 * 16 + l15 + dj;
            int off = (di * 66 + col) * 64 + (((h * 4 + l4g) ^ (col & 7)) * 8);
            short8 bfrag = *(const short8*)(lds + off);
            acc[n0] = __builtin_amdgcn_mfma_f32_16x16x32_bf16(afrag[s], bfrag, acc[n0], 0, 0, 0);
        }
    }
#pragma unroll
    for (int hh = 0; hh < 2; hh++) {
#pragma unroll
        for (int n0 = 0; n0 < 4; n0++) {
            int j = n0 * 16 + l15;
            short8 bfr = *(const short8*)(xr + j * 64 + (((hh * 4 + l4g) ^ (j & 7)) * 8));
            accr[n0] = __builtin_amdgcn_mfma_f32_16x16x32_bf16(arf[hh], bfr, accr[n0], 0, 0, 0);
        }
    }

    int ocb = oc0 + (l4g << 2);
    float4 g4 = *(const float4*)(bnp + ocb);
    float4 be4 = *(const float4*)(bnp + 64 + ocb);
    float4 m4 = *(const float4*)(bnp + 128 + ocb);
    float4 v4 = *(const float4*)(bnp + 192 + ocb);
    float sc[4], sh[4];
    sc[0] = g4.x * rsqrtf(v4.x + EPS); sh[0] = be4.x - m4.x * sc[0];
    sc[1] = g4.y * rsqrtf(v4.y + EPS); sh[1] = be4.y - m4.y * sc[1];
    sc[2] = g4.z * rsqrtf(v4.z + EPS); sh[2] = be4.z - m4.z * sc[2];
    sc[3] = g4.w * rsqrtf(v4.w + EPS); sh[3] = be4.w - m4.w * sc[3];
    float4 rg4 = *(const float4*)(rbn + ocb);
    float4 rbe4 = *(const float4*)(rbn + 64 + ocb);
    float4 rm4 = *(const float4*)(rbn + 128 + ocb);
    float4 rv4 = *(const float4*)(rbn + 192 + ocb);
    float rsc[4], rsh[4];
    rsc[0] = rg4.x * rsqrtf(rv4.x + EPS); rsh[0] = rbe4.x - rm4.x * rsc[0];
    rsc[1] = rg4.y * rsqrtf(rv4.y + EPS); rsh[1] = rbe4.y - rm4.y * rsc[1];
    rsc[2] = rg4.z * rsqrtf(rv4.z + EPS); rsh[2] = rbe4.z - rm4.z * rsc[2];
    rsc[3] = rg4.w * rsqrtf(rv4.w + EPS); rsh[3] = rbe4.w - rm4.w * rsc[3];
    float pa = pre[0];
#pragma unroll
    for (int n0 = 0; n0 < 4; n0++) {
        int q = n0 * 16 + l15;
#pragma unroll
        for (int r = 0; r < 4; r++) {
            float v = fmaf(acc[n0][r], sc[r], sh[r]);
            v = v >= 0.f ? v : pa * v;
            float rv = fmaf(accr[n0][r], rsc[r], rsh[r]);
            size_t addr = ((size_t)b * 64 + ocb + r) * 4096 + p * 64 + q;
            outf[addr] = v + rv;
        }
    }
}

extern "C" void kernel_launch(void* const* d_in, const int* in_sizes, int n_in,
                              void* d_out, int out_size, void* d_ws, size_t ws_size,
                              hipStream_t stream) {
    const float* x = (const float*)d_in[0];
    const float* in_proj_w = (const float*)d_in[1];
    const float* conv1d_w = (const float*)d_in[2];
    const float* conv1d_b = (const float*)d_in[3];
    const float* x_proj_w = (const float*)d_in[4];
    const float* dt_proj_w = (const float*)d_in[5];
    const float* dt_proj_b = (const float*)d_in[6];
    const float* A_log = (const float*)d_in[7];
    const float* Dp = (const float*)d_in[8];
    const float* out_proj_w = (const float*)d_in[9];
    const float* prelu_ssm = (const float*)d_in[10];
    const float* res_w = (const float*)d_in[11];
    const float* res_bn = (const float*)d_in[12];
    const float* conv1_w = (const float*)d_in[13];
    const float* bn1 = (const float*)d_in[14];
    const float* prelu1 = (const float*)d_in[15];
    const float* conv2_w = (const float*)d_in[16];
    const float* bn2 = (const float*)d_in[17];
    const float* prelu2 = (const float*)d_in[18];
    float* out = (float*)d_out;
    float* ws = (float*)d_ws;

    const size_t S = (size_t)BB * LL * DD;        // 4,194,304 floats
    const size_t HALF = S / 2;
    float* chH = ws;                              // [0, HALF)    live s1..s3
    float* chP = ws + HALF;                       // [HALF, S)    live s1..s2
    unsigned short* xmT = (unsigned short*)(ws + S);              // bf16 [b][ck][d][32]
    unsigned short* zT = (unsigned short*)(ws + S + HALF);        // bf16
    float* dtT = ws + 2 * S;                      // f32 [b][ck][d][32]
    unsigned short* img1t = (unsigned short*)(ws + 3 * S);        // bf16 [b][px][64]
    float* Bc2 = ws + 3 * S + S / 4;              // S/8
    float* Cc2 = Bc2 + S / 8;                     // S/8
    unsigned short* Wk1 = (unsigned short*)(Cc2 + S / 8);         // 36864 bf16 each
    unsigned short* Wk2 = Wk1 + 36864;
    unsigned short* img2t = (unsigned short*)(ws + HALF);         // over chP, after s2

    k_front<<<dim3(512), dim3(256), 0, stream>>>(x, in_proj_w, x_proj_w, conv1d_w, conv1d_b,
                                                 dt_proj_w, dt_proj_b,
                                                 xmT, zT, Bc2, Cc2, dtT);
    k_wprep<<<dim3(288), dim3(256), 0, stream>>>(conv1_w, conv2_w, Wk1, Wk2);
    k_s1<<<dim3(512), dim3(256), 0, stream>>>(xmT, Bc2, dtT, A_log, chH, chP);
    k_s2<<<dim3(256), dim3(64), 0, stream>>>(chH, chP);
    k_s3<<<dim3(512), dim3(256), 0, stream>>>(xmT, zT, Bc2, Cc2, dtT, A_log, Dp, chH,
                                              out_proj_w, prelu_ssm, img1t);
    k_conv3m<<<dim3(512), dim3(256), 0, stream>>>(img1t, Wk1, bn1, prelu1, img2t);
    k_conv3f<<<dim3(512), dim3(256), 0, stream>>>(img2t, Wk2, bn2, prelu2, x, res_w, res_bn, out);
}